// Round 10
// baseline (749.673 us; speedup 1.0000x reference)
//
#include <hip/hip_runtime.h>
#include <type_traits>

#define FDIM 320
#define NHEADS 10
#define NGR 256

typedef __bf16 bf16x8 __attribute__((ext_vector_type(8)));
typedef float f32x4 __attribute__((ext_vector_type(4)));

// ---------------- weight transpose+convert (both weights, one launch) ------
__global__ void wconv2_kernel(const float* __restrict__ Wg, const float* __restrict__ Wa,
                              __bf16* __restrict__ Tg, __bf16* __restrict__ Ta) {
  int idx = blockIdx.x * 256 + threadIdx.x;
  bool first = idx < FDIM * FDIM;
  const float* W = first ? Wg : Wa;
  __bf16* T = first ? Tg : Ta;
  int i2 = first ? idx : idx - FDIM * FDIM;
  int k = i2 / FDIM, c = i2 - k * FDIM;
  T[c * FDIM + k] = (__bf16)W[i2];
}

// ---------------- node GEMM v3: full-N, BK=32, LDS dbuf, async reg-stage ---
#define GLSTR 40

template<typename TA, bool SCORES>
__global__ __launch_bounds__(256, 2) void gemm320v3_kernel(
    const TA* __restrict__ A, const __bf16* __restrict__ Wt,
    __bf16* __restrict__ C, int M,
    const float* __restrict__ att_s, const float* __restrict__ att_d,
    float* __restrict__ as_, float* __restrict__ ad_)
{
  __shared__ __bf16 As[2][64 * GLSTR];
  __shared__ __bf16 Bs[2][320 * GLSTR];

  const int tid = threadIdx.x;
  const int lane = tid & 63;
  const int w = tid >> 6;
  const int wr = w >> 1, wc = w & 1;
  const int r = lane & 15, kg = lane >> 4;
  const int m0 = blockIdx.x * 64;

  const int brow = tid >> 2, bq = tid & 3;
  const int gmrow = m0 + brow;
  const bool arow_ok = gmrow < M;

  bf16x8 bstg[5];
  bf16x8 astg;
  float4 af32a, af32b;

  auto stage_load = [&](int k0) {
    #pragma unroll
    for (int i = 0; i < 5; i++) {
      int ch = tid + i * 256;
      int col = ch >> 2, kc = ch & 3;
      bstg[i] = *(const bf16x8*)(Wt + (size_t)col * FDIM + k0 + kc * 8);
    }
    if constexpr (std::is_same_v<TA, float>) {
      if (arow_ok) {
        const float4* ap = (const float4*)(A + (size_t)gmrow * FDIM + k0 + bq * 8);
        af32a = ap[0]; af32b = ap[1];
      }
    } else {
      if (arow_ok) astg = *(const bf16x8*)(A + (size_t)gmrow * FDIM + k0 + bq * 8);
    }
  };
  auto stage_write = [&](int b) {
    #pragma unroll
    for (int i = 0; i < 5; i++) {
      int ch = tid + i * 256;
      int col = ch >> 2, kc = ch & 3;
      *(bf16x8*)&Bs[b][col * GLSTR + kc * 8] = bstg[i];
    }
    bf16x8 v = {};
    if constexpr (std::is_same_v<TA, float>) {
      if (arow_ok) {
        v[0]=(__bf16)af32a.x; v[1]=(__bf16)af32a.y; v[2]=(__bf16)af32a.z; v[3]=(__bf16)af32a.w;
        v[4]=(__bf16)af32b.x; v[5]=(__bf16)af32b.y; v[6]=(__bf16)af32b.z; v[7]=(__bf16)af32b.w;
      }
    } else {
      if (arow_ok) v = astg;
    }
    *(bf16x8*)&As[b][brow * GLSTR + bq * 8] = v;
  };

  f32x4 acc0[10], acc1[10];
  #pragma unroll
  for (int i = 0; i < 10; i++) { acc0[i] = (f32x4){0,0,0,0}; acc1[i] = (f32x4){0,0,0,0}; }

  stage_load(0);
  stage_write(0);
  __syncthreads();

  int cur = 0;
  for (int k = 0; k < 10; k++) {
    if (k < 9) stage_load((k + 1) * 32);
    {
      bf16x8 a0 = *(const bf16x8*)&As[cur][(wr*32 + r)      * GLSTR + kg*8];
      bf16x8 a1 = *(const bf16x8*)&As[cur][(wr*32 + 16 + r) * GLSTR + kg*8];
      #pragma unroll
      for (int nf = 0; nf < 10; nf++) {
        bf16x8 b = *(const bf16x8*)&Bs[cur][(wc*160 + nf*16 + r) * GLSTR + kg*8];
        acc0[nf] = __builtin_amdgcn_mfma_f32_16x16x32_bf16(a0, b, acc0[nf], 0, 0, 0);
        acc1[nf] = __builtin_amdgcn_mfma_f32_16x16x32_bf16(a1, b, acc1[nf], 0, 0, 0);
      }
    }
    if (k < 9) {
      stage_write(cur ^ 1);
      __syncthreads();
      cur ^= 1;
    }
  }

  // ---- store C ----
  #pragma unroll
  for (int nf = 0; nf < 10; nf++) {
    int gn = wc*160 + nf*16 + r;
    #pragma unroll
    for (int q = 0; q < 4; q++) {
      int gm0 = m0 + wr*32 + kg*4 + q;
      if (gm0 < M)       C[(size_t)gm0 * FDIM + gn] = (__bf16)acc0[nf][q];
      int gm1 = gm0 + 16;
      if (gm1 < M)       C[(size_t)gm1 * FDIM + gn] = (__bf16)acc1[nf][q];
    }
  }

  // ---- fused GAT scores ----
  if constexpr (SCORES) {
    #pragma unroll
    for (int th = 0; th < 5; th++) {
      int t = wc * 5 + th;
      float s0 = att_s[t*32 + r],      s1 = att_s[t*32 + 16 + r];
      float d0 = att_d[t*32 + r],      d1 = att_d[t*32 + 16 + r];
      #pragma unroll
      for (int q = 0; q < 4; q++) {
        float ps0 = acc0[2*th][q]*s0 + acc0[2*th+1][q]*s1;
        float ps1 = acc1[2*th][q]*s0 + acc1[2*th+1][q]*s1;
        float pd0 = acc0[2*th][q]*d0 + acc0[2*th+1][q]*d1;
        float pd1 = acc1[2*th][q]*d0 + acc1[2*th+1][q]*d1;
        #pragma unroll
        for (int off = 1; off < 16; off <<= 1) {
          ps0 += __shfl_xor(ps0, off, 16);
          ps1 += __shfl_xor(ps1, off, 16);
          pd0 += __shfl_xor(pd0, off, 16);
          pd1 += __shfl_xor(pd1, off, 16);
        }
        if (r == 0) {
          int row0 = m0 + wr*32 + kg*4 + q;
          if (row0 < M) { as_[row0*NHEADS + t] = ps0; ad_[row0*NHEADS + t] = pd0; }
          int row1 = row0 + 16;
          if (row1 < M) { as_[row1*NHEADS + t] = ps1; ad_[row1*NHEADS + t] = pd1; }
        }
      }
    }
  }
}

// ---------------- generic GEMM (FC layers): C = A*B, f32 in/out ------------
#define BM 128
#define BN 64
#define BK 32
#define LSTR 56

template<int FLAGS>  // bit0: relu, bit1: bias
__global__ __launch_bounds__(256) void gemm_bf16_kernel(
    const float* __restrict__ A, const float* __restrict__ B,
    float* __restrict__ C, const float* __restrict__ bias,
    int M, int N, int K, int ldc)
{
  __shared__ __bf16 As[BM * LSTR];
  __shared__ __bf16 Bs[BN * LSTR];

  const int tid = threadIdx.x;
  const int lane = tid & 63;
  const int w = tid >> 6;
  const int wm = w >> 1, wn = w & 1;
  const int r = lane & 15, kg = lane >> 4;
  const int m0 = blockIdx.x * BM, n0 = blockIdx.y * BN;

  f32x4 acc[4][2];
  #pragma unroll
  for (int i = 0; i < 4; i++)
    #pragma unroll
    for (int j = 0; j < 2; j++)
      acc[i][j] = (f32x4){0.f, 0.f, 0.f, 0.f};

  const int arow = tid >> 1, ahalf = tid & 1;
  const int bk = tid >> 3, bn = (tid & 7) * 8;

  for (int k0 = 0; k0 < K; k0 += BK) {
    __syncthreads();
    {
      int gm = m0 + arow;
      int kbase = k0 + ahalf * 16;
      float tmp[16];
      if (gm < M && kbase + 16 <= K) {
        const float4* ap = (const float4*)(A + (size_t)gm * K + kbase);
        #pragma unroll
        for (int q = 0; q < 4; q++) {
          float4 v = ap[q];
          tmp[q*4+0] = v.x; tmp[q*4+1] = v.y; tmp[q*4+2] = v.z; tmp[q*4+3] = v.w;
        }
      } else {
        #pragma unroll
        for (int q = 0; q < 16; q++) {
          int kk = kbase + q;
          tmp[q] = (gm < M && kk < K) ? A[(size_t)gm * K + kk] : 0.f;
        }
      }
      bf16x8 v0, v1;
      #pragma unroll
      for (int q = 0; q < 8; q++) { v0[q] = (__bf16)tmp[q]; v1[q] = (__bf16)tmp[q+8]; }
      bf16x8* dp = (bf16x8*)&As[arow * LSTR + ahalf * 16];
      dp[0] = v0; dp[1] = v1;
    }
    {
      int gk = k0 + bk;
      float tb[8];
      if (gk < K && n0 + bn + 8 <= N) {
        const float4* bp = (const float4*)(B + (size_t)gk * N + n0 + bn);
        float4 u0 = bp[0], u1 = bp[1];
        tb[0]=u0.x; tb[1]=u0.y; tb[2]=u0.z; tb[3]=u0.w;
        tb[4]=u1.x; tb[5]=u1.y; tb[6]=u1.z; tb[7]=u1.w;
      } else {
        #pragma unroll
        for (int q = 0; q < 8; q++) {
          int gn = n0 + bn + q;
          tb[q] = (gk < K && gn < N) ? B[(size_t)gk * N + gn] : 0.f;
        }
      }
      #pragma unroll
      for (int q = 0; q < 8; q++) Bs[(bn + q) * LSTR + bk] = (__bf16)tb[q];
    }
    __syncthreads();
    bf16x8 af[4], bfr[2];
    #pragma unroll
    for (int mf = 0; mf < 4; mf++)
      af[mf] = *(const bf16x8*)&As[(wm*64 + mf*16 + r) * LSTR + kg*8];
    #pragma unroll
    for (int nf = 0; nf < 2; nf++)
      bfr[nf] = *(const bf16x8*)&Bs[(wn*32 + nf*16 + r) * LSTR + kg*8];
    #pragma unroll
    for (int mf = 0; mf < 4; mf++)
      #pragma unroll
      for (int nf = 0; nf < 2; nf++)
        acc[mf][nf] = __builtin_amdgcn_mfma_f32_16x16x32_bf16(af[mf], bfr[nf], acc[mf][nf], 0, 0, 0);
  }

  #pragma unroll
  for (int mf = 0; mf < 4; mf++) {
    #pragma unroll
    for (int nf = 0; nf < 2; nf++) {
      #pragma unroll
      for (int q = 0; q < 4; q++) {
        int gm = m0 + wm*64 + mf*16 + kg*4 + q;
        int gn = n0 + wn*32 + nf*16 + r;
        if (gm < M && gn < N) {
          float v = acc[mf][nf][q];
          if (FLAGS & 2) v += bias[gn];
          if (FLAGS & 1) v = fmaxf(v, 0.f);
          C[(size_t)gm * ldc + gn] = v;
        }
      }
    }
  }
}

// ---------------- split-K GEMM: P[s][M][N] partials ----------------
__global__ __launch_bounds__(256) void gemm_splitk_kernel(
    const float* __restrict__ A, const float* __restrict__ B,
    float* __restrict__ P, int M, int N, int K, int KS)
{
  __shared__ __bf16 As[BM * LSTR];
  __shared__ __bf16 Bs[BN * LSTR];

  const int tid = threadIdx.x;
  const int lane = tid & 63;
  const int w = tid >> 6;
  const int wm = w >> 1, wn = w & 1;
  const int r = lane & 15, kg = lane >> 4;
  const int m0 = blockIdx.x * BM, n0 = blockIdx.y * BN;
  const int kstart = blockIdx.z * KS;
  const int kend = min(K, kstart + KS);

  f32x4 acc[4][2];
  #pragma unroll
  for (int i = 0; i < 4; i++)
    #pragma unroll
    for (int j = 0; j < 2; j++)
      acc[i][j] = (f32x4){0.f, 0.f, 0.f, 0.f};

  const int arow = tid >> 1, ahalf = tid & 1;
  const int bk = tid >> 3, bn = (tid & 7) * 8;

  for (int k0 = kstart; k0 < kend; k0 += BK) {
    __syncthreads();
    {
      int gm = m0 + arow;
      int kbase = k0 + ahalf * 16;
      float tmp[16];
      if (gm < M && kbase + 16 <= kend) {
        const float4* ap = (const float4*)(A + (size_t)gm * K + kbase);
        #pragma unroll
        for (int q = 0; q < 4; q++) {
          float4 v = ap[q];
          tmp[q*4+0] = v.x; tmp[q*4+1] = v.y; tmp[q*4+2] = v.z; tmp[q*4+3] = v.w;
        }
      } else {
        #pragma unroll
        for (int q = 0; q < 16; q++) {
          int kk = kbase + q;
          tmp[q] = (gm < M && kk < kend) ? A[(size_t)gm * K + kk] : 0.f;
        }
      }
      bf16x8 v0, v1;
      #pragma unroll
      for (int q = 0; q < 8; q++) { v0[q] = (__bf16)tmp[q]; v1[q] = (__bf16)tmp[q+8]; }
      bf16x8* dp = (bf16x8*)&As[arow * LSTR + ahalf * 16];
      dp[0] = v0; dp[1] = v1;
    }
    {
      int gk = k0 + bk;
      float tb[8];
      if (gk < kend && n0 + bn + 8 <= N) {
        const float4* bp = (const float4*)(B + (size_t)gk * N + n0 + bn);
        float4 u0 = bp[0], u1 = bp[1];
        tb[0]=u0.x; tb[1]=u0.y; tb[2]=u0.z; tb[3]=u0.w;
        tb[4]=u1.x; tb[5]=u1.y; tb[6]=u1.z; tb[7]=u1.w;
      } else {
        #pragma unroll
        for (int q = 0; q < 8; q++) {
          int gn = n0 + bn + q;
          tb[q] = (gk < kend && gn < N) ? B[(size_t)gk * N + gn] : 0.f;
        }
      }
      #pragma unroll
      for (int q = 0; q < 8; q++) Bs[(bn + q) * LSTR + bk] = (__bf16)tb[q];
    }
    __syncthreads();
    bf16x8 af[4], bfr[2];
    #pragma unroll
    for (int mf = 0; mf < 4; mf++)
      af[mf] = *(const bf16x8*)&As[(wm*64 + mf*16 + r) * LSTR + kg*8];
    #pragma unroll
    for (int nf = 0; nf < 2; nf++)
      bfr[nf] = *(const bf16x8*)&Bs[(wn*32 + nf*16 + r) * LSTR + kg*8];
    #pragma unroll
    for (int mf = 0; mf < 4; mf++)
      #pragma unroll
      for (int nf = 0; nf < 2; nf++)
        acc[mf][nf] = __builtin_amdgcn_mfma_f32_16x16x32_bf16(af[mf], bfr[nf], acc[mf][nf], 0, 0, 0);
  }

  float* Pp = P + (size_t)blockIdx.z * M * N;
  #pragma unroll
  for (int mf = 0; mf < 4; mf++) {
    #pragma unroll
    for (int nf = 0; nf < 2; nf++) {
      #pragma unroll
      for (int q = 0; q < 4; q++) {
        int gm = m0 + wm*64 + mf*16 + kg*4 + q;
        int gn = n0 + wn*32 + nf*16 + r;
        if (gm < M && gn < N)
          Pp[(size_t)gm * N + gn] = acc[mf][nf][q];
      }
    }
  }
}

// reduce partials; STACK: rows M/2.. go to cols N.. (fc_g2 branch packing)
template<int FLAGS, bool STACK>
__global__ void reduce_kernel(const float* __restrict__ P, float* __restrict__ C,
                              const float* __restrict__ bias, int M, int N, int S, int ldc)
{
  int i = blockIdx.x * 256 + threadIdx.x;
  if (i >= M * N) return;
  float v = 0.f;
  for (int s = 0; s < S; s++) v += P[(size_t)s * M * N + i];
  int row = i / N, col = i - row * N;
  if (FLAGS & 2) v += bias[col];
  if (FLAGS & 1) v = fmaxf(v, 0.f);
  if (STACK) { if (row >= (M >> 1)) { row -= (M >> 1); col += N; } }
  C[(size_t)row * ldc + col] = v;
}

// ---------------- CSR build ----------------
__global__ void count_kernel(const int* __restrict__ dst, int* __restrict__ cnt, int E) {
  int e = blockIdx.x * 256 + threadIdx.x;
  if (e < E) atomicAdd(&cnt[dst[e]], 1);
}

__global__ void bsum_kernel(const int* __restrict__ cnt, int* __restrict__ bsum, int n) {
  __shared__ int wp[4];
  int tid = threadIdx.x, lane = tid & 63, wid = tid >> 6;
  int i = blockIdx.x * 256 + tid;
  int v = (i < n) ? cnt[i] : 0;
  #pragma unroll
  for (int off = 32; off >= 1; off >>= 1) v += __shfl_xor(v, off, 64);
  if (lane == 0) wp[wid] = v;
  __syncthreads();
  if (tid == 0) bsum[blockIdx.x] = wp[0] + wp[1] + wp[2] + wp[3];
}

__global__ void bscan_kernel(int* __restrict__ bsum, int nb) {
  __shared__ int wp[4];
  int tid = threadIdx.x, lane = tid & 63, wid = tid >> 6;
  int v = (tid < nb) ? bsum[tid] : 0;
  int xv = v;
  #pragma unroll
  for (int off = 1; off < 64; off <<= 1) {
    int y = __shfl_up(xv, off, 64);
    if (lane >= off) xv += y;
  }
  if (lane == 63) wp[wid] = xv;
  __syncthreads();
  if (tid == 0) { int s = 0; for (int k = 0; k < 4; k++) { int t = wp[k]; wp[k] = s; s += t; } }
  __syncthreads();
  if (tid < nb) bsum[tid] = wp[wid] + xv - v;   // exclusive
}

__global__ void rpfill_kernel(const int* __restrict__ cnt, const int* __restrict__ bsum,
                              int* __restrict__ rp, float* __restrict__ dinv, int n, int E) {
  __shared__ int wp[4];
  int tid = threadIdx.x, lane = tid & 63, wid = tid >> 6;
  int i = blockIdx.x * 256 + tid;
  int v = (i < n) ? cnt[i] : 0;
  int xv = v;
  #pragma unroll
  for (int off = 1; off < 64; off <<= 1) {
    int y = __shfl_up(xv, off, 64);
    if (lane >= off) xv += y;
  }
  if (lane == 63) wp[wid] = xv;
  __syncthreads();
  if (tid == 0) { int s = 0; for (int k = 0; k < 4; k++) { int t = wp[k]; wp[k] = s; s += t; } }
  __syncthreads();
  if (i < n) {
    rp[i] = bsum[blockIdx.x] + wp[wid] + xv - v;
    dinv[i] = rsqrtf((float)(v + 1));
  }
  if (blockIdx.x == 0 && tid == 0) rp[n] = E;
}

__global__ void fill_kernel(const int* __restrict__ src, const int* __restrict__ dst,
                            const int* __restrict__ rp, int* __restrict__ fil,
                            int* __restrict__ csr, int E) {
  int e = blockIdx.x * 256 + threadIdx.x;
  if (e < E) {
    int d = dst[e];
    int pos = rp[d] + atomicAdd(&fil[d], 1);
    csr[pos] = src[e];
  }
}

// ---------------- GCN aggregate (wave/node, 40-lane bf16x8 loads) ----------
__global__ void gcn_agg_kernel(const __bf16* __restrict__ h, const int* __restrict__ rp,
                               const int* __restrict__ csr, const float* __restrict__ dinv,
                               const float* __restrict__ bias, __bf16* __restrict__ out, int n)
{
  const int lane = threadIdx.x & 63;
  const int v = blockIdx.x * 4 + (threadIdx.x >> 6);
  if (v >= n) return;
  const bool act = lane < 40;
  const float dv = dinv[v];
  const int e0 = rp[v], e1 = rp[v + 1];
  float acc[8], bia[8];
  if (act) {
    bf16x8 hv = *(const bf16x8*)(h + (size_t)v * FDIM + 8 * lane);
    const float4* bp = (const float4*)(bias + 8 * lane);
    float4 b0 = bp[0], b1 = bp[1];
    bia[0]=b0.x; bia[1]=b0.y; bia[2]=b0.z; bia[3]=b0.w;
    bia[4]=b1.x; bia[5]=b1.y; bia[6]=b1.z; bia[7]=b1.w;
    #pragma unroll
    for (int j = 0; j < 8; j++) acc[j] = dv * (float)hv[j];
  }
  for (int base = e0; base < e1; base += 64) {
    int nn = min(64, e1 - base);
    int s_l = (lane < nn) ? csr[base + lane] : 0;
    float d_l = (lane < nn) ? dinv[s_l] : 0.f;
    for (int j2 = 0; j2 < nn; j2++) {
      int sj = __shfl(s_l, j2, 64);
      float cj = __shfl(d_l, j2, 64);
      if (act) {
        bf16x8 hv = *(const bf16x8*)(h + (size_t)sj * FDIM + 8 * lane);
        #pragma unroll
        for (int j = 0; j < 8; j++) acc[j] += cj * (float)hv[j];
      }
    }
  }
  if (act) {
    bf16x8 o;
    #pragma unroll
    for (int j = 0; j < 8; j++) o[j] = (__bf16)fmaxf(dv * acc[j] + bia[j], 0.f);
    *(bf16x8*)(out + (size_t)v * FDIM + 8 * lane) = o;
  }
}

__device__ __forceinline__ float lrelu(float x) { return x > 0.f ? x : 0.2f * x; }

// ---- online segment softmax stats: one pass; writes m, 1/den, aself -------
__global__ void mdenom3_kernel(const int* __restrict__ rp, const int* __restrict__ csr,
                               const float* __restrict__ as_, const float* __restrict__ ad_,
                               float* __restrict__ minv, float* __restrict__ invden,
                               float* __restrict__ aself, int n)
{
  int tid = blockIdx.x * 256 + threadIdx.x;
  if (tid >= n * NHEADS) return;
  int v = tid / NHEADS, t = tid - v * NHEADS;
  int e0 = rp[v], e1 = rp[v + 1];
  float adv = ad_[tid];
  float esf = lrelu(as_[tid] + adv);
  float m = esf, den = 1.f;
  for (int e = e0; e < e1; e++) {
    int s = csr[e];
    float ev = lrelu(as_[s * NHEADS + t] + adv);
    float nm = fmaxf(m, ev);
    den = den * __expf(m - nm) + __expf(ev - nm);
    m = nm;
  }
  float inv = 1.f / den;
  minv[tid] = m;
  invden[tid] = inv;
  aself[tid] = __expf(esf - m) * inv;
}

// -------- GAT aggregate: per-chunk LDS alpha staging + 40-lane wide loads --
__global__ void gat_agg_kernel(const __bf16* __restrict__ h, const int* __restrict__ rp,
                               const int* __restrict__ csr, const float* __restrict__ as_,
                               const float* __restrict__ ad_, const float* __restrict__ minv,
                               const float* __restrict__ invden, const float* __restrict__ aself,
                               const float* __restrict__ bias, __bf16* __restrict__ out, int n)
{
  __shared__ float alds[4][64][11];   // per-wave alpha tile (stride 11: 2-way alias, free)
  const int lane = threadIdx.x & 63;
  const int wid = threadIdx.x >> 6;
  const int v = blockIdx.x * 4 + wid;
  if (v >= n) return;
  const bool act = lane < 40;
  const int hl = lane >> 2;           // head of channels 8*lane..8*lane+7
  const int e0 = rp[v], e1 = rp[v + 1];

  // per-node per-head params in regs (every lane holds all 10)
  float adv[NHEADS], mm[NHEADS], iv[NHEADS];
  {
    const float* adp = ad_ + (size_t)v * NHEADS;
    const float* mp  = minv + (size_t)v * NHEADS;
    const float* ip  = invden + (size_t)v * NHEADS;
    #pragma unroll
    for (int t = 0; t < NHEADS; t++) { adv[t] = adp[t]; mm[t] = mp[t]; iv[t] = ip[t]; }
  }

  float acc[8], bia[8];
  if (act) {
    float aslf = aself[v * NHEADS + hl];
    bf16x8 hv = *(const bf16x8*)(h + (size_t)v * FDIM + 8 * lane);
    const float4* bp = (const float4*)(bias + 8 * lane);
    float4 b0 = bp[0], b1 = bp[1];
    bia[0]=b0.x; bia[1]=b0.y; bia[2]=b0.z; bia[3]=b0.w;
    bia[4]=b1.x; bia[5]=b1.y; bia[6]=b1.z; bia[7]=b1.w;
    #pragma unroll
    for (int j = 0; j < 8; j++) acc[j] = aslf * (float)hv[j];
  }

  for (int base = e0; base < e1; base += 64) {
    int nn = min(64, e1 - base);
    int s_l = (lane < nn) ? csr[base + lane] : 0;
    // stage: lane computes all 10 alphas for its edge (wave-parallel exps)
    if (lane < nn) {
      float av[NHEADS];
      const float2* ap2 = (const float2*)(as_ + (size_t)s_l * NHEADS);
      #pragma unroll
      for (int q = 0; q < 5; q++) { float2 u = ap2[q]; av[2*q] = u.x; av[2*q+1] = u.y; }
      #pragma unroll
      for (int t = 0; t < NHEADS; t++)
        alds[wid][lane][t] = __expf(lrelu(av[t] + adv[t]) - mm[t]) * iv[t];
    }
    // consume: one dependent gather (h row) per edge; alpha from LDS
    for (int j2 = 0; j2 < nn; j2++) {
      int sj = __shfl(s_l, j2, 64);
      if (act) {
        float al = alds[wid][j2][hl];
        bf16x8 hv = *(const bf16x8*)(h + (size_t)sj * FDIM + 8 * lane);
        #pragma unroll
        for (int j = 0; j < 8; j++) acc[j] += al * (float)hv[j];
      }
    }
  }
  if (act) {
    bf16x8 o;
    #pragma unroll
    for (int j = 0; j < 8; j++) o[j] = (__bf16)fmaxf(acc[j] + bia[j], 0.f);
    *(bf16x8*)(out + (size_t)v * FDIM + 8 * lane) = o;
  }
}

// ---------------- batch boundaries + pooling ----------------
__global__ void bstart_kernel(const int* __restrict__ batch, int* __restrict__ bstart,
                              int n, int B_) {
  int v = blockIdx.x * 256 + threadIdx.x;
  if (v > n) return;
  int bv = (v < n) ? batch[v] : B_;
  int bp = (v == 0) ? -1 : batch[v - 1];
  for (int gg = bp + 1; gg <= bv; gg++) bstart[gg] = v;
}

__global__ void pool_kernel(const __bf16* __restrict__ xin, const int* __restrict__ bstart,
                            float* __restrict__ g) {
  int gid = blockIdx.x;
  int c = blockIdx.y * 64 + threadIdx.x;
  int s = bstart[gid], e = bstart[gid + 1];
  float mx = -__builtin_inff(), sm = 0.f;
  for (int v = s; v < e; v++) {
    float val = (float)xin[(size_t)v * FDIM + c];
    mx = fmaxf(mx, val);
    sm += val;
  }
  float cntf = (float)(e - s);
  g[gid * (2 * FDIM) + c] = mx;
  g[gid * (2 * FDIM) + FDIM + c] = sm / fmaxf(cntf, 1.f);
}

// ---------------- launch ----------------
extern "C" void kernel_launch(void* const* d_in, const int* in_sizes, int n_in,
                              void* d_out, int out_size, void* d_ws, size_t ws_size,
                              hipStream_t stream)
{
  const int N = in_sizes[0] / FDIM;
  const int E = in_sizes[2] / 2;
  const int NB = (N + 255) / 256;

  const float* x[2]   = {(const float*)d_in[0], (const float*)d_in[1]};
  const int*   ei[2]  = {(const int*)d_in[2], (const int*)d_in[3]};
  const int*   bat[2] = {(const int*)d_in[4], (const int*)d_in[5]};
  const float* W_gcn   = (const float*)d_in[6];
  const float* b_gcn   = (const float*)d_in[7];
  const float* W_gat   = (const float*)d_in[8];
  const float* att_src = (const float*)d_in[9];
  const float* att_dst = (const float*)d_in[10];
  const float* b_gat   = (const float*)d_in[11];
  const float* W_fc_g1 = (const float*)d_in[12];
  const float* b_fc_g1 = (const float*)d_in[13];
  const float* W_fc_g2 = (const float*)d_in[14];
  const float* b_fc_g2 = (const float*)d_in[15];
  const float* W_fc1   = (const float*)d_in[16];
  const float* b_fc1   = (const float*)d_in[17];
  const float* W_fc2   = (const float*)d_in[18];
  const float* b_fc2   = (const float*)d_in[19];
  const float* W_out   = (const float*)d_in[20];
  const float* b_out   = (const float*)d_in[21];
  float* outp = (float*)d_out;

  char* ws = (char*)d_ws;
  size_t off = 0;
  auto alloc = [&](size_t bytes) -> char* {
    char* p = ws + off;
    off += (bytes + 255) & ~(size_t)255;
    return p;
  };
  int*    cnt    = (int*)alloc((size_t)N * 4);
  int*    fil    = (int*)alloc((size_t)N * 4);
  size_t  zero_span = (size_t)((char*)fil - (char*)cnt) + ((size_t)N * 4 + 255 & ~(size_t)255);
  int*    rp     = (int*)alloc((size_t)(N + 1) * 4);
  int*    bsum   = (int*)alloc((size_t)NB * 4);
  int*    csr    = (int*)alloc((size_t)E * 4);
  float*  dinv   = (float*)alloc((size_t)N * 4);
  int*    bstart = (int*)alloc((size_t)(NGR + 1) * 4);
  __bf16* WgcnT  = (__bf16*)alloc((size_t)FDIM * FDIM * 2);
  __bf16* WgatT  = (__bf16*)alloc((size_t)FDIM * FDIM * 2);
  __bf16* hbuf   = (__bf16*)alloc((size_t)N * FDIM * 2);
  __bf16* xbuf   = (__bf16*)alloc((size_t)N * FDIM * 2);
  float*  as_    = (float*)alloc((size_t)N * NHEADS * 4);
  float*  ad_    = (float*)alloc((size_t)N * NHEADS * 4);
  float*  minv   = (float*)alloc((size_t)N * NHEADS * 4);
  float*  invden = (float*)alloc((size_t)N * NHEADS * 4);
  float*  aself  = (float*)alloc((size_t)N * NHEADS * 4);
  float*  g      = (float*)alloc((size_t)2 * NGR * 2 * FDIM * 4);   // both branches
  float*  t1     = (float*)alloc((size_t)2 * NGR * 1500 * 4);       // both branches
  float*  xc     = (float*)alloc((size_t)NGR * 256 * 4);
  float*  t2     = (float*)alloc((size_t)NGR * 1024 * 4);
  float*  t3     = (float*)alloc((size_t)NGR * 512 * 4);
  float*  part   = (float*)alloc((size_t)8 * 512 * 512 * 4);        // split-K partials (8 MB)
  if (off > ws_size) return;  // workspace too small: bail (visible as absmax fail)

  wconv2_kernel<<<2 * (FDIM * FDIM) / 256, 256, 0, stream>>>(W_gcn, W_gat, WgcnT, WgatT);

  for (int br = 0; br < 2; br++) {
    hipMemsetAsync(cnt, 0, zero_span, stream);
    const int* srcp = ei[br];
    const int* dstp = ei[br] + E;
    count_kernel<<<(E + 255) / 256, 256, 0, stream>>>(dstp, cnt, E);
    bsum_kernel<<<NB, 256, 0, stream>>>(cnt, bsum, N);
    bscan_kernel<<<1, 256, 0, stream>>>(bsum, NB);
    rpfill_kernel<<<NB, 256, 0, stream>>>(cnt, bsum, rp, dinv, N, E);
    fill_kernel<<<(E + 255) / 256, 256, 0, stream>>>(srcp, dstp, rp, fil, csr, E);

    int g320 = (N + 63) / 64;
    gemm320v3_kernel<float, false><<<g320, 256, 0, stream>>>(
        x[br], WgcnT, hbuf, N, nullptr, nullptr, nullptr, nullptr);
    gcn_agg_kernel<<<(N + 3) / 4, 256, 0, stream>>>(hbuf, rp, csr, dinv, b_gcn, xbuf, N);
    gemm320v3_kernel<__bf16, true><<<g320, 256, 0, stream>>>(
        xbuf, WgatT, hbuf, N, att_src, att_dst, as_, ad_);

    mdenom3_kernel<<<(N * NHEADS + 255) / 256, 256, 0, stream>>>(rp, csr, as_, ad_, minv, invden, aself, N);
    gat_agg_kernel<<<(N + 3) / 4, 256, 0, stream>>>(hbuf, rp, csr, as_, ad_, minv, invden, aself, b_gat, xbuf, N);

    bstart_kernel<<<(N + 256) / 256, 256, 0, stream>>>(bat[br], bstart, N, NGR);
    dim3 gpool(NGR, FDIM / 64);
    pool_kernel<<<gpool, 64, 0, stream>>>(xbuf, bstart, g + (size_t)br * NGR * 2 * FDIM);
  }

  // ---- batched FC head: M=512 covers both branches ----
  {
    dim3 gfc1((512 + BM - 1) / BM, (1500 + BN - 1) / BN);
    gemm_bf16_kernel<3><<<gfc1, 256, 0, stream>>>(g, W_fc_g1, t1, b_fc_g1, 512, 1500, 2 * FDIM, 1500);
    int S = 8, KS = ((1500 + S * BK - 1) / (S * BK)) * BK;
    dim3 gfc2((512 + BM - 1) / BM, (128 + BN - 1) / BN, S);
    gemm_splitk_kernel<<<gfc2, 256, 0, stream>>>(t1, W_fc_g2, part, 512, 128, 1500, KS);
    reduce_kernel<2, true><<<(512 * 128 + 255) / 256, 256, 0, stream>>>(part, xc, b_fc_g2, 512, 128, S, 256);
  }
  {
    dim3 gx1((NGR + BM - 1) / BM, (1024 + BN - 1) / BN);
    gemm_bf16_kernel<3><<<gx1, 256, 0, stream>>>(xc, W_fc1, t2, b_fc1, NGR, 1024, 256, 1024);
    int S = 4, KS = ((1024 + S * BK - 1) / (S * BK)) * BK;
    dim3 gx2((NGR + BM - 1) / BM, (512 + BN - 1) / BN, S);
    gemm_splitk_kernel<<<gx2, 256, 0, stream>>>(t2, W_fc2, part, NGR, 512, 1024, KS);
    reduce_kernel<3, false><<<(NGR * 512 + 255) / 256, 256, 0, stream>>>(part, t3, b_fc2, NGR, 512, S, 512);
    int S2 = 4, KS2 = ((512 + S2 * BK - 1) / (S2 * BK)) * BK;
    dim3 gx3((NGR + BM - 1) / BM, 1, S2);
    gemm_splitk_kernel<<<gx3, 256, 0, stream>>>(t3, W_out, part, NGR, 2, 512, KS2);
    reduce_kernel<2, false><<<(NGR * 2 + 255) / 256, 256, 0, stream>>>(part, outp, b_out, NGR, 2, S2, 2);
  }
}

// Round 11
// 724.697 us; speedup vs baseline: 1.0345x; 1.0345x over previous
//
#include <hip/hip_runtime.h>
#include <type_traits>

#define FDIM 320
#define NHEADS 10
#define NGR 256

typedef __bf16 bf16x8 __attribute__((ext_vector_type(8)));
typedef float f32x4 __attribute__((ext_vector_type(4)));

// ---------------- weight transpose+convert (both weights, one launch) ------
__global__ void wconv2_kernel(const float* __restrict__ Wg, const float* __restrict__ Wa,
                              __bf16* __restrict__ Tg, __bf16* __restrict__ Ta) {
  int idx = blockIdx.x * 256 + threadIdx.x;
  bool first = idx < FDIM * FDIM;
  const float* W = first ? Wg : Wa;
  __bf16* T = first ? Tg : Ta;
  int i2 = first ? idx : idx - FDIM * FDIM;
  int k = i2 / FDIM, c = i2 - k * FDIM;
  T[c * FDIM + k] = (__bf16)W[i2];
}

// ---------------- node GEMM v3: full-N, BK=32, LDS dbuf, async reg-stage ---
#define GLSTR 40

template<typename TA, bool SCORES>
__global__ __launch_bounds__(256, 2) void gemm320v3_kernel(
    const TA* __restrict__ A, const __bf16* __restrict__ Wt,
    __bf16* __restrict__ C, int M,
    const float* __restrict__ att_s, const float* __restrict__ att_d,
    float* __restrict__ as_, float* __restrict__ ad_)
{
  __shared__ __bf16 As[2][64 * GLSTR];
  __shared__ __bf16 Bs[2][320 * GLSTR];

  const int tid = threadIdx.x;
  const int lane = tid & 63;
  const int w = tid >> 6;
  const int wr = w >> 1, wc = w & 1;
  const int r = lane & 15, kg = lane >> 4;
  const int m0 = blockIdx.x * 64;

  const int brow = tid >> 2, bq = tid & 3;
  const int gmrow = m0 + brow;
  const bool arow_ok = gmrow < M;

  bf16x8 bstg[5];
  bf16x8 astg;
  float4 af32a, af32b;

  auto stage_load = [&](int k0) {
    #pragma unroll
    for (int i = 0; i < 5; i++) {
      int ch = tid + i * 256;
      int col = ch >> 2, kc = ch & 3;
      bstg[i] = *(const bf16x8*)(Wt + (size_t)col * FDIM + k0 + kc * 8);
    }
    if constexpr (std::is_same_v<TA, float>) {
      if (arow_ok) {
        const float4* ap = (const float4*)(A + (size_t)gmrow * FDIM + k0 + bq * 8);
        af32a = ap[0]; af32b = ap[1];
      }
    } else {
      if (arow_ok) astg = *(const bf16x8*)(A + (size_t)gmrow * FDIM + k0 + bq * 8);
    }
  };
  auto stage_write = [&](int b) {
    #pragma unroll
    for (int i = 0; i < 5; i++) {
      int ch = tid + i * 256;
      int col = ch >> 2, kc = ch & 3;
      *(bf16x8*)&Bs[b][col * GLSTR + kc * 8] = bstg[i];
    }
    bf16x8 v = {};
    if constexpr (std::is_same_v<TA, float>) {
      if (arow_ok) {
        v[0]=(__bf16)af32a.x; v[1]=(__bf16)af32a.y; v[2]=(__bf16)af32a.z; v[3]=(__bf16)af32a.w;
        v[4]=(__bf16)af32b.x; v[5]=(__bf16)af32b.y; v[6]=(__bf16)af32b.z; v[7]=(__bf16)af32b.w;
      }
    } else {
      if (arow_ok) v = astg;
    }
    *(bf16x8*)&As[b][brow * GLSTR + bq * 8] = v;
  };

  f32x4 acc0[10], acc1[10];
  #pragma unroll
  for (int i = 0; i < 10; i++) { acc0[i] = (f32x4){0,0,0,0}; acc1[i] = (f32x4){0,0,0,0}; }

  stage_load(0);
  stage_write(0);
  __syncthreads();

  int cur = 0;
  for (int k = 0; k < 10; k++) {
    if (k < 9) stage_load((k + 1) * 32);
    {
      bf16x8 a0 = *(const bf16x8*)&As[cur][(wr*32 + r)      * GLSTR + kg*8];
      bf16x8 a1 = *(const bf16x8*)&As[cur][(wr*32 + 16 + r) * GLSTR + kg*8];
      #pragma unroll
      for (int nf = 0; nf < 10; nf++) {
        bf16x8 b = *(const bf16x8*)&Bs[cur][(wc*160 + nf*16 + r) * GLSTR + kg*8];
        acc0[nf] = __builtin_amdgcn_mfma_f32_16x16x32_bf16(a0, b, acc0[nf], 0, 0, 0);
        acc1[nf] = __builtin_amdgcn_mfma_f32_16x16x32_bf16(a1, b, acc1[nf], 0, 0, 0);
      }
    }
    if (k < 9) {
      stage_write(cur ^ 1);
      __syncthreads();
      cur ^= 1;
    }
  }

  // ---- store C ----
  #pragma unroll
  for (int nf = 0; nf < 10; nf++) {
    int gn = wc*160 + nf*16 + r;
    #pragma unroll
    for (int q = 0; q < 4; q++) {
      int gm0 = m0 + wr*32 + kg*4 + q;
      if (gm0 < M)       C[(size_t)gm0 * FDIM + gn] = (__bf16)acc0[nf][q];
      int gm1 = gm0 + 16;
      if (gm1 < M)       C[(size_t)gm1 * FDIM + gn] = (__bf16)acc1[nf][q];
    }
  }

  // ---- fused GAT scores ----
  if constexpr (SCORES) {
    #pragma unroll
    for (int th = 0; th < 5; th++) {
      int t = wc * 5 + th;
      float s0 = att_s[t*32 + r],      s1 = att_s[t*32 + 16 + r];
      float d0 = att_d[t*32 + r],      d1 = att_d[t*32 + 16 + r];
      #pragma unroll
      for (int q = 0; q < 4; q++) {
        float ps0 = acc0[2*th][q]*s0 + acc0[2*th+1][q]*s1;
        float ps1 = acc1[2*th][q]*s0 + acc1[2*th+1][q]*s1;
        float pd0 = acc0[2*th][q]*d0 + acc0[2*th+1][q]*d1;
        float pd1 = acc1[2*th][q]*d0 + acc1[2*th+1][q]*d1;
        #pragma unroll
        for (int off = 1; off < 16; off <<= 1) {
          ps0 += __shfl_xor(ps0, off, 16);
          ps1 += __shfl_xor(ps1, off, 16);
          pd0 += __shfl_xor(pd0, off, 16);
          pd1 += __shfl_xor(pd1, off, 16);
        }
        if (r == 0) {
          int row0 = m0 + wr*32 + kg*4 + q;
          if (row0 < M) { as_[row0*NHEADS + t] = ps0; ad_[row0*NHEADS + t] = pd0; }
          int row1 = row0 + 16;
          if (row1 < M) { as_[row1*NHEADS + t] = ps1; ad_[row1*NHEADS + t] = pd1; }
        }
      }
    }
  }
}

// ---------------- generic GEMM (FC layers): C = A*B, f32 in/out ------------
#define BM 128
#define BN 64
#define BK 32
#define LSTR 56

template<int FLAGS>  // bit0: relu, bit1: bias
__global__ __launch_bounds__(256) void gemm_bf16_kernel(
    const float* __restrict__ A, const float* __restrict__ B,
    float* __restrict__ C, const float* __restrict__ bias,
    int M, int N, int K, int ldc)
{
  __shared__ __bf16 As[BM * LSTR];
  __shared__ __bf16 Bs[BN * LSTR];

  const int tid = threadIdx.x;
  const int lane = tid & 63;
  const int w = tid >> 6;
  const int wm = w >> 1, wn = w & 1;
  const int r = lane & 15, kg = lane >> 4;
  const int m0 = blockIdx.x * BM, n0 = blockIdx.y * BN;

  f32x4 acc[4][2];
  #pragma unroll
  for (int i = 0; i < 4; i++)
    #pragma unroll
    for (int j = 0; j < 2; j++)
      acc[i][j] = (f32x4){0.f, 0.f, 0.f, 0.f};

  const int arow = tid >> 1, ahalf = tid & 1;
  const int bk = tid >> 3, bn = (tid & 7) * 8;

  for (int k0 = 0; k0 < K; k0 += BK) {
    __syncthreads();
    {
      int gm = m0 + arow;
      int kbase = k0 + ahalf * 16;
      float tmp[16];
      if (gm < M && kbase + 16 <= K) {
        const float4* ap = (const float4*)(A + (size_t)gm * K + kbase);
        #pragma unroll
        for (int q = 0; q < 4; q++) {
          float4 v = ap[q];
          tmp[q*4+0] = v.x; tmp[q*4+1] = v.y; tmp[q*4+2] = v.z; tmp[q*4+3] = v.w;
        }
      } else {
        #pragma unroll
        for (int q = 0; q < 16; q++) {
          int kk = kbase + q;
          tmp[q] = (gm < M && kk < K) ? A[(size_t)gm * K + kk] : 0.f;
        }
      }
      bf16x8 v0, v1;
      #pragma unroll
      for (int q = 0; q < 8; q++) { v0[q] = (__bf16)tmp[q]; v1[q] = (__bf16)tmp[q+8]; }
      bf16x8* dp = (bf16x8*)&As[arow * LSTR + ahalf * 16];
      dp[0] = v0; dp[1] = v1;
    }
    {
      int gk = k0 + bk;
      float tb[8];
      if (gk < K && n0 + bn + 8 <= N) {
        const float4* bp = (const float4*)(B + (size_t)gk * N + n0 + bn);
        float4 u0 = bp[0], u1 = bp[1];
        tb[0]=u0.x; tb[1]=u0.y; tb[2]=u0.z; tb[3]=u0.w;
        tb[4]=u1.x; tb[5]=u1.y; tb[6]=u1.z; tb[7]=u1.w;
      } else {
        #pragma unroll
        for (int q = 0; q < 8; q++) {
          int gn = n0 + bn + q;
          tb[q] = (gk < K && gn < N) ? B[(size_t)gk * N + gn] : 0.f;
        }
      }
      #pragma unroll
      for (int q = 0; q < 8; q++) Bs[(bn + q) * LSTR + bk] = (__bf16)tb[q];
    }
    __syncthreads();
    bf16x8 af[4], bfr[2];
    #pragma unroll
    for (int mf = 0; mf < 4; mf++)
      af[mf] = *(const bf16x8*)&As[(wm*64 + mf*16 + r) * LSTR + kg*8];
    #pragma unroll
    for (int nf = 0; nf < 2; nf++)
      bfr[nf] = *(const bf16x8*)&Bs[(wn*32 + nf*16 + r) * LSTR + kg*8];
    #pragma unroll
    for (int mf = 0; mf < 4; mf++)
      #pragma unroll
      for (int nf = 0; nf < 2; nf++)
        acc[mf][nf] = __builtin_amdgcn_mfma_f32_16x16x32_bf16(af[mf], bfr[nf], acc[mf][nf], 0, 0, 0);
  }

  #pragma unroll
  for (int mf = 0; mf < 4; mf++) {
    #pragma unroll
    for (int nf = 0; nf < 2; nf++) {
      #pragma unroll
      for (int q = 0; q < 4; q++) {
        int gm = m0 + wm*64 + mf*16 + kg*4 + q;
        int gn = n0 + wn*32 + nf*16 + r;
        if (gm < M && gn < N) {
          float v = acc[mf][nf][q];
          if (FLAGS & 2) v += bias[gn];
          if (FLAGS & 1) v = fmaxf(v, 0.f);
          C[(size_t)gm * ldc + gn] = v;
        }
      }
    }
  }
}

// ---------------- split-K GEMM: P[s][M][N] partials ----------------
__global__ __launch_bounds__(256) void gemm_splitk_kernel(
    const float* __restrict__ A, const float* __restrict__ B,
    float* __restrict__ P, int M, int N, int K, int KS)
{
  __shared__ __bf16 As[BM * LSTR];
  __shared__ __bf16 Bs[BN * LSTR];

  const int tid = threadIdx.x;
  const int lane = tid & 63;
  const int w = tid >> 6;
  const int wm = w >> 1, wn = w & 1;
  const int r = lane & 15, kg = lane >> 4;
  const int m0 = blockIdx.x * BM, n0 = blockIdx.y * BN;
  const int kstart = blockIdx.z * KS;
  const int kend = min(K, kstart + KS);

  f32x4 acc[4][2];
  #pragma unroll
  for (int i = 0; i < 4; i++)
    #pragma unroll
    for (int j = 0; j < 2; j++)
      acc[i][j] = (f32x4){0.f, 0.f, 0.f, 0.f};

  const int arow = tid >> 1, ahalf = tid & 1;
  const int bk = tid >> 3, bn = (tid & 7) * 8;

  for (int k0 = kstart; k0 < kend; k0 += BK) {
    __syncthreads();
    {
      int gm = m0 + arow;
      int kbase = k0 + ahalf * 16;
      float tmp[16];
      if (gm < M && kbase + 16 <= kend) {
        const float4* ap = (const float4*)(A + (size_t)gm * K + kbase);
        #pragma unroll
        for (int q = 0; q < 4; q++) {
          float4 v = ap[q];
          tmp[q*4+0] = v.x; tmp[q*4+1] = v.y; tmp[q*4+2] = v.z; tmp[q*4+3] = v.w;
        }
      } else {
        #pragma unroll
        for (int q = 0; q < 16; q++) {
          int kk = kbase + q;
          tmp[q] = (gm < M && kk < kend) ? A[(size_t)gm * K + kk] : 0.f;
        }
      }
      bf16x8 v0, v1;
      #pragma unroll
      for (int q = 0; q < 8; q++) { v0[q] = (__bf16)tmp[q]; v1[q] = (__bf16)tmp[q+8]; }
      bf16x8* dp = (bf16x8*)&As[arow * LSTR + ahalf * 16];
      dp[0] = v0; dp[1] = v1;
    }
    {
      int gk = k0 + bk;
      float tb[8];
      if (gk < kend && n0 + bn + 8 <= N) {
        const float4* bp = (const float4*)(B + (size_t)gk * N + n0 + bn);
        float4 u0 = bp[0], u1 = bp[1];
        tb[0]=u0.x; tb[1]=u0.y; tb[2]=u0.z; tb[3]=u0.w;
        tb[4]=u1.x; tb[5]=u1.y; tb[6]=u1.z; tb[7]=u1.w;
      } else {
        #pragma unroll
        for (int q = 0; q < 8; q++) {
          int gn = n0 + bn + q;
          tb[q] = (gk < kend && gn < N) ? B[(size_t)gk * N + gn] : 0.f;
        }
      }
      #pragma unroll
      for (int q = 0; q < 8; q++) Bs[(bn + q) * LSTR + bk] = (__bf16)tb[q];
    }
    __syncthreads();
    bf16x8 af[4], bfr[2];
    #pragma unroll
    for (int mf = 0; mf < 4; mf++)
      af[mf] = *(const bf16x8*)&As[(wm*64 + mf*16 + r) * LSTR + kg*8];
    #pragma unroll
    for (int nf = 0; nf < 2; nf++)
      bfr[nf] = *(const bf16x8*)&Bs[(wn*32 + nf*16 + r) * LSTR + kg*8];
    #pragma unroll
    for (int mf = 0; mf < 4; mf++)
      #pragma unroll
      for (int nf = 0; nf < 2; nf++)
        acc[mf][nf] = __builtin_amdgcn_mfma_f32_16x16x32_bf16(af[mf], bfr[nf], acc[mf][nf], 0, 0, 0);
  }

  float* Pp = P + (size_t)blockIdx.z * M * N;
  #pragma unroll
  for (int mf = 0; mf < 4; mf++) {
    #pragma unroll
    for (int nf = 0; nf < 2; nf++) {
      #pragma unroll
      for (int q = 0; q < 4; q++) {
        int gm = m0 + wm*64 + mf*16 + kg*4 + q;
        int gn = n0 + wn*32 + nf*16 + r;
        if (gm < M && gn < N)
          Pp[(size_t)gm * N + gn] = acc[mf][nf][q];
      }
    }
  }
}

// reduce partials; STACK: rows M/2.. go to cols N.. (fc_g2 branch packing)
template<int FLAGS, bool STACK>
__global__ void reduce_kernel(const float* __restrict__ P, float* __restrict__ C,
                              const float* __restrict__ bias, int M, int N, int S, int ldc)
{
  int i = blockIdx.x * 256 + threadIdx.x;
  if (i >= M * N) return;
  float v = 0.f;
  for (int s = 0; s < S; s++) v += P[(size_t)s * M * N + i];
  int row = i / N, col = i - row * N;
  if (FLAGS & 2) v += bias[col];
  if (FLAGS & 1) v = fmaxf(v, 0.f);
  if (STACK) { if (row >= (M >> 1)) { row -= (M >> 1); col += N; } }
  C[(size_t)row * ldc + col] = v;
}

// ---------------- CSR build ----------------
__global__ void count_kernel(const int* __restrict__ dst, int* __restrict__ cnt, int E) {
  int e = blockIdx.x * 256 + threadIdx.x;
  if (e < E) atomicAdd(&cnt[dst[e]], 1);
}

__global__ void bsum_kernel(const int* __restrict__ cnt, int* __restrict__ bsum, int n) {
  __shared__ int wp[4];
  int tid = threadIdx.x, lane = tid & 63, wid = tid >> 6;
  int i = blockIdx.x * 256 + tid;
  int v = (i < n) ? cnt[i] : 0;
  #pragma unroll
  for (int off = 32; off >= 1; off >>= 1) v += __shfl_xor(v, off, 64);
  if (lane == 0) wp[wid] = v;
  __syncthreads();
  if (tid == 0) bsum[blockIdx.x] = wp[0] + wp[1] + wp[2] + wp[3];
}

__global__ void bscan_kernel(int* __restrict__ bsum, int nb) {
  __shared__ int wp[4];
  int tid = threadIdx.x, lane = tid & 63, wid = tid >> 6;
  int v = (tid < nb) ? bsum[tid] : 0;
  int xv = v;
  #pragma unroll
  for (int off = 1; off < 64; off <<= 1) {
    int y = __shfl_up(xv, off, 64);
    if (lane >= off) xv += y;
  }
  if (lane == 63) wp[wid] = xv;
  __syncthreads();
  if (tid == 0) { int s = 0; for (int k = 0; k < 4; k++) { int t = wp[k]; wp[k] = s; s += t; } }
  __syncthreads();
  if (tid < nb) bsum[tid] = wp[wid] + xv - v;   // exclusive
}

__global__ void rpfill_kernel(const int* __restrict__ cnt, const int* __restrict__ bsum,
                              int* __restrict__ rp, float* __restrict__ dinv, int n, int E) {
  __shared__ int wp[4];
  int tid = threadIdx.x, lane = tid & 63, wid = tid >> 6;
  int i = blockIdx.x * 256 + tid;
  int v = (i < n) ? cnt[i] : 0;
  int xv = v;
  #pragma unroll
  for (int off = 1; off < 64; off <<= 1) {
    int y = __shfl_up(xv, off, 64);
    if (lane >= off) xv += y;
  }
  if (lane == 63) wp[wid] = xv;
  __syncthreads();
  if (tid == 0) { int s = 0; for (int k = 0; k < 4; k++) { int t = wp[k]; wp[k] = s; s += t; } }
  __syncthreads();
  if (i < n) {
    rp[i] = bsum[blockIdx.x] + wp[wid] + xv - v;
    dinv[i] = rsqrtf((float)(v + 1));
  }
  if (blockIdx.x == 0 && tid == 0) rp[n] = E;
}

__global__ void fill_kernel(const int* __restrict__ src, const int* __restrict__ dst,
                            const int* __restrict__ rp, int* __restrict__ fil,
                            int* __restrict__ csr, int E) {
  int e = blockIdx.x * 256 + threadIdx.x;
  if (e < E) {
    int d = dst[e];
    int pos = rp[d] + atomicAdd(&fil[d], 1);
    csr[pos] = src[e];
  }
}

// ------- GCN aggregate: 40-lane wide loads, 4-deep pipelined gather --------
__global__ void gcn_agg_kernel(const __bf16* __restrict__ h, const int* __restrict__ rp,
                               const int* __restrict__ csr, const float* __restrict__ dinv,
                               const float* __restrict__ bias, __bf16* __restrict__ out, int n)
{
  const int lane = threadIdx.x & 63;
  const int v = blockIdx.x * 4 + (threadIdx.x >> 6);
  if (v >= n) return;
  const bool act = lane < 40;
  const float dv = dinv[v];
  const int e0 = rp[v], e1 = rp[v + 1];
  float acc[8], bia[8];
  if (act) {
    bf16x8 hv = *(const bf16x8*)(h + (size_t)v * FDIM + 8 * lane);
    const float4* bp = (const float4*)(bias + 8 * lane);
    float4 b0 = bp[0], b1 = bp[1];
    bia[0]=b0.x; bia[1]=b0.y; bia[2]=b0.z; bia[3]=b0.w;
    bia[4]=b1.x; bia[5]=b1.y; bia[6]=b1.z; bia[7]=b1.w;
    #pragma unroll
    for (int j = 0; j < 8; j++) acc[j] = dv * (float)hv[j];
  }
  for (int base = e0; base < e1; base += 64) {
    int nn = min(64, e1 - base);
    int s_l = (lane < nn) ? csr[base + lane] : 0;
    float d_l = (lane < nn) ? dinv[s_l] : 0.f;
    int j2 = 0;
    for (; j2 + 4 <= nn; j2 += 4) {
      int sj0 = __shfl(s_l, j2, 64),     sj1 = __shfl(s_l, j2 + 1, 64);
      int sj2 = __shfl(s_l, j2 + 2, 64), sj3 = __shfl(s_l, j2 + 3, 64);
      float c0 = __shfl(d_l, j2, 64),     c1 = __shfl(d_l, j2 + 1, 64);
      float c2 = __shfl(d_l, j2 + 2, 64), c3 = __shfl(d_l, j2 + 3, 64);
      if (act) {
        bf16x8 h0 = *(const bf16x8*)(h + (size_t)sj0 * FDIM + 8 * lane);
        bf16x8 h1 = *(const bf16x8*)(h + (size_t)sj1 * FDIM + 8 * lane);
        bf16x8 h2 = *(const bf16x8*)(h + (size_t)sj2 * FDIM + 8 * lane);
        bf16x8 h3 = *(const bf16x8*)(h + (size_t)sj3 * FDIM + 8 * lane);
        #pragma unroll
        for (int j = 0; j < 8; j++)
          acc[j] += c0 * (float)h0[j] + c1 * (float)h1[j]
                  + c2 * (float)h2[j] + c3 * (float)h3[j];
      }
    }
    for (; j2 < nn; j2++) {
      int sj = __shfl(s_l, j2, 64);
      float cj = __shfl(d_l, j2, 64);
      if (act) {
        bf16x8 hv = *(const bf16x8*)(h + (size_t)sj * FDIM + 8 * lane);
        #pragma unroll
        for (int j = 0; j < 8; j++) acc[j] += cj * (float)hv[j];
      }
    }
  }
  if (act) {
    bf16x8 o;
    #pragma unroll
    for (int j = 0; j < 8; j++) o[j] = (__bf16)fmaxf(dv * acc[j] + bia[j], 0.f);
    *(bf16x8*)(out + (size_t)v * FDIM + 8 * lane) = o;
  }
}

__device__ __forceinline__ float lrelu(float x) { return x > 0.f ? x : 0.2f * x; }

// ---- online segment softmax stats: one pass; writes m, 1/den, aself -------
__global__ void mdenom3_kernel(const int* __restrict__ rp, const int* __restrict__ csr,
                               const float* __restrict__ as_, const float* __restrict__ ad_,
                               float* __restrict__ minv, float* __restrict__ invden,
                               float* __restrict__ aself, int n)
{
  int tid = blockIdx.x * 256 + threadIdx.x;
  if (tid >= n * NHEADS) return;
  int v = tid / NHEADS, t = tid - v * NHEADS;
  int e0 = rp[v], e1 = rp[v + 1];
  float adv = ad_[tid];
  float esf = lrelu(as_[tid] + adv);
  float m = esf, den = 1.f;
  for (int e = e0; e < e1; e++) {
    int s = csr[e];
    float ev = lrelu(as_[s * NHEADS + t] + adv);
    float nm = fmaxf(m, ev);
    den = den * __expf(m - nm) + __expf(ev - nm);
    m = nm;
  }
  float inv = 1.f / den;
  minv[tid] = m;
  invden[tid] = inv;
  aself[tid] = __expf(esf - m) * inv;
}

// -- GAT aggregate: LDS alpha staging + 40-lane wide loads, 4-deep pipeline -
__global__ void gat_agg_kernel(const __bf16* __restrict__ h, const int* __restrict__ rp,
                               const int* __restrict__ csr, const float* __restrict__ as_,
                               const float* __restrict__ ad_, const float* __restrict__ minv,
                               const float* __restrict__ invden, const float* __restrict__ aself,
                               const float* __restrict__ bias, __bf16* __restrict__ out, int n)
{
  __shared__ float alds[4][64][11];   // per-wave alpha tile (stride 11: 2-way alias, free)
  const int lane = threadIdx.x & 63;
  const int wid = threadIdx.x >> 6;
  const int v = blockIdx.x * 4 + wid;
  if (v >= n) return;
  const bool act = lane < 40;
  const int hl = lane >> 2;           // head of channels 8*lane..8*lane+7
  const int e0 = rp[v], e1 = rp[v + 1];

  float adv[NHEADS], mm[NHEADS], iv[NHEADS];
  {
    const float* adp = ad_ + (size_t)v * NHEADS;
    const float* mp  = minv + (size_t)v * NHEADS;
    const float* ip  = invden + (size_t)v * NHEADS;
    #pragma unroll
    for (int t = 0; t < NHEADS; t++) { adv[t] = adp[t]; mm[t] = mp[t]; iv[t] = ip[t]; }
  }

  float acc[8], bia[8];
  if (act) {
    float aslf = aself[v * NHEADS + hl];
    bf16x8 hv = *(const bf16x8*)(h + (size_t)v * FDIM + 8 * lane);
    const float4* bp = (const float4*)(bias + 8 * lane);
    float4 b0 = bp[0], b1 = bp[1];
    bia[0]=b0.x; bia[1]=b0.y; bia[2]=b0.z; bia[3]=b0.w;
    bia[4]=b1.x; bia[5]=b1.y; bia[6]=b1.z; bia[7]=b1.w;
    #pragma unroll
    for (int j = 0; j < 8; j++) acc[j] = aslf * (float)hv[j];
  }

  for (int base = e0; base < e1; base += 64) {
    int nn = min(64, e1 - base);
    int s_l = (lane < nn) ? csr[base + lane] : 0;
    // stage: lane computes all 10 alphas for its edge (wave-parallel exps)
    if (lane < nn) {
      float av[NHEADS];
      const float2* ap2 = (const float2*)(as_ + (size_t)s_l * NHEADS);
      #pragma unroll
      for (int q = 0; q < 5; q++) { float2 u = ap2[q]; av[2*q] = u.x; av[2*q+1] = u.y; }
      #pragma unroll
      for (int t = 0; t < NHEADS; t++)
        alds[wid][lane][t] = __expf(lrelu(av[t] + adv[t]) - mm[t]) * iv[t];
    }
    // consume: 4-deep pipelined gathers; alpha from LDS
    int j2 = 0;
    for (; j2 + 4 <= nn; j2 += 4) {
      int sj0 = __shfl(s_l, j2, 64),     sj1 = __shfl(s_l, j2 + 1, 64);
      int sj2 = __shfl(s_l, j2 + 2, 64), sj3 = __shfl(s_l, j2 + 3, 64);
      if (act) {
        bf16x8 h0 = *(const bf16x8*)(h + (size_t)sj0 * FDIM + 8 * lane);
        bf16x8 h1 = *(const bf16x8*)(h + (size_t)sj1 * FDIM + 8 * lane);
        bf16x8 h2 = *(const bf16x8*)(h + (size_t)sj2 * FDIM + 8 * lane);
        bf16x8 h3 = *(const bf16x8*)(h + (size_t)sj3 * FDIM + 8 * lane);
        float a0 = alds[wid][j2][hl],     a1 = alds[wid][j2 + 1][hl];
        float a2 = alds[wid][j2 + 2][hl], a3 = alds[wid][j2 + 3][hl];
        #pragma unroll
        for (int j = 0; j < 8; j++)
          acc[j] += a0 * (float)h0[j] + a1 * (float)h1[j]
                  + a2 * (float)h2[j] + a3 * (float)h3[j];
      }
    }
    for (; j2 < nn; j2++) {
      int sj = __shfl(s_l, j2, 64);
      if (act) {
        float al = alds[wid][j2][hl];
        bf16x8 hv = *(const bf16x8*)(h + (size_t)sj * FDIM + 8 * lane);
        #pragma unroll
        for (int j = 0; j < 8; j++) acc[j] += al * (float)hv[j];
      }
    }
  }
  if (act) {
    bf16x8 o;
    #pragma unroll
    for (int j = 0; j < 8; j++) o[j] = (__bf16)fmaxf(acc[j] + bia[j], 0.f);
    *(bf16x8*)(out + (size_t)v * FDIM + 8 * lane) = o;
  }
}

// ---------------- batch boundaries + pooling ----------------
__global__ void bstart_kernel(const int* __restrict__ batch, int* __restrict__ bstart,
                              int n, int B_) {
  int v = blockIdx.x * 256 + threadIdx.x;
  if (v > n) return;
  int bv = (v < n) ? batch[v] : B_;
  int bp = (v == 0) ? -1 : batch[v - 1];
  for (int gg = bp + 1; gg <= bv; gg++) bstart[gg] = v;
}

__global__ void pool_kernel(const __bf16* __restrict__ xin, const int* __restrict__ bstart,
                            float* __restrict__ g) {
  int gid = blockIdx.x;
  int c = blockIdx.y * 64 + threadIdx.x;
  int s = bstart[gid], e = bstart[gid + 1];
  float mx = -__builtin_inff(), sm = 0.f;
  for (int v = s; v < e; v++) {
    float val = (float)xin[(size_t)v * FDIM + c];
    mx = fmaxf(mx, val);
    sm += val;
  }
  float cntf = (float)(e - s);
  g[gid * (2 * FDIM) + c] = mx;
  g[gid * (2 * FDIM) + FDIM + c] = sm / fmaxf(cntf, 1.f);
}

// ---------------- launch ----------------
extern "C" void kernel_launch(void* const* d_in, const int* in_sizes, int n_in,
                              void* d_out, int out_size, void* d_ws, size_t ws_size,
                              hipStream_t stream)
{
  const int N = in_sizes[0] / FDIM;
  const int E = in_sizes[2] / 2;
  const int NB = (N + 255) / 256;

  const float* x[2]   = {(const float*)d_in[0], (const float*)d_in[1]};
  const int*   ei[2]  = {(const int*)d_in[2], (const int*)d_in[3]};
  const int*   bat[2] = {(const int*)d_in[4], (const int*)d_in[5]};
  const float* W_gcn   = (const float*)d_in[6];
  const float* b_gcn   = (const float*)d_in[7];
  const float* W_gat   = (const float*)d_in[8];
  const float* att_src = (const float*)d_in[9];
  const float* att_dst = (const float*)d_in[10];
  const float* b_gat   = (const float*)d_in[11];
  const float* W_fc_g1 = (const float*)d_in[12];
  const float* b_fc_g1 = (const float*)d_in[13];
  const float* W_fc_g2 = (const float*)d_in[14];
  const float* b_fc_g2 = (const float*)d_in[15];
  const float* W_fc1   = (const float*)d_in[16];
  const float* b_fc1   = (const float*)d_in[17];
  const float* W_fc2   = (const float*)d_in[18];
  const float* b_fc2   = (const float*)d_in[19];
  const float* W_out   = (const float*)d_in[20];
  const float* b_out   = (const float*)d_in[21];
  float* outp = (float*)d_out;

  char* ws = (char*)d_ws;
  size_t off = 0;
  auto alloc = [&](size_t bytes) -> char* {
    char* p = ws + off;
    off += (bytes + 255) & ~(size_t)255;
    return p;
  };
  int*    cnt    = (int*)alloc((size_t)N * 4);
  int*    fil    = (int*)alloc((size_t)N * 4);
  size_t  zero_span = (size_t)((char*)fil - (char*)cnt) + ((size_t)N * 4 + 255 & ~(size_t)255);
  int*    rp     = (int*)alloc((size_t)(N + 1) * 4);
  int*    bsum   = (int*)alloc((size_t)NB * 4);
  int*    csr    = (int*)alloc((size_t)E * 4);
  float*  dinv   = (float*)alloc((size_t)N * 4);
  int*    bstart = (int*)alloc((size_t)(NGR + 1) * 4);
  __bf16* WgcnT  = (__bf16*)alloc((size_t)FDIM * FDIM * 2);
  __bf16* WgatT  = (__bf16*)alloc((size_t)FDIM * FDIM * 2);
  __bf16* hbuf   = (__bf16*)alloc((size_t)N * FDIM * 2);
  __bf16* xbuf   = (__bf16*)alloc((size_t)N * FDIM * 2);
  float*  as_    = (float*)alloc((size_t)N * NHEADS * 4);
  float*  ad_    = (float*)alloc((size_t)N * NHEADS * 4);
  float*  minv   = (float*)alloc((size_t)N * NHEADS * 4);
  float*  invden = (float*)alloc((size_t)N * NHEADS * 4);
  float*  aself  = (float*)alloc((size_t)N * NHEADS * 4);
  float*  g      = (float*)alloc((size_t)2 * NGR * 2 * FDIM * 4);   // both branches
  float*  t1     = (float*)alloc((size_t)2 * NGR * 1500 * 4);       // both branches
  float*  xc     = (float*)alloc((size_t)NGR * 256 * 4);
  float*  t2     = (float*)alloc((size_t)NGR * 1024 * 4);
  float*  t3     = (float*)alloc((size_t)NGR * 512 * 4);
  float*  part   = (float*)alloc((size_t)8 * 512 * 512 * 4);        // split-K partials (8 MB)
  if (off > ws_size) return;  // workspace too small: bail (visible as absmax fail)

  wconv2_kernel<<<2 * (FDIM * FDIM) / 256, 256, 0, stream>>>(W_gcn, W_gat, WgcnT, WgatT);

  for (int br = 0; br < 2; br++) {
    hipMemsetAsync(cnt, 0, zero_span, stream);
    const int* srcp = ei[br];
    const int* dstp = ei[br] + E;
    count_kernel<<<(E + 255) / 256, 256, 0, stream>>>(dstp, cnt, E);
    bsum_kernel<<<NB, 256, 0, stream>>>(cnt, bsum, N);
    bscan_kernel<<<1, 256, 0, stream>>>(bsum, NB);
    rpfill_kernel<<<NB, 256, 0, stream>>>(cnt, bsum, rp, dinv, N, E);
    fill_kernel<<<(E + 255) / 256, 256, 0, stream>>>(srcp, dstp, rp, fil, csr, E);

    int g320 = (N + 63) / 64;
    gemm320v3_kernel<float, false><<<g320, 256, 0, stream>>>(
        x[br], WgcnT, hbuf, N, nullptr, nullptr, nullptr, nullptr);
    gcn_agg_kernel<<<(N + 3) / 4, 256, 0, stream>>>(hbuf, rp, csr, dinv, b_gcn, xbuf, N);
    gemm320v3_kernel<__bf16, true><<<g320, 256, 0, stream>>>(
        xbuf, WgatT, hbuf, N, att_src, att_dst, as_, ad_);

    mdenom3_kernel<<<(N * NHEADS + 255) / 256, 256, 0, stream>>>(rp, csr, as_, ad_, minv, invden, aself, N);
    gat_agg_kernel<<<(N + 3) / 4, 256, 0, stream>>>(hbuf, rp, csr, as_, ad_, minv, invden, aself, b_gat, xbuf, N);

    bstart_kernel<<<(N + 256) / 256, 256, 0, stream>>>(bat[br], bstart, N, NGR);
    dim3 gpool(NGR, FDIM / 64);
    pool_kernel<<<gpool, 64, 0, stream>>>(xbuf, bstart, g + (size_t)br * NGR * 2 * FDIM);
  }

  // ---- batched FC head: M=512 covers both branches ----
  {
    dim3 gfc1((512 + BM - 1) / BM, (1500 + BN - 1) / BN);
    gemm_bf16_kernel<3><<<gfc1, 256, 0, stream>>>(g, W_fc_g1, t1, b_fc_g1, 512, 1500, 2 * FDIM, 1500);
    int S = 8, KS = ((1500 + S * BK - 1) / (S * BK)) * BK;
    dim3 gfc2((512 + BM - 1) / BM, (128 + BN - 1) / BN, S);
    gemm_splitk_kernel<<<gfc2, 256, 0, stream>>>(t1, W_fc_g2, part, 512, 128, 1500, KS);
    reduce_kernel<2, true><<<(512 * 128 + 255) / 256, 256, 0, stream>>>(part, xc, b_fc_g2, 512, 128, S, 256);
  }
  {
    dim3 gx1((NGR + BM - 1) / BM, (1024 + BN - 1) / BN);
    gemm_bf16_kernel<3><<<gx1, 256, 0, stream>>>(xc, W_fc1, t2, b_fc1, NGR, 1024, 256, 1024);
    int S = 4, KS = ((1024 + S * BK - 1) / (S * BK)) * BK;
    dim3 gx2((NGR + BM - 1) / BM, (512 + BN - 1) / BN, S);
    gemm_splitk_kernel<<<gx2, 256, 0, stream>>>(t2, W_fc2, part, NGR, 512, 1024, KS);
    reduce_kernel<3, false><<<(NGR * 512 + 255) / 256, 256, 0, stream>>>(part, t3, b_fc2, NGR, 512, S, 512);
    int S2 = 4, KS2 = ((512 + S2 * BK - 1) / (S2 * BK)) * BK;
    dim3 gx3((NGR + BM - 1) / BM, 1, S2);
    gemm_splitk_kernel<<<gx3, 256, 0, stream>>>(t3, W_out, part, NGR, 2, 512, KS2);
    reduce_kernel<2, false><<<(NGR * 2 + 255) / 256, 256, 0, stream>>>(part, outp, b_out, NGR, 2, S2, 2);
  }
}

// Round 12
// 721.510 us; speedup vs baseline: 1.0390x; 1.0044x over previous
//
#include <hip/hip_runtime.h>
#include <type_traits>

#define FDIM 320
#define NHEADS 10
#define NGR 256

typedef __bf16 bf16x8 __attribute__((ext_vector_type(8)));
typedef float f32x4 __attribute__((ext_vector_type(4)));

// ---------------- weight transpose+convert (both weights, one launch) ------
__global__ void wconv2_kernel(const float* __restrict__ Wg, const float* __restrict__ Wa,
                              __bf16* __restrict__ Tg, __bf16* __restrict__ Ta) {
  int idx = blockIdx.x * 256 + threadIdx.x;
  bool first = idx < FDIM * FDIM;
  const float* W = first ? Wg : Wa;
  __bf16* T = first ? Tg : Ta;
  int i2 = first ? idx : idx - FDIM * FDIM;
  int k = i2 / FDIM, c = i2 - k * FDIM;
  T[c * FDIM + k] = (__bf16)W[i2];
}

// ---------------- node GEMM v3: full-N, BK=32, LDS dbuf, async reg-stage ---
#define GLSTR 40

template<typename TA, bool SCORES>
__global__ __launch_bounds__(256, 2) void gemm320v3_kernel(
    const TA* __restrict__ A, const __bf16* __restrict__ Wt,
    __bf16* __restrict__ C, int M,
    const float* __restrict__ att_s, const float* __restrict__ att_d,
    float* __restrict__ as_, float* __restrict__ ad_)
{
  __shared__ __bf16 As[2][64 * GLSTR];
  __shared__ __bf16 Bs[2][320 * GLSTR];

  const int tid = threadIdx.x;
  const int lane = tid & 63;
  const int w = tid >> 6;
  const int wr = w >> 1, wc = w & 1;
  const int r = lane & 15, kg = lane >> 4;
  const int m0 = blockIdx.x * 64;

  const int brow = tid >> 2, bq = tid & 3;
  const int gmrow = m0 + brow;
  const bool arow_ok = gmrow < M;

  bf16x8 bstg[5];
  bf16x8 astg;
  float4 af32a, af32b;

  auto stage_load = [&](int k0) {
    #pragma unroll
    for (int i = 0; i < 5; i++) {
      int ch = tid + i * 256;
      int col = ch >> 2, kc = ch & 3;
      bstg[i] = *(const bf16x8*)(Wt + (size_t)col * FDIM + k0 + kc * 8);
    }
    if constexpr (std::is_same_v<TA, float>) {
      if (arow_ok) {
        const float4* ap = (const float4*)(A + (size_t)gmrow * FDIM + k0 + bq * 8);
        af32a = ap[0]; af32b = ap[1];
      }
    } else {
      if (arow_ok) astg = *(const bf16x8*)(A + (size_t)gmrow * FDIM + k0 + bq * 8);
    }
  };
  auto stage_write = [&](int b) {
    #pragma unroll
    for (int i = 0; i < 5; i++) {
      int ch = tid + i * 256;
      int col = ch >> 2, kc = ch & 3;
      *(bf16x8*)&Bs[b][col * GLSTR + kc * 8] = bstg[i];
    }
    bf16x8 v = {};
    if constexpr (std::is_same_v<TA, float>) {
      if (arow_ok) {
        v[0]=(__bf16)af32a.x; v[1]=(__bf16)af32a.y; v[2]=(__bf16)af32a.z; v[3]=(__bf16)af32a.w;
        v[4]=(__bf16)af32b.x; v[5]=(__bf16)af32b.y; v[6]=(__bf16)af32b.z; v[7]=(__bf16)af32b.w;
      }
    } else {
      if (arow_ok) v = astg;
    }
    *(bf16x8*)&As[b][brow * GLSTR + bq * 8] = v;
  };

  f32x4 acc0[10], acc1[10];
  #pragma unroll
  for (int i = 0; i < 10; i++) { acc0[i] = (f32x4){0,0,0,0}; acc1[i] = (f32x4){0,0,0,0}; }

  stage_load(0);
  stage_write(0);
  __syncthreads();

  int cur = 0;
  for (int k = 0; k < 10; k++) {
    if (k < 9) stage_load((k + 1) * 32);
    {
      bf16x8 a0 = *(const bf16x8*)&As[cur][(wr*32 + r)      * GLSTR + kg*8];
      bf16x8 a1 = *(const bf16x8*)&As[cur][(wr*32 + 16 + r) * GLSTR + kg*8];
      #pragma unroll
      for (int nf = 0; nf < 10; nf++) {
        bf16x8 b = *(const bf16x8*)&Bs[cur][(wc*160 + nf*16 + r) * GLSTR + kg*8];
        acc0[nf] = __builtin_amdgcn_mfma_f32_16x16x32_bf16(a0, b, acc0[nf], 0, 0, 0);
        acc1[nf] = __builtin_amdgcn_mfma_f32_16x16x32_bf16(a1, b, acc1[nf], 0, 0, 0);
      }
    }
    if (k < 9) {
      stage_write(cur ^ 1);
      __syncthreads();
      cur ^= 1;
    }
  }

  // ---- store C ----
  #pragma unroll
  for (int nf = 0; nf < 10; nf++) {
    int gn = wc*160 + nf*16 + r;
    #pragma unroll
    for (int q = 0; q < 4; q++) {
      int gm0 = m0 + wr*32 + kg*4 + q;
      if (gm0 < M)       C[(size_t)gm0 * FDIM + gn] = (__bf16)acc0[nf][q];
      int gm1 = gm0 + 16;
      if (gm1 < M)       C[(size_t)gm1 * FDIM + gn] = (__bf16)acc1[nf][q];
    }
  }

  // ---- fused GAT scores ----
  if constexpr (SCORES) {
    #pragma unroll
    for (int th = 0; th < 5; th++) {
      int t = wc * 5 + th;
      float s0 = att_s[t*32 + r],      s1 = att_s[t*32 + 16 + r];
      float d0 = att_d[t*32 + r],      d1 = att_d[t*32 + 16 + r];
      #pragma unroll
      for (int q = 0; q < 4; q++) {
        float ps0 = acc0[2*th][q]*s0 + acc0[2*th+1][q]*s1;
        float ps1 = acc1[2*th][q]*s0 + acc1[2*th+1][q]*s1;
        float pd0 = acc0[2*th][q]*d0 + acc0[2*th+1][q]*d1;
        float pd1 = acc1[2*th][q]*d0 + acc1[2*th+1][q]*d1;
        #pragma unroll
        for (int off = 1; off < 16; off <<= 1) {
          ps0 += __shfl_xor(ps0, off, 16);
          ps1 += __shfl_xor(ps1, off, 16);
          pd0 += __shfl_xor(pd0, off, 16);
          pd1 += __shfl_xor(pd1, off, 16);
        }
        if (r == 0) {
          int row0 = m0 + wr*32 + kg*4 + q;
          if (row0 < M) { as_[row0*NHEADS + t] = ps0; ad_[row0*NHEADS + t] = pd0; }
          int row1 = row0 + 16;
          if (row1 < M) { as_[row1*NHEADS + t] = ps1; ad_[row1*NHEADS + t] = pd1; }
        }
      }
    }
  }
}

// ---------------- generic GEMM (FC layers): C = A*B, f32 in/out ------------
#define BM 128
#define BN 64
#define BK 32
#define LSTR 56

template<int FLAGS>  // bit0: relu, bit1: bias
__global__ __launch_bounds__(256) void gemm_bf16_kernel(
    const float* __restrict__ A, const float* __restrict__ B,
    float* __restrict__ C, const float* __restrict__ bias,
    int M, int N, int K, int ldc)
{
  __shared__ __bf16 As[BM * LSTR];
  __shared__ __bf16 Bs[BN * LSTR];

  const int tid = threadIdx.x;
  const int lane = tid & 63;
  const int w = tid >> 6;
  const int wm = w >> 1, wn = w & 1;
  const int r = lane & 15, kg = lane >> 4;
  const int m0 = blockIdx.x * BM, n0 = blockIdx.y * BN;

  f32x4 acc[4][2];
  #pragma unroll
  for (int i = 0; i < 4; i++)
    #pragma unroll
    for (int j = 0; j < 2; j++)
      acc[i][j] = (f32x4){0.f, 0.f, 0.f, 0.f};

  const int arow = tid >> 1, ahalf = tid & 1;
  const int bk = tid >> 3, bn = (tid & 7) * 8;

  for (int k0 = 0; k0 < K; k0 += BK) {
    __syncthreads();
    {
      int gm = m0 + arow;
      int kbase = k0 + ahalf * 16;
      float tmp[16];
      if (gm < M && kbase + 16 <= K) {
        const float4* ap = (const float4*)(A + (size_t)gm * K + kbase);
        #pragma unroll
        for (int q = 0; q < 4; q++) {
          float4 v = ap[q];
          tmp[q*4+0] = v.x; tmp[q*4+1] = v.y; tmp[q*4+2] = v.z; tmp[q*4+3] = v.w;
        }
      } else {
        #pragma unroll
        for (int q = 0; q < 16; q++) {
          int kk = kbase + q;
          tmp[q] = (gm < M && kk < K) ? A[(size_t)gm * K + kk] : 0.f;
        }
      }
      bf16x8 v0, v1;
      #pragma unroll
      for (int q = 0; q < 8; q++) { v0[q] = (__bf16)tmp[q]; v1[q] = (__bf16)tmp[q+8]; }
      bf16x8* dp = (bf16x8*)&As[arow * LSTR + ahalf * 16];
      dp[0] = v0; dp[1] = v1;
    }
    {
      int gk = k0 + bk;
      float tb[8];
      if (gk < K && n0 + bn + 8 <= N) {
        const float4* bp = (const float4*)(B + (size_t)gk * N + n0 + bn);
        float4 u0 = bp[0], u1 = bp[1];
        tb[0]=u0.x; tb[1]=u0.y; tb[2]=u0.z; tb[3]=u0.w;
        tb[4]=u1.x; tb[5]=u1.y; tb[6]=u1.z; tb[7]=u1.w;
      } else {
        #pragma unroll
        for (int q = 0; q < 8; q++) {
          int gn = n0 + bn + q;
          tb[q] = (gk < K && gn < N) ? B[(size_t)gk * N + gn] : 0.f;
        }
      }
      #pragma unroll
      for (int q = 0; q < 8; q++) Bs[(bn + q) * LSTR + bk] = (__bf16)tb[q];
    }
    __syncthreads();
    bf16x8 af[4], bfr[2];
    #pragma unroll
    for (int mf = 0; mf < 4; mf++)
      af[mf] = *(const bf16x8*)&As[(wm*64 + mf*16 + r) * LSTR + kg*8];
    #pragma unroll
    for (int nf = 0; nf < 2; nf++)
      bfr[nf] = *(const bf16x8*)&Bs[(wn*32 + nf*16 + r) * LSTR + kg*8];
    #pragma unroll
    for (int mf = 0; mf < 4; mf++)
      #pragma unroll
      for (int nf = 0; nf < 2; nf++)
        acc[mf][nf] = __builtin_amdgcn_mfma_f32_16x16x32_bf16(af[mf], bfr[nf], acc[mf][nf], 0, 0, 0);
  }

  #pragma unroll
  for (int mf = 0; mf < 4; mf++) {
    #pragma unroll
    for (int nf = 0; nf < 2; nf++) {
      #pragma unroll
      for (int q = 0; q < 4; q++) {
        int gm = m0 + wm*64 + mf*16 + kg*4 + q;
        int gn = n0 + wn*32 + nf*16 + r;
        if (gm < M && gn < N) {
          float v = acc[mf][nf][q];
          if (FLAGS & 2) v += bias[gn];
          if (FLAGS & 1) v = fmaxf(v, 0.f);
          C[(size_t)gm * ldc + gn] = v;
        }
      }
    }
  }
}

// ---------------- split-K GEMM: P[s][M][N] partials ----------------
__global__ __launch_bounds__(256) void gemm_splitk_kernel(
    const float* __restrict__ A, const float* __restrict__ B,
    float* __restrict__ P, int M, int N, int K, int KS)
{
  __shared__ __bf16 As[BM * LSTR];
  __shared__ __bf16 Bs[BN * LSTR];

  const int tid = threadIdx.x;
  const int lane = tid & 63;
  const int w = tid >> 6;
  const int wm = w >> 1, wn = w & 1;
  const int r = lane & 15, kg = lane >> 4;
  const int m0 = blockIdx.x * BM, n0 = blockIdx.y * BN;
  const int kstart = blockIdx.z * KS;
  const int kend = min(K, kstart + KS);

  f32x4 acc[4][2];
  #pragma unroll
  for (int i = 0; i < 4; i++)
    #pragma unroll
    for (int j = 0; j < 2; j++)
      acc[i][j] = (f32x4){0.f, 0.f, 0.f, 0.f};

  const int arow = tid >> 1, ahalf = tid & 1;
  const int bk = tid >> 3, bn = (tid & 7) * 8;

  for (int k0 = kstart; k0 < kend; k0 += BK) {
    __syncthreads();
    {
      int gm = m0 + arow;
      int kbase = k0 + ahalf * 16;
      float tmp[16];
      if (gm < M && kbase + 16 <= kend) {
        const float4* ap = (const float4*)(A + (size_t)gm * K + kbase);
        #pragma unroll
        for (int q = 0; q < 4; q++) {
          float4 v = ap[q];
          tmp[q*4+0] = v.x; tmp[q*4+1] = v.y; tmp[q*4+2] = v.z; tmp[q*4+3] = v.w;
        }
      } else {
        #pragma unroll
        for (int q = 0; q < 16; q++) {
          int kk = kbase + q;
          tmp[q] = (gm < M && kk < kend) ? A[(size_t)gm * K + kk] : 0.f;
        }
      }
      bf16x8 v0, v1;
      #pragma unroll
      for (int q = 0; q < 8; q++) { v0[q] = (__bf16)tmp[q]; v1[q] = (__bf16)tmp[q+8]; }
      bf16x8* dp = (bf16x8*)&As[arow * LSTR + ahalf * 16];
      dp[0] = v0; dp[1] = v1;
    }
    {
      int gk = k0 + bk;
      float tb[8];
      if (gk < kend && n0 + bn + 8 <= N) {
        const float4* bp = (const float4*)(B + (size_t)gk * N + n0 + bn);
        float4 u0 = bp[0], u1 = bp[1];
        tb[0]=u0.x; tb[1]=u0.y; tb[2]=u0.z; tb[3]=u0.w;
        tb[4]=u1.x; tb[5]=u1.y; tb[6]=u1.z; tb[7]=u1.w;
      } else {
        #pragma unroll
        for (int q = 0; q < 8; q++) {
          int gn = n0 + bn + q;
          tb[q] = (gk < kend && gn < N) ? B[(size_t)gk * N + gn] : 0.f;
        }
      }
      #pragma unroll
      for (int q = 0; q < 8; q++) Bs[(bn + q) * LSTR + bk] = (__bf16)tb[q];
    }
    __syncthreads();
    bf16x8 af[4], bfr[2];
    #pragma unroll
    for (int mf = 0; mf < 4; mf++)
      af[mf] = *(const bf16x8*)&As[(wm*64 + mf*16 + r) * LSTR + kg*8];
    #pragma unroll
    for (int nf = 0; nf < 2; nf++)
      bfr[nf] = *(const bf16x8*)&Bs[(wn*32 + nf*16 + r) * LSTR + kg*8];
    #pragma unroll
    for (int mf = 0; mf < 4; mf++)
      #pragma unroll
      for (int nf = 0; nf < 2; nf++)
        acc[mf][nf] = __builtin_amdgcn_mfma_f32_16x16x32_bf16(af[mf], bfr[nf], acc[mf][nf], 0, 0, 0);
  }

  float* Pp = P + (size_t)blockIdx.z * M * N;
  #pragma unroll
  for (int mf = 0; mf < 4; mf++) {
    #pragma unroll
    for (int nf = 0; nf < 2; nf++) {
      #pragma unroll
      for (int q = 0; q < 4; q++) {
        int gm = m0 + wm*64 + mf*16 + kg*4 + q;
        int gn = n0 + wn*32 + nf*16 + r;
        if (gm < M && gn < N)
          Pp[(size_t)gm * N + gn] = acc[mf][nf][q];
      }
    }
  }
}

// reduce partials; STACK: rows M/2.. go to cols N.. (fc_g2 branch packing)
template<int FLAGS, bool STACK>
__global__ void reduce_kernel(const float* __restrict__ P, float* __restrict__ C,
                              const float* __restrict__ bias, int M, int N, int S, int ldc)
{
  int i = blockIdx.x * 256 + threadIdx.x;
  if (i >= M * N) return;
  float v = 0.f;
  for (int s = 0; s < S; s++) v += P[(size_t)s * M * N + i];
  int row = i / N, col = i - row * N;
  if (FLAGS & 2) v += bias[col];
  if (FLAGS & 1) v = fmaxf(v, 0.f);
  if (STACK) { if (row >= (M >> 1)) { row -= (M >> 1); col += N; } }
  C[(size_t)row * ldc + col] = v;
}

// ---------------- CSR build ----------------
__global__ void count_kernel(const int* __restrict__ dst, int* __restrict__ cnt, int E) {
  int e = blockIdx.x * 256 + threadIdx.x;
  if (e < E) atomicAdd(&cnt[dst[e]], 1);
}

__global__ void bsum_kernel(const int* __restrict__ cnt, int* __restrict__ bsum, int n) {
  __shared__ int wp[4];
  int tid = threadIdx.x, lane = tid & 63, wid = tid >> 6;
  int i = blockIdx.x * 256 + tid;
  int v = (i < n) ? cnt[i] : 0;
  #pragma unroll
  for (int off = 32; off >= 1; off >>= 1) v += __shfl_xor(v, off, 64);
  if (lane == 0) wp[wid] = v;
  __syncthreads();
  if (tid == 0) bsum[blockIdx.x] = wp[0] + wp[1] + wp[2] + wp[3];
}

__global__ void bscan_kernel(int* __restrict__ bsum, int nb) {
  __shared__ int wp[4];
  int tid = threadIdx.x, lane = tid & 63, wid = tid >> 6;
  int v = (tid < nb) ? bsum[tid] : 0;
  int xv = v;
  #pragma unroll
  for (int off = 1; off < 64; off <<= 1) {
    int y = __shfl_up(xv, off, 64);
    if (lane >= off) xv += y;
  }
  if (lane == 63) wp[wid] = xv;
  __syncthreads();
  if (tid == 0) { int s = 0; for (int k = 0; k < 4; k++) { int t = wp[k]; wp[k] = s; s += t; } }
  __syncthreads();
  if (tid < nb) bsum[tid] = wp[wid] + xv - v;   // exclusive
}

__global__ void rpfill_kernel(const int* __restrict__ cnt, const int* __restrict__ bsum,
                              int* __restrict__ rp, float* __restrict__ dinv, int n, int E) {
  __shared__ int wp[4];
  int tid = threadIdx.x, lane = tid & 63, wid = tid >> 6;
  int i = blockIdx.x * 256 + tid;
  int v = (i < n) ? cnt[i] : 0;
  int xv = v;
  #pragma unroll
  for (int off = 1; off < 64; off <<= 1) {
    int y = __shfl_up(xv, off, 64);
    if (lane >= off) xv += y;
  }
  if (lane == 63) wp[wid] = xv;
  __syncthreads();
  if (tid == 0) { int s = 0; for (int k = 0; k < 4; k++) { int t = wp[k]; wp[k] = s; s += t; } }
  __syncthreads();
  if (i < n) {
    rp[i] = bsum[blockIdx.x] + wp[wid] + xv - v;
    dinv[i] = rsqrtf((float)(v + 1));
  }
  if (blockIdx.x == 0 && tid == 0) rp[n] = E;
}

__global__ void fill_kernel(const int* __restrict__ src, const int* __restrict__ dst,
                            const int* __restrict__ rp, int* __restrict__ fil,
                            int* __restrict__ csr, int E) {
  int e = blockIdx.x * 256 + threadIdx.x;
  if (e < E) {
    int d = dst[e];
    int pos = rp[d] + atomicAdd(&fil[d], 1);
    csr[pos] = src[e];
  }
}

// -- GCN aggregate: scalar (SGPR) edge walk + 40-lane wide loads, 4-deep ----
__global__ void gcn_agg_kernel(const __bf16* __restrict__ h, const int* __restrict__ rp,
                               const int* __restrict__ csr, const float* __restrict__ dinv,
                               const float* __restrict__ bias, __bf16* __restrict__ out, int n)
{
  const int lane = threadIdx.x & 63;
  int v0 = blockIdx.x * 4 + (threadIdx.x >> 6);
  if (v0 >= n) return;
  const int v = __builtin_amdgcn_readfirstlane(v0);   // wave-uniform -> SGPR
  const bool act = lane < 40;
  const float dv = dinv[v];
  const int e0 = rp[v], e1 = rp[v + 1];
  float acc[8], bia[8];
  if (act) {
    bf16x8 hv = *(const bf16x8*)(h + (size_t)v * FDIM + 8 * lane);
    const float4* bp = (const float4*)(bias + 8 * lane);
    float4 b0 = bp[0], b1 = bp[1];
    bia[0]=b0.x; bia[1]=b0.y; bia[2]=b0.z; bia[3]=b0.w;
    bia[4]=b1.x; bia[5]=b1.y; bia[6]=b1.z; bia[7]=b1.w;
    #pragma unroll
    for (int j = 0; j < 8; j++) acc[j] = dv * (float)hv[j];
  }
  int e = e0;
  for (; e + 4 <= e1; e += 4) {
    int sj0 = csr[e], sj1 = csr[e+1], sj2 = csr[e+2], sj3 = csr[e+3];   // uniform -> s_load
    float c0 = dinv[sj0], c1 = dinv[sj1], c2 = dinv[sj2], c3 = dinv[sj3];
    if (act) {
      bf16x8 h0 = *(const bf16x8*)(h + (size_t)sj0 * FDIM + 8 * lane);
      bf16x8 h1 = *(const bf16x8*)(h + (size_t)sj1 * FDIM + 8 * lane);
      bf16x8 h2 = *(const bf16x8*)(h + (size_t)sj2 * FDIM + 8 * lane);
      bf16x8 h3 = *(const bf16x8*)(h + (size_t)sj3 * FDIM + 8 * lane);
      #pragma unroll
      for (int j = 0; j < 8; j++)
        acc[j] += c0 * (float)h0[j] + c1 * (float)h1[j]
                + c2 * (float)h2[j] + c3 * (float)h3[j];
    }
  }
  for (; e < e1; e++) {
    int sj = csr[e];
    float cj = dinv[sj];
    if (act) {
      bf16x8 hv = *(const bf16x8*)(h + (size_t)sj * FDIM + 8 * lane);
      #pragma unroll
      for (int j = 0; j < 8; j++) acc[j] += cj * (float)hv[j];
    }
  }
  if (act) {
    bf16x8 o;
    #pragma unroll
    for (int j = 0; j < 8; j++) o[j] = (__bf16)fmaxf(dv * acc[j] + bia[j], 0.f);
    *(bf16x8*)(out + (size_t)v * FDIM + 8 * lane) = o;
  }
}

__device__ __forceinline__ float lrelu(float x) { return x > 0.f ? x : 0.2f * x; }

// ---- softmax stats + materialized alpha: pass1 online (m,den), pass2
// (cache-hot re-walk) writes aint[e][t]; also writes aself ------------------
__global__ void mdenom4_kernel(const int* __restrict__ rp, const int* __restrict__ csr,
                               const float* __restrict__ as_, const float* __restrict__ ad_,
                               float* __restrict__ aint, float* __restrict__ aself, int n)
{
  int tid = blockIdx.x * 256 + threadIdx.x;
  if (tid >= n * NHEADS) return;
  int v = tid / NHEADS, t = tid - v * NHEADS;
  int e0 = rp[v], e1 = rp[v + 1];
  float adv = ad_[tid];
  float esf = lrelu(as_[tid] + adv);
  float m = esf, den = 1.f;
  for (int e = e0; e < e1; e++) {
    int s = csr[e];
    float ev = lrelu(as_[s * NHEADS + t] + adv);
    float nm = fmaxf(m, ev);
    den = den * __expf(m - nm) + __expf(ev - nm);
    m = nm;
  }
  float inv = 1.f / den;
  for (int e = e0; e < e1; e++) {
    int s = csr[e];
    aint[(size_t)e * NHEADS + t] = __expf(lrelu(as_[s * NHEADS + t] + adv) - m) * inv;
  }
  aself[tid] = __expf(esf - m) * inv;
}

// -- GAT aggregate: scalar edge walk, linear aint read, 40-lane wide, 4-deep
__global__ void gat_agg_kernel(const __bf16* __restrict__ h, const int* __restrict__ rp,
                               const int* __restrict__ csr, const float* __restrict__ aint,
                               const float* __restrict__ aself, const float* __restrict__ bias,
                               __bf16* __restrict__ out, int n)
{
  const int lane = threadIdx.x & 63;
  int v0 = blockIdx.x * 4 + (threadIdx.x >> 6);
  if (v0 >= n) return;
  const int v = __builtin_amdgcn_readfirstlane(v0);   // wave-uniform -> SGPR
  const bool act = lane < 40;
  const int hl = lane >> 2;           // head of channels 8*lane..8*lane+7
  const int e0 = rp[v], e1 = rp[v + 1];

  float acc[8], bia[8];
  if (act) {
    float aslf = aself[v * NHEADS + hl];
    bf16x8 hv = *(const bf16x8*)(h + (size_t)v * FDIM + 8 * lane);
    const float4* bp = (const float4*)(bias + 8 * lane);
    float4 b0 = bp[0], b1 = bp[1];
    bia[0]=b0.x; bia[1]=b0.y; bia[2]=b0.z; bia[3]=b0.w;
    bia[4]=b1.x; bia[5]=b1.y; bia[6]=b1.z; bia[7]=b1.w;
    #pragma unroll
    for (int j = 0; j < 8; j++) acc[j] = aslf * (float)hv[j];
  }

  int e = e0;
  for (; e + 4 <= e1; e += 4) {
    int sj0 = csr[e], sj1 = csr[e+1], sj2 = csr[e+2], sj3 = csr[e+3];   // uniform -> s_load
    if (act) {
      float a0 = aint[(size_t)(e+0) * NHEADS + hl];
      float a1 = aint[(size_t)(e+1) * NHEADS + hl];
      float a2 = aint[(size_t)(e+2) * NHEADS + hl];
      float a3 = aint[(size_t)(e+3) * NHEADS + hl];
      bf16x8 h0 = *(const bf16x8*)(h + (size_t)sj0 * FDIM + 8 * lane);
      bf16x8 h1 = *(const bf16x8*)(h + (size_t)sj1 * FDIM + 8 * lane);
      bf16x8 h2 = *(const bf16x8*)(h + (size_t)sj2 * FDIM + 8 * lane);
      bf16x8 h3 = *(const bf16x8*)(h + (size_t)sj3 * FDIM + 8 * lane);
      #pragma unroll
      for (int j = 0; j < 8; j++)
        acc[j] += a0 * (float)h0[j] + a1 * (float)h1[j]
                + a2 * (float)h2[j] + a3 * (float)h3[j];
    }
  }
  for (; e < e1; e++) {
    int sj = csr[e];
    if (act) {
      float al = aint[(size_t)e * NHEADS + hl];
      bf16x8 hv = *(const bf16x8*)(h + (size_t)sj * FDIM + 8 * lane);
      #pragma unroll
      for (int j = 0; j < 8; j++) acc[j] += al * (float)hv[j];
    }
  }
  if (act) {
    bf16x8 o;
    #pragma unroll
    for (int j = 0; j < 8; j++) o[j] = (__bf16)fmaxf(acc[j] + bia[j], 0.f);
    *(bf16x8*)(out + (size_t)v * FDIM + 8 * lane) = o;
  }
}

// ---------------- batch boundaries + pooling ----------------
__global__ void bstart_kernel(const int* __restrict__ batch, int* __restrict__ bstart,
                              int n, int B_) {
  int v = blockIdx.x * 256 + threadIdx.x;
  if (v > n) return;
  int bv = (v < n) ? batch[v] : B_;
  int bp = (v == 0) ? -1 : batch[v - 1];
  for (int gg = bp + 1; gg <= bv; gg++) bstart[gg] = v;
}

__global__ void pool_kernel(const __bf16* __restrict__ xin, const int* __restrict__ bstart,
                            float* __restrict__ g) {
  int gid = blockIdx.x;
  int c = blockIdx.y * 64 + threadIdx.x;
  int s = bstart[gid], e = bstart[gid + 1];
  float mx = -__builtin_inff(), sm = 0.f;
  for (int v = s; v < e; v++) {
    float val = (float)xin[(size_t)v * FDIM + c];
    mx = fmaxf(mx, val);
    sm += val;
  }
  float cntf = (float)(e - s);
  g[gid * (2 * FDIM) + c] = mx;
  g[gid * (2 * FDIM) + FDIM + c] = sm / fmaxf(cntf, 1.f);
}

// ---------------- launch ----------------
extern "C" void kernel_launch(void* const* d_in, const int* in_sizes, int n_in,
                              void* d_out, int out_size, void* d_ws, size_t ws_size,
                              hipStream_t stream)
{
  const int N = in_sizes[0] / FDIM;
  const int E = in_sizes[2] / 2;
  const int NB = (N + 255) / 256;

  const float* x[2]   = {(const float*)d_in[0], (const float*)d_in[1]};
  const int*   ei[2]  = {(const int*)d_in[2], (const int*)d_in[3]};
  const int*   bat[2] = {(const int*)d_in[4], (const int*)d_in[5]};
  const float* W_gcn   = (const float*)d_in[6];
  const float* b_gcn   = (const float*)d_in[7];
  const float* W_gat   = (const float*)d_in[8];
  const float* att_src = (const float*)d_in[9];
  const float* att_dst = (const float*)d_in[10];
  const float* b_gat   = (const float*)d_in[11];
  const float* W_fc_g1 = (const float*)d_in[12];
  const float* b_fc_g1 = (const float*)d_in[13];
  const float* W_fc_g2 = (const float*)d_in[14];
  const float* b_fc_g2 = (const float*)d_in[15];
  const float* W_fc1   = (const float*)d_in[16];
  const float* b_fc1   = (const float*)d_in[17];
  const float* W_fc2   = (const float*)d_in[18];
  const float* b_fc2   = (const float*)d_in[19];
  const float* W_out   = (const float*)d_in[20];
  const float* b_out   = (const float*)d_in[21];
  float* outp = (float*)d_out;

  char* ws = (char*)d_ws;
  size_t off = 0;
  auto alloc = [&](size_t bytes) -> char* {
    char* p = ws + off;
    off += (bytes + 255) & ~(size_t)255;
    return p;
  };
  int*    cnt    = (int*)alloc((size_t)N * 4);
  int*    fil    = (int*)alloc((size_t)N * 4);
  size_t  zero_span = (size_t)((char*)fil - (char*)cnt) + ((size_t)N * 4 + 255 & ~(size_t)255);
  int*    rp     = (int*)alloc((size_t)(N + 1) * 4);
  int*    bsum   = (int*)alloc((size_t)NB * 4);
  int*    csr    = (int*)alloc((size_t)E * 4);
  float*  dinv   = (float*)alloc((size_t)N * 4);
  int*    bstart = (int*)alloc((size_t)(NGR + 1) * 4);
  __bf16* WgcnT  = (__bf16*)alloc((size_t)FDIM * FDIM * 2);
  __bf16* WgatT  = (__bf16*)alloc((size_t)FDIM * FDIM * 2);
  __bf16* hbuf   = (__bf16*)alloc((size_t)N * FDIM * 2);
  __bf16* xbuf   = (__bf16*)alloc((size_t)N * FDIM * 2);
  float*  as_    = (float*)alloc((size_t)N * NHEADS * 4);
  float*  ad_    = (float*)alloc((size_t)N * NHEADS * 4);
  float*  aint   = (float*)alloc((size_t)E * NHEADS * 4);
  float*  aself  = (float*)alloc((size_t)N * NHEADS * 4);
  float*  g      = (float*)alloc((size_t)2 * NGR * 2 * FDIM * 4);   // both branches
  float*  t1     = (float*)alloc((size_t)2 * NGR * 1500 * 4);       // both branches
  float*  xc     = (float*)alloc((size_t)NGR * 256 * 4);
  float*  t2     = (float*)alloc((size_t)NGR * 1024 * 4);
  float*  t3     = (float*)alloc((size_t)NGR * 512 * 4);
  float*  part   = (float*)alloc((size_t)8 * 512 * 512 * 4);        // split-K partials (8 MB)
  if (off > ws_size) return;  // workspace too small: bail (visible as absmax fail)

  wconv2_kernel<<<2 * (FDIM * FDIM) / 256, 256, 0, stream>>>(W_gcn, W_gat, WgcnT, WgatT);

  for (int br = 0; br < 2; br++) {
    hipMemsetAsync(cnt, 0, zero_span, stream);
    const int* srcp = ei[br];
    const int* dstp = ei[br] + E;
    count_kernel<<<(E + 255) / 256, 256, 0, stream>>>(dstp, cnt, E);
    bsum_kernel<<<NB, 256, 0, stream>>>(cnt, bsum, N);
    bscan_kernel<<<1, 256, 0, stream>>>(bsum, NB);
    rpfill_kernel<<<NB, 256, 0, stream>>>(cnt, bsum, rp, dinv, N, E);
    fill_kernel<<<(E + 255) / 256, 256, 0, stream>>>(srcp, dstp, rp, fil, csr, E);

    int g320 = (N + 63) / 64;
    gemm320v3_kernel<float, false><<<g320, 256, 0, stream>>>(
        x[br], WgcnT, hbuf, N, nullptr, nullptr, nullptr, nullptr);
    gcn_agg_kernel<<<(N + 3) / 4, 256, 0, stream>>>(hbuf, rp, csr, dinv, b_gcn, xbuf, N);
    gemm320v3_kernel<__bf16, true><<<g320, 256, 0, stream>>>(
        xbuf, WgatT, hbuf, N, att_src, att_dst, as_, ad_);

    mdenom4_kernel<<<(N * NHEADS + 255) / 256, 256, 0, stream>>>(rp, csr, as_, ad_, aint, aself, N);
    gat_agg_kernel<<<(N + 3) / 4, 256, 0, stream>>>(hbuf, rp, csr, aint, aself, b_gat, xbuf, N);

    bstart_kernel<<<(N + 256) / 256, 256, 0, stream>>>(bat[br], bstart, N, NGR);
    dim3 gpool(NGR, FDIM / 64);
    pool_kernel<<<gpool, 64, 0, stream>>>(xbuf, bstart, g + (size_t)br * NGR * 2 * FDIM);
  }

  // ---- batched FC head: M=512 covers both branches ----
  {
    dim3 gfc1((512 + BM - 1) / BM, (1500 + BN - 1) / BN);
    gemm_bf16_kernel<3><<<gfc1, 256, 0, stream>>>(g, W_fc_g1, t1, b_fc_g1, 512, 1500, 2 * FDIM, 1500);
    int S = 8, KS = ((1500 + S * BK - 1) / (S * BK)) * BK;
    dim3 gfc2((512 + BM - 1) / BM, (128 + BN - 1) / BN, S);
    gemm_splitk_kernel<<<gfc2, 256, 0, stream>>>(t1, W_fc_g2, part, 512, 128, 1500, KS);
    reduce_kernel<2, true><<<(512 * 128 + 255) / 256, 256, 0, stream>>>(part, xc, b_fc_g2, 512, 128, S, 256);
  }
  {
    dim3 gx1((NGR + BM - 1) / BM, (1024 + BN - 1) / BN);
    gemm_bf16_kernel<3><<<gx1, 256, 0, stream>>>(xc, W_fc1, t2, b_fc1, NGR, 1024, 256, 1024);
    int S = 4, KS = ((1024 + S * BK - 1) / (S * BK)) * BK;
    dim3 gx2((NGR + BM - 1) / BM, (512 + BN - 1) / BN, S);
    gemm_splitk_kernel<<<gx2, 256, 0, stream>>>(t2, W_fc2, part, NGR, 512, 1024, KS);
    reduce_kernel<3, false><<<(NGR * 512 + 255) / 256, 256, 0, stream>>>(part, t3, b_fc2, NGR, 512, S, 512);
    int S2 = 4, KS2 = ((512 + S2 * BK - 1) / (S2 * BK)) * BK;
    dim3 gx3((NGR + BM - 1) / BM, 1, S2);
    gemm_splitk_kernel<<<gx3, 256, 0, stream>>>(t3, W_out, part, NGR, 2, 512, KS2);
    reduce_kernel<2, false><<<(NGR * 2 + 255) / 256, 256, 0, stream>>>(part, outp, b_out, NGR, 2, S2, 2);
  }
}

// Round 13
// 655.914 us; speedup vs baseline: 1.1429x; 1.1000x over previous
//
#include <hip/hip_runtime.h>
#include <type_traits>

#define FDIM 320
#define NHEADS 10
#define NGR 256

typedef __bf16 bf16x8 __attribute__((ext_vector_type(8)));
typedef float f32x4 __attribute__((ext_vector_type(4)));

// ---------------- weight transpose+convert (both weights, one launch) ------
__global__ void wconv2_kernel(const float* __restrict__ Wg, const float* __restrict__ Wa,
                              __bf16* __restrict__ Tg, __bf16* __restrict__ Ta) {
  int idx = blockIdx.x * 256 + threadIdx.x;
  bool first = idx < FDIM * FDIM;
  const float* W = first ? Wg : Wa;
  __bf16* T = first ? Tg : Ta;
  int i2 = first ? idx : idx - FDIM * FDIM;
  int k = i2 / FDIM, c = i2 - k * FDIM;
  T[c * FDIM + k] = (__bf16)W[i2];
}

// ---------------- node GEMM v3: full-N, BK=32, LDS dbuf, async reg-stage ---
#define GLSTR 40

template<typename TA, bool SCORES>
__global__ __launch_bounds__(256, 2) void gemm320v3_kernel(
    const TA* __restrict__ A, const __bf16* __restrict__ Wt,
    __bf16* __restrict__ C, int M,
    const float* __restrict__ att_s, const float* __restrict__ att_d,
    float* __restrict__ as_, float* __restrict__ ad_)
{
  __shared__ __bf16 As[2][64 * GLSTR];
  __shared__ __bf16 Bs[2][320 * GLSTR];

  const int tid = threadIdx.x;
  const int lane = tid & 63;
  const int w = tid >> 6;
  const int wr = w >> 1, wc = w & 1;
  const int r = lane & 15, kg = lane >> 4;
  const int m0 = blockIdx.x * 64;

  const int brow = tid >> 2, bq = tid & 3;
  const int gmrow = m0 + brow;
  const bool arow_ok = gmrow < M;

  bf16x8 bstg[5];
  bf16x8 astg;
  float4 af32a, af32b;

  auto stage_load = [&](int k0) {
    #pragma unroll
    for (int i = 0; i < 5; i++) {
      int ch = tid + i * 256;
      int col = ch >> 2, kc = ch & 3;
      bstg[i] = *(const bf16x8*)(Wt + (size_t)col * FDIM + k0 + kc * 8);
    }
    if constexpr (std::is_same_v<TA, float>) {
      if (arow_ok) {
        const float4* ap = (const float4*)(A + (size_t)gmrow * FDIM + k0 + bq * 8);
        af32a = ap[0]; af32b = ap[1];
      }
    } else {
      if (arow_ok) astg = *(const bf16x8*)(A + (size_t)gmrow * FDIM + k0 + bq * 8);
    }
  };
  auto stage_write = [&](int b) {
    #pragma unroll
    for (int i = 0; i < 5; i++) {
      int ch = tid + i * 256;
      int col = ch >> 2, kc = ch & 3;
      *(bf16x8*)&Bs[b][col * GLSTR + kc * 8] = bstg[i];
    }
    bf16x8 v = {};
    if constexpr (std::is_same_v<TA, float>) {
      if (arow_ok) {
        v[0]=(__bf16)af32a.x; v[1]=(__bf16)af32a.y; v[2]=(__bf16)af32a.z; v[3]=(__bf16)af32a.w;
        v[4]=(__bf16)af32b.x; v[5]=(__bf16)af32b.y; v[6]=(__bf16)af32b.z; v[7]=(__bf16)af32b.w;
      }
    } else {
      if (arow_ok) v = astg;
    }
    *(bf16x8*)&As[b][brow * GLSTR + bq * 8] = v;
  };

  f32x4 acc0[10], acc1[10];
  #pragma unroll
  for (int i = 0; i < 10; i++) { acc0[i] = (f32x4){0,0,0,0}; acc1[i] = (f32x4){0,0,0,0}; }

  stage_load(0);
  stage_write(0);
  __syncthreads();

  int cur = 0;
  for (int k = 0; k < 10; k++) {
    if (k < 9) stage_load((k + 1) * 32);
    {
      bf16x8 a0 = *(const bf16x8*)&As[cur][(wr*32 + r)      * GLSTR + kg*8];
      bf16x8 a1 = *(const bf16x8*)&As[cur][(wr*32 + 16 + r) * GLSTR + kg*8];
      #pragma unroll
      for (int nf = 0; nf < 10; nf++) {
        bf16x8 b = *(const bf16x8*)&Bs[cur][(wc*160 + nf*16 + r) * GLSTR + kg*8];
        acc0[nf] = __builtin_amdgcn_mfma_f32_16x16x32_bf16(a0, b, acc0[nf], 0, 0, 0);
        acc1[nf] = __builtin_amdgcn_mfma_f32_16x16x32_bf16(a1, b, acc1[nf], 0, 0, 0);
      }
    }
    if (k < 9) {
      stage_write(cur ^ 1);
      __syncthreads();
      cur ^= 1;
    }
  }

  // ---- store C ----
  #pragma unroll
  for (int nf = 0; nf < 10; nf++) {
    int gn = wc*160 + nf*16 + r;
    #pragma unroll
    for (int q = 0; q < 4; q++) {
      int gm0 = m0 + wr*32 + kg*4 + q;
      if (gm0 < M)       C[(size_t)gm0 * FDIM + gn] = (__bf16)acc0[nf][q];
      int gm1 = gm0 + 16;
      if (gm1 < M)       C[(size_t)gm1 * FDIM + gn] = (__bf16)acc1[nf][q];
    }
  }

  // ---- fused GAT scores ----
  if constexpr (SCORES) {
    #pragma unroll
    for (int th = 0; th < 5; th++) {
      int t = wc * 5 + th;
      float s0 = att_s[t*32 + r],      s1 = att_s[t*32 + 16 + r];
      float d0 = att_d[t*32 + r],      d1 = att_d[t*32 + 16 + r];
      #pragma unroll
      for (int q = 0; q < 4; q++) {
        float ps0 = acc0[2*th][q]*s0 + acc0[2*th+1][q]*s1;
        float ps1 = acc1[2*th][q]*s0 + acc1[2*th+1][q]*s1;
        float pd0 = acc0[2*th][q]*d0 + acc0[2*th+1][q]*d1;
        float pd1 = acc1[2*th][q]*d0 + acc1[2*th+1][q]*d1;
        #pragma unroll
        for (int off = 1; off < 16; off <<= 1) {
          ps0 += __shfl_xor(ps0, off, 16);
          ps1 += __shfl_xor(ps1, off, 16);
          pd0 += __shfl_xor(pd0, off, 16);
          pd1 += __shfl_xor(pd1, off, 16);
        }
        if (r == 0) {
          int row0 = m0 + wr*32 + kg*4 + q;
          if (row0 < M) { as_[row0*NHEADS + t] = ps0; ad_[row0*NHEADS + t] = pd0; }
          int row1 = row0 + 16;
          if (row1 < M) { as_[row1*NHEADS + t] = ps1; ad_[row1*NHEADS + t] = pd1; }
        }
      }
    }
  }
}

// ---------------- generic GEMM (FC layers): C = A*B, f32 in/out ------------
#define BM 128
#define BN 64
#define BK 32
#define LSTR 56

template<int FLAGS>  // bit0: relu, bit1: bias
__global__ __launch_bounds__(256) void gemm_bf16_kernel(
    const float* __restrict__ A, const float* __restrict__ B,
    float* __restrict__ C, const float* __restrict__ bias,
    int M, int N, int K, int ldc)
{
  __shared__ __bf16 As[BM * LSTR];
  __shared__ __bf16 Bs[BN * LSTR];

  const int tid = threadIdx.x;
  const int lane = tid & 63;
  const int w = tid >> 6;
  const int wm = w >> 1, wn = w & 1;
  const int r = lane & 15, kg = lane >> 4;
  const int m0 = blockIdx.x * BM, n0 = blockIdx.y * BN;

  f32x4 acc[4][2];
  #pragma unroll
  for (int i = 0; i < 4; i++)
    #pragma unroll
    for (int j = 0; j < 2; j++)
      acc[i][j] = (f32x4){0.f, 0.f, 0.f, 0.f};

  const int arow = tid >> 1, ahalf = tid & 1;
  const int bk = tid >> 3, bn = (tid & 7) * 8;

  for (int k0 = 0; k0 < K; k0 += BK) {
    __syncthreads();
    {
      int gm = m0 + arow;
      int kbase = k0 + ahalf * 16;
      float tmp[16];
      if (gm < M && kbase + 16 <= K) {
        const float4* ap = (const float4*)(A + (size_t)gm * K + kbase);
        #pragma unroll
        for (int q = 0; q < 4; q++) {
          float4 v = ap[q];
          tmp[q*4+0] = v.x; tmp[q*4+1] = v.y; tmp[q*4+2] = v.z; tmp[q*4+3] = v.w;
        }
      } else {
        #pragma unroll
        for (int q = 0; q < 16; q++) {
          int kk = kbase + q;
          tmp[q] = (gm < M && kk < K) ? A[(size_t)gm * K + kk] : 0.f;
        }
      }
      bf16x8 v0, v1;
      #pragma unroll
      for (int q = 0; q < 8; q++) { v0[q] = (__bf16)tmp[q]; v1[q] = (__bf16)tmp[q+8]; }
      bf16x8* dp = (bf16x8*)&As[arow * LSTR + ahalf * 16];
      dp[0] = v0; dp[1] = v1;
    }
    {
      int gk = k0 + bk;
      float tb[8];
      if (gk < K && n0 + bn + 8 <= N) {
        const float4* bp = (const float4*)(B + (size_t)gk * N + n0 + bn);
        float4 u0 = bp[0], u1 = bp[1];
        tb[0]=u0.x; tb[1]=u0.y; tb[2]=u0.z; tb[3]=u0.w;
        tb[4]=u1.x; tb[5]=u1.y; tb[6]=u1.z; tb[7]=u1.w;
      } else {
        #pragma unroll
        for (int q = 0; q < 8; q++) {
          int gn = n0 + bn + q;
          tb[q] = (gk < K && gn < N) ? B[(size_t)gk * N + gn] : 0.f;
        }
      }
      #pragma unroll
      for (int q = 0; q < 8; q++) Bs[(bn + q) * LSTR + bk] = (__bf16)tb[q];
    }
    __syncthreads();
    bf16x8 af[4], bfr[2];
    #pragma unroll
    for (int mf = 0; mf < 4; mf++)
      af[mf] = *(const bf16x8*)&As[(wm*64 + mf*16 + r) * LSTR + kg*8];
    #pragma unroll
    for (int nf = 0; nf < 2; nf++)
      bfr[nf] = *(const bf16x8*)&Bs[(wn*32 + nf*16 + r) * LSTR + kg*8];
    #pragma unroll
    for (int mf = 0; mf < 4; mf++)
      #pragma unroll
      for (int nf = 0; nf < 2; nf++)
        acc[mf][nf] = __builtin_amdgcn_mfma_f32_16x16x32_bf16(af[mf], bfr[nf], acc[mf][nf], 0, 0, 0);
  }

  #pragma unroll
  for (int mf = 0; mf < 4; mf++) {
    #pragma unroll
    for (int nf = 0; nf < 2; nf++) {
      #pragma unroll
      for (int q = 0; q < 4; q++) {
        int gm = m0 + wm*64 + mf*16 + kg*4 + q;
        int gn = n0 + wn*32 + nf*16 + r;
        if (gm < M && gn < N) {
          float v = acc[mf][nf][q];
          if (FLAGS & 2) v += bias[gn];
          if (FLAGS & 1) v = fmaxf(v, 0.f);
          C[(size_t)gm * ldc + gn] = v;
        }
      }
    }
  }
}

// ---------------- split-K GEMM: P[s][M][N] partials ----------------
__global__ __launch_bounds__(256) void gemm_splitk_kernel(
    const float* __restrict__ A, const float* __restrict__ B,
    float* __restrict__ P, int M, int N, int K, int KS)
{
  __shared__ __bf16 As[BM * LSTR];
  __shared__ __bf16 Bs[BN * LSTR];

  const int tid = threadIdx.x;
  const int lane = tid & 63;
  const int w = tid >> 6;
  const int wm = w >> 1, wn = w & 1;
  const int r = lane & 15, kg = lane >> 4;
  const int m0 = blockIdx.x * BM, n0 = blockIdx.y * BN;
  const int kstart = blockIdx.z * KS;
  const int kend = min(K, kstart + KS);

  f32x4 acc[4][2];
  #pragma unroll
  for (int i = 0; i < 4; i++)
    #pragma unroll
    for (int j = 0; j < 2; j++)
      acc[i][j] = (f32x4){0.f, 0.f, 0.f, 0.f};

  const int arow = tid >> 1, ahalf = tid & 1;
  const int bk = tid >> 3, bn = (tid & 7) * 8;

  for (int k0 = kstart; k0 < kend; k0 += BK) {
    __syncthreads();
    {
      int gm = m0 + arow;
      int kbase = k0 + ahalf * 16;
      float tmp[16];
      if (gm < M && kbase + 16 <= kend) {
        const float4* ap = (const float4*)(A + (size_t)gm * K + kbase);
        #pragma unroll
        for (int q = 0; q < 4; q++) {
          float4 v = ap[q];
          tmp[q*4+0] = v.x; tmp[q*4+1] = v.y; tmp[q*4+2] = v.z; tmp[q*4+3] = v.w;
        }
      } else {
        #pragma unroll
        for (int q = 0; q < 16; q++) {
          int kk = kbase + q;
          tmp[q] = (gm < M && kk < kend) ? A[(size_t)gm * K + kk] : 0.f;
        }
      }
      bf16x8 v0, v1;
      #pragma unroll
      for (int q = 0; q < 8; q++) { v0[q] = (__bf16)tmp[q]; v1[q] = (__bf16)tmp[q+8]; }
      bf16x8* dp = (bf16x8*)&As[arow * LSTR + ahalf * 16];
      dp[0] = v0; dp[1] = v1;
    }
    {
      int gk = k0 + bk;
      float tb[8];
      if (gk < kend && n0 + bn + 8 <= N) {
        const float4* bp = (const float4*)(B + (size_t)gk * N + n0 + bn);
        float4 u0 = bp[0], u1 = bp[1];
        tb[0]=u0.x; tb[1]=u0.y; tb[2]=u0.z; tb[3]=u0.w;
        tb[4]=u1.x; tb[5]=u1.y; tb[6]=u1.z; tb[7]=u1.w;
      } else {
        #pragma unroll
        for (int q = 0; q < 8; q++) {
          int gn = n0 + bn + q;
          tb[q] = (gk < kend && gn < N) ? B[(size_t)gk * N + gn] : 0.f;
        }
      }
      #pragma unroll
      for (int q = 0; q < 8; q++) Bs[(bn + q) * LSTR + bk] = (__bf16)tb[q];
    }
    __syncthreads();
    bf16x8 af[4], bfr[2];
    #pragma unroll
    for (int mf = 0; mf < 4; mf++)
      af[mf] = *(const bf16x8*)&As[(wm*64 + mf*16 + r) * LSTR + kg*8];
    #pragma unroll
    for (int nf = 0; nf < 2; nf++)
      bfr[nf] = *(const bf16x8*)&Bs[(wn*32 + nf*16 + r) * LSTR + kg*8];
    #pragma unroll
    for (int mf = 0; mf < 4; mf++)
      #pragma unroll
      for (int nf = 0; nf < 2; nf++)
        acc[mf][nf] = __builtin_amdgcn_mfma_f32_16x16x32_bf16(af[mf], bfr[nf], acc[mf][nf], 0, 0, 0);
  }

  float* Pp = P + (size_t)blockIdx.z * M * N;
  #pragma unroll
  for (int mf = 0; mf < 4; mf++) {
    #pragma unroll
    for (int nf = 0; nf < 2; nf++) {
      #pragma unroll
      for (int q = 0; q < 4; q++) {
        int gm = m0 + wm*64 + mf*16 + kg*4 + q;
        int gn = n0 + wn*32 + nf*16 + r;
        if (gm < M && gn < N)
          Pp[(size_t)gm * N + gn] = acc[mf][nf][q];
      }
    }
  }
}

// reduce partials; STACK: rows M/2.. go to cols N.. (fc_g2 branch packing)
template<int FLAGS, bool STACK>
__global__ void reduce_kernel(const float* __restrict__ P, float* __restrict__ C,
                              const float* __restrict__ bias, int M, int N, int S, int ldc)
{
  int i = blockIdx.x * 256 + threadIdx.x;
  if (i >= M * N) return;
  float v = 0.f;
  for (int s = 0; s < S; s++) v += P[(size_t)s * M * N + i];
  int row = i / N, col = i - row * N;
  if (FLAGS & 2) v += bias[col];
  if (FLAGS & 1) v = fmaxf(v, 0.f);
  if (STACK) { if (row >= (M >> 1)) { row -= (M >> 1); col += N; } }
  C[(size_t)row * ldc + col] = v;
}

// ---------------- CSR build ----------------
__global__ void count_kernel(const int* __restrict__ dst, int* __restrict__ cnt, int E) {
  int e = blockIdx.x * 256 + threadIdx.x;
  if (e < E) atomicAdd(&cnt[dst[e]], 1);
}

__global__ void bsum_kernel(const int* __restrict__ cnt, int* __restrict__ bsum, int n) {
  __shared__ int wp[4];
  int tid = threadIdx.x, lane = tid & 63, wid = tid >> 6;
  int i = blockIdx.x * 256 + tid;
  int v = (i < n) ? cnt[i] : 0;
  #pragma unroll
  for (int off = 32; off >= 1; off >>= 1) v += __shfl_xor(v, off, 64);
  if (lane == 0) wp[wid] = v;
  __syncthreads();
  if (tid == 0) bsum[blockIdx.x] = wp[0] + wp[1] + wp[2] + wp[3];
}

__global__ void bscan_kernel(int* __restrict__ bsum, int nb) {
  __shared__ int wp[4];
  int tid = threadIdx.x, lane = tid & 63, wid = tid >> 6;
  int v = (tid < nb) ? bsum[tid] : 0;
  int xv = v;
  #pragma unroll
  for (int off = 1; off < 64; off <<= 1) {
    int y = __shfl_up(xv, off, 64);
    if (lane >= off) xv += y;
  }
  if (lane == 63) wp[wid] = xv;
  __syncthreads();
  if (tid == 0) { int s = 0; for (int k = 0; k < 4; k++) { int t = wp[k]; wp[k] = s; s += t; } }
  __syncthreads();
  if (tid < nb) bsum[tid] = wp[wid] + xv - v;   // exclusive
}

__global__ void rpfill_kernel(const int* __restrict__ cnt, const int* __restrict__ bsum,
                              int* __restrict__ rp, float* __restrict__ dinv, int n, int E) {
  __shared__ int wp[4];
  int tid = threadIdx.x, lane = tid & 63, wid = tid >> 6;
  int i = blockIdx.x * 256 + tid;
  int v = (i < n) ? cnt[i] : 0;
  int xv = v;
  #pragma unroll
  for (int off = 1; off < 64; off <<= 1) {
    int y = __shfl_up(xv, off, 64);
    if (lane >= off) xv += y;
  }
  if (lane == 63) wp[wid] = xv;
  __syncthreads();
  if (tid == 0) { int s = 0; for (int k = 0; k < 4; k++) { int t = wp[k]; wp[k] = s; s += t; } }
  __syncthreads();
  if (i < n) {
    rp[i] = bsum[blockIdx.x] + wp[wid] + xv - v;
    dinv[i] = rsqrtf((float)(v + 1));
  }
  if (blockIdx.x == 0 && tid == 0) rp[n] = E;
}

__global__ void fill_kernel(const int* __restrict__ src, const int* __restrict__ dst,
                            const int* __restrict__ rp, int* __restrict__ fil,
                            int* __restrict__ csr, int E) {
  int e = blockIdx.x * 256 + threadIdx.x;
  if (e < E) {
    int d = dst[e];
    int pos = rp[d] + atomicAdd(&fil[d], 1);
    csr[pos] = src[e];
  }
}

// -- GCN aggregate: scalar (SGPR) edge walk + 40-lane wide loads, 4-deep ----
__global__ void gcn_agg_kernel(const __bf16* __restrict__ h, const int* __restrict__ rp,
                               const int* __restrict__ csr, const float* __restrict__ dinv,
                               const float* __restrict__ bias, __bf16* __restrict__ out, int n)
{
  const int lane = threadIdx.x & 63;
  int v0 = blockIdx.x * 4 + (threadIdx.x >> 6);
  if (v0 >= n) return;
  const int v = __builtin_amdgcn_readfirstlane(v0);   // wave-uniform -> SGPR
  const bool act = lane < 40;
  const float dv = dinv[v];
  const int e0 = rp[v], e1 = rp[v + 1];
  float acc[8], bia[8];
  if (act) {
    bf16x8 hv = *(const bf16x8*)(h + (size_t)v * FDIM + 8 * lane);
    const float4* bp = (const float4*)(bias + 8 * lane);
    float4 b0 = bp[0], b1 = bp[1];
    bia[0]=b0.x; bia[1]=b0.y; bia[2]=b0.z; bia[3]=b0.w;
    bia[4]=b1.x; bia[5]=b1.y; bia[6]=b1.z; bia[7]=b1.w;
    #pragma unroll
    for (int j = 0; j < 8; j++) acc[j] = dv * (float)hv[j];
  }
  int e = e0;
  for (; e + 4 <= e1; e += 4) {
    int sj0 = csr[e], sj1 = csr[e+1], sj2 = csr[e+2], sj3 = csr[e+3];   // uniform -> s_load
    float c0 = dinv[sj0], c1 = dinv[sj1], c2 = dinv[sj2], c3 = dinv[sj3];
    if (act) {
      bf16x8 h0 = *(const bf16x8*)(h + (size_t)sj0 * FDIM + 8 * lane);
      bf16x8 h1 = *(const bf16x8*)(h + (size_t)sj1 * FDIM + 8 * lane);
      bf16x8 h2 = *(const bf16x8*)(h + (size_t)sj2 * FDIM + 8 * lane);
      bf16x8 h3 = *(const bf16x8*)(h + (size_t)sj3 * FDIM + 8 * lane);
      #pragma unroll
      for (int j = 0; j < 8; j++)
        acc[j] += c0 * (float)h0[j] + c1 * (float)h1[j]
                + c2 * (float)h2[j] + c3 * (float)h3[j];
    }
  }
  for (; e < e1; e++) {
    int sj = csr[e];
    float cj = dinv[sj];
    if (act) {
      bf16x8 hv = *(const bf16x8*)(h + (size_t)sj * FDIM + 8 * lane);
      #pragma unroll
      for (int j = 0; j < 8; j++) acc[j] += cj * (float)hv[j];
    }
  }
  if (act) {
    bf16x8 o;
    #pragma unroll
    for (int j = 0; j < 8; j++) o[j] = (__bf16)fmaxf(dv * acc[j] + bia[j], 0.f);
    *(bf16x8*)(out + (size_t)v * FDIM + 8 * lane) = o;
  }
}

__device__ __forceinline__ float lrelu(float x) { return x > 0.f ? x : 0.2f * x; }

// ---- softmax stats + materialized alpha: pass1 online (m,den), pass2
// (cache-hot re-walk) writes aint[e][t]; also writes aself ------------------
__global__ void mdenom4_kernel(const int* __restrict__ rp, const int* __restrict__ csr,
                               const float* __restrict__ as_, const float* __restrict__ ad_,
                               float* __restrict__ aint, float* __restrict__ aself, int n)
{
  int tid = blockIdx.x * 256 + threadIdx.x;
  if (tid >= n * NHEADS) return;
  int v = tid / NHEADS, t = tid - v * NHEADS;
  int e0 = rp[v], e1 = rp[v + 1];
  float adv = ad_[tid];
  float esf = lrelu(as_[tid] + adv);
  float m = esf, den = 1.f;
  for (int e = e0; e < e1; e++) {
    int s = csr[e];
    float ev = lrelu(as_[s * NHEADS + t] + adv);
    float nm = fmaxf(m, ev);
    den = den * __expf(m - nm) + __expf(ev - nm);
    m = nm;
  }
  float inv = 1.f / den;
  for (int e = e0; e < e1; e++) {
    int s = csr[e];
    aint[(size_t)e * NHEADS + t] = __expf(lrelu(as_[s * NHEADS + t] + adv) - m) * inv;
  }
  aself[tid] = __expf(esf - m) * inv;
}

// -- GAT aggregate: scalar edge walk, linear aint read, 40-lane wide, 4-deep
__global__ void gat_agg_kernel(const __bf16* __restrict__ h, const int* __restrict__ rp,
                               const int* __restrict__ csr, const float* __restrict__ aint,
                               const float* __restrict__ aself, const float* __restrict__ bias,
                               __bf16* __restrict__ out, int n)
{
  const int lane = threadIdx.x & 63;
  int v0 = blockIdx.x * 4 + (threadIdx.x >> 6);
  if (v0 >= n) return;
  const int v = __builtin_amdgcn_readfirstlane(v0);   // wave-uniform -> SGPR
  const bool act = lane < 40;
  const int hl = lane >> 2;           // head of channels 8*lane..8*lane+7
  const int e0 = rp[v], e1 = rp[v + 1];

  float acc[8], bia[8];
  if (act) {
    float aslf = aself[v * NHEADS + hl];
    bf16x8 hv = *(const bf16x8*)(h + (size_t)v * FDIM + 8 * lane);
    const float4* bp = (const float4*)(bias + 8 * lane);
    float4 b0 = bp[0], b1 = bp[1];
    bia[0]=b0.x; bia[1]=b0.y; bia[2]=b0.z; bia[3]=b0.w;
    bia[4]=b1.x; bia[5]=b1.y; bia[6]=b1.z; bia[7]=b1.w;
    #pragma unroll
    for (int j = 0; j < 8; j++) acc[j] = aslf * (float)hv[j];
  }

  int e = e0;
  for (; e + 4 <= e1; e += 4) {
    int sj0 = csr[e], sj1 = csr[e+1], sj2 = csr[e+2], sj3 = csr[e+3];   // uniform -> s_load
    if (act) {
      float a0 = aint[(size_t)(e+0) * NHEADS + hl];
      float a1 = aint[(size_t)(e+1) * NHEADS + hl];
      float a2 = aint[(size_t)(e+2) * NHEADS + hl];
      float a3 = aint[(size_t)(e+3) * NHEADS + hl];
      bf16x8 h0 = *(const bf16x8*)(h + (size_t)sj0 * FDIM + 8 * lane);
      bf16x8 h1 = *(const bf16x8*)(h + (size_t)sj1 * FDIM + 8 * lane);
      bf16x8 h2 = *(const bf16x8*)(h + (size_t)sj2 * FDIM + 8 * lane);
      bf16x8 h3 = *(const bf16x8*)(h + (size_t)sj3 * FDIM + 8 * lane);
      #pragma unroll
      for (int j = 0; j < 8; j++)
        acc[j] += a0 * (float)h0[j] + a1 * (float)h1[j]
                + a2 * (float)h2[j] + a3 * (float)h3[j];
    }
  }
  for (; e < e1; e++) {
    int sj = csr[e];
    if (act) {
      float al = aint[(size_t)e * NHEADS + hl];
      bf16x8 hv = *(const bf16x8*)(h + (size_t)sj * FDIM + 8 * lane);
      #pragma unroll
      for (int j = 0; j < 8; j++) acc[j] += al * (float)hv[j];
    }
  }
  if (act) {
    bf16x8 o;
    #pragma unroll
    for (int j = 0; j < 8; j++) o[j] = (__bf16)fmaxf(acc[j] + bia[j], 0.f);
    *(bf16x8*)(out + (size_t)v * FDIM + 8 * lane) = o;
  }
}

// ---------------- batch boundaries + pooling ----------------
__global__ void bstart_kernel(const int* __restrict__ batch, int* __restrict__ bstart,
                              int n, int B_) {
  int v = blockIdx.x * 256 + threadIdx.x;
  if (v > n) return;
  int bv = (v < n) ? batch[v] : B_;
  int bp = (v == 0) ? -1 : batch[v - 1];
  for (int gg = bp + 1; gg <= bv; gg++) bstart[gg] = v;
}

// ---- pool v2: block per graph, 4 waves stride nodes, 40-lane bf16x8 -------
__global__ __launch_bounds__(256) void pool_kernel(
    const __bf16* __restrict__ xin, const int* __restrict__ bstart,
    float* __restrict__ g)
{
  __shared__ float pmx[4][FDIM];
  __shared__ float psm[4][FDIM];
  const int gid = blockIdx.x;
  const int lane = threadIdx.x & 63;
  const int wid = threadIdx.x >> 6;
  const bool act = lane < 40;
  const int s = bstart[gid], e = bstart[gid + 1];
  float mx[8], sm[8];
  #pragma unroll
  for (int j = 0; j < 8; j++) { mx[j] = -__builtin_inff(); sm[j] = 0.f; }
  for (int v = s + wid; v < e; v += 4) {
    if (act) {
      bf16x8 hv = *(const bf16x8*)(xin + (size_t)v * FDIM + 8 * lane);
      #pragma unroll
      for (int j = 0; j < 8; j++) {
        float val = (float)hv[j];
        mx[j] = fmaxf(mx[j], val);
        sm[j] += val;
      }
    }
  }
  if (act) {
    #pragma unroll
    for (int j = 0; j < 8; j++) {
      pmx[wid][8 * lane + j] = mx[j];
      psm[wid][8 * lane + j] = sm[j];
    }
  }
  __syncthreads();
  if (wid == 0 && act) {
    float cntf = (float)(e - s);
    float rcnt = 1.f / fmaxf(cntf, 1.f);
    #pragma unroll
    for (int j = 0; j < 8; j++) {
      int c = 8 * lane + j;
      float m2 = fmaxf(fmaxf(pmx[0][c], pmx[1][c]), fmaxf(pmx[2][c], pmx[3][c]));
      float s2 = psm[0][c] + psm[1][c] + psm[2][c] + psm[3][c];
      g[gid * (2 * FDIM) + c] = m2;
      g[gid * (2 * FDIM) + FDIM + c] = s2 * rcnt;
    }
  }
}

// ---------------- launch ----------------
extern "C" void kernel_launch(void* const* d_in, const int* in_sizes, int n_in,
                              void* d_out, int out_size, void* d_ws, size_t ws_size,
                              hipStream_t stream)
{
  const int N = in_sizes[0] / FDIM;
  const int E = in_sizes[2] / 2;
  const int NB = (N + 255) / 256;

  const float* x[2]   = {(const float*)d_in[0], (const float*)d_in[1]};
  const int*   ei[2]  = {(const int*)d_in[2], (const int*)d_in[3]};
  const int*   bat[2] = {(const int*)d_in[4], (const int*)d_in[5]};
  const float* W_gcn   = (const float*)d_in[6];
  const float* b_gcn   = (const float*)d_in[7];
  const float* W_gat   = (const float*)d_in[8];
  const float* att_src = (const float*)d_in[9];
  const float* att_dst = (const float*)d_in[10];
  const float* b_gat   = (const float*)d_in[11];
  const float* W_fc_g1 = (const float*)d_in[12];
  const float* b_fc_g1 = (const float*)d_in[13];
  const float* W_fc_g2 = (const float*)d_in[14];
  const float* b_fc_g2 = (const float*)d_in[15];
  const float* W_fc1   = (const float*)d_in[16];
  const float* b_fc1   = (const float*)d_in[17];
  const float* W_fc2   = (const float*)d_in[18];
  const float* b_fc2   = (const float*)d_in[19];
  const float* W_out   = (const float*)d_in[20];
  const float* b_out   = (const float*)d_in[21];
  float* outp = (float*)d_out;

  char* ws = (char*)d_ws;
  size_t off = 0;
  auto alloc = [&](size_t bytes) -> char* {
    char* p = ws + off;
    off += (bytes + 255) & ~(size_t)255;
    return p;
  };
  int*    cnt    = (int*)alloc((size_t)N * 4);
  int*    fil    = (int*)alloc((size_t)N * 4);
  size_t  zero_span = (size_t)((char*)fil - (char*)cnt) + ((size_t)N * 4 + 255 & ~(size_t)255);
  int*    rp     = (int*)alloc((size_t)(N + 1) * 4);
  int*    bsum   = (int*)alloc((size_t)NB * 4);
  int*    csr    = (int*)alloc((size_t)E * 4);
  float*  dinv   = (float*)alloc((size_t)N * 4);
  int*    bstart = (int*)alloc((size_t)(NGR + 1) * 4);
  __bf16* WgcnT  = (__bf16*)alloc((size_t)FDIM * FDIM * 2);
  __bf16* WgatT  = (__bf16*)alloc((size_t)FDIM * FDIM * 2);
  __bf16* hbuf   = (__bf16*)alloc((size_t)N * FDIM * 2);
  __bf16* xbuf   = (__bf16*)alloc((size_t)N * FDIM * 2);
  float*  as_    = (float*)alloc((size_t)N * NHEADS * 4);
  float*  ad_    = (float*)alloc((size_t)N * NHEADS * 4);
  float*  aint   = (float*)alloc((size_t)E * NHEADS * 4);
  float*  aself  = (float*)alloc((size_t)N * NHEADS * 4);
  float*  g      = (float*)alloc((size_t)2 * NGR * 2 * FDIM * 4);   // both branches
  float*  t1     = (float*)alloc((size_t)2 * NGR * 1500 * 4);       // both branches
  float*  xc     = (float*)alloc((size_t)NGR * 256 * 4);
  float*  t2     = (float*)alloc((size_t)NGR * 1024 * 4);
  float*  t3     = (float*)alloc((size_t)NGR * 512 * 4);
  float*  part   = (float*)alloc((size_t)8 * 512 * 512 * 4);        // split-K partials (8 MB)
  if (off > ws_size) return;  // workspace too small: bail (visible as absmax fail)

  wconv2_kernel<<<2 * (FDIM * FDIM) / 256, 256, 0, stream>>>(W_gcn, W_gat, WgcnT, WgatT);

  for (int br = 0; br < 2; br++) {
    hipMemsetAsync(cnt, 0, zero_span, stream);
    const int* srcp = ei[br];
    const int* dstp = ei[br] + E;
    count_kernel<<<(E + 255) / 256, 256, 0, stream>>>(dstp, cnt, E);
    bsum_kernel<<<NB, 256, 0, stream>>>(cnt, bsum, N);
    bscan_kernel<<<1, 256, 0, stream>>>(bsum, NB);
    rpfill_kernel<<<NB, 256, 0, stream>>>(cnt, bsum, rp, dinv, N, E);
    fill_kernel<<<(E + 255) / 256, 256, 0, stream>>>(srcp, dstp, rp, fil, csr, E);

    int g320 = (N + 63) / 64;
    gemm320v3_kernel<float, false><<<g320, 256, 0, stream>>>(
        x[br], WgcnT, hbuf, N, nullptr, nullptr, nullptr, nullptr);
    gcn_agg_kernel<<<(N + 3) / 4, 256, 0, stream>>>(hbuf, rp, csr, dinv, b_gcn, xbuf, N);
    gemm320v3_kernel<__bf16, true><<<g320, 256, 0, stream>>>(
        xbuf, WgatT, hbuf, N, att_src, att_dst, as_, ad_);

    mdenom4_kernel<<<(N * NHEADS + 255) / 256, 256, 0, stream>>>(rp, csr, as_, ad_, aint, aself, N);
    gat_agg_kernel<<<(N + 3) / 4, 256, 0, stream>>>(hbuf, rp, csr, aint, aself, b_gat, xbuf, N);

    bstart_kernel<<<(N + 256) / 256, 256, 0, stream>>>(bat[br], bstart, N, NGR);
    pool_kernel<<<NGR, 256, 0, stream>>>(xbuf, bstart, g + (size_t)br * NGR * 2 * FDIM);
  }

  // ---- batched FC head: M=512 covers both branches ----
  {
    dim3 gfc1((512 + BM - 1) / BM, (1500 + BN - 1) / BN);
    gemm_bf16_kernel<3><<<gfc1, 256, 0, stream>>>(g, W_fc_g1, t1, b_fc_g1, 512, 1500, 2 * FDIM, 1500);
    int S = 8, KS = ((1500 + S * BK - 1) / (S * BK)) * BK;
    dim3 gfc2((512 + BM - 1) / BM, (128 + BN - 1) / BN, S);
    gemm_splitk_kernel<<<gfc2, 256, 0, stream>>>(t1, W_fc_g2, part, 512, 128, 1500, KS);
    reduce_kernel<2, true><<<(512 * 128 + 255) / 256, 256, 0, stream>>>(part, xc, b_fc_g2, 512, 128, S, 256);
  }
  {
    dim3 gx1((NGR + BM - 1) / BM, (1024 + BN - 1) / BN);
    gemm_bf16_kernel<3><<<gx1, 256, 0, stream>>>(xc, W_fc1, t2, b_fc1, NGR, 1024, 256, 1024);
    int S = 4, KS = ((1024 + S * BK - 1) / (S * BK)) * BK;
    dim3 gx2((NGR + BM - 1) / BM, (512 + BN - 1) / BN, S);
    gemm_splitk_kernel<<<gx2, 256, 0, stream>>>(t2, W_fc2, part, NGR, 512, 1024, KS);
    reduce_kernel<3, false><<<(NGR * 512 + 255) / 256, 256, 0, stream>>>(part, t3, b_fc2, NGR, 512, S, 512);
    int S2 = 4, KS2 = ((512 + S2 * BK - 1) / (S2 * BK)) * BK;
    dim3 gx3((NGR + BM - 1) / BM, 1, S2);
    gemm_splitk_kernel<<<gx3, 256, 0, stream>>>(t3, W_out, part, NGR, 2, 512, KS2);
    reduce_kernel<2, false><<<(NGR * 2 + 255) / 256, 256, 0, stream>>>(part, outp, b_out, NGR, 2, S2, 2);
  }
}

// Round 14
// 612.071 us; speedup vs baseline: 1.2248x; 1.0716x over previous
//
#include <hip/hip_runtime.h>
#include <type_traits>

#define FDIM 320
#define NHEADS 10
#define NGR 256

typedef __bf16 bf16x8 __attribute__((ext_vector_type(8)));
typedef float f32x4 __attribute__((ext_vector_type(4)));

// ---------------- weight transpose+convert (both weights, one launch) ------
__global__ void wconv2_kernel(const float* __restrict__ Wg, const float* __restrict__ Wa,
                              __bf16* __restrict__ Tg, __bf16* __restrict__ Ta) {
  int idx = blockIdx.x * 256 + threadIdx.x;
  bool first = idx < FDIM * FDIM;
  const float* W = first ? Wg : Wa;
  __bf16* T = first ? Tg : Ta;
  int i2 = first ? idx : idx - FDIM * FDIM;
  int k = i2 / FDIM, c = i2 - k * FDIM;
  T[c * FDIM + k] = (__bf16)W[i2];
}

// ---------------- node GEMM v3 (merged branches): full-N, LDS dbuf ---------
#define GLSTR 40

template<typename TA, bool SCORES>
__global__ __launch_bounds__(256, 2) void gemm320v3_kernel(
    const TA* __restrict__ A, const TA* __restrict__ A2, int Npad, int Nreal,
    const __bf16* __restrict__ Wt, __bf16* __restrict__ C,
    const float* __restrict__ att_s, const float* __restrict__ att_d,
    float* __restrict__ as_, float* __restrict__ ad_)
{
  __shared__ __bf16 As[2][64 * GLSTR];
  __shared__ __bf16 Bs[2][320 * GLSTR];

  const int tid = threadIdx.x;
  const int lane = tid & 63;
  const int w = tid >> 6;
  const int wr = w >> 1, wc = w & 1;
  const int r = lane & 15, kg = lane >> 4;
  const int m0 = blockIdx.x * 64;          // global row base
  const bool brB = m0 >= Npad;             // Npad % 64 == 0 -> block uniform
  const int loff = brB ? Npad : 0;

  const int brow = tid >> 2, bq = tid & 3;
  const int grow = m0 + brow;
  const int lrow = grow - loff;
  const bool arow_ok = lrow < Nreal;

  bf16x8 bstg[5];
  bf16x8 astg;
  float4 af32a, af32b;

  auto stage_load = [&](int k0) {
    #pragma unroll
    for (int i = 0; i < 5; i++) {
      int ch = tid + i * 256;
      int col = ch >> 2, kc = ch & 3;
      bstg[i] = *(const bf16x8*)(Wt + (size_t)col * FDIM + k0 + kc * 8);
    }
    if constexpr (std::is_same_v<TA, float>) {
      if (arow_ok) {
        const float* Ab = brB ? A2 : A;
        const float4* ap = (const float4*)(Ab + (size_t)lrow * FDIM + k0 + bq * 8);
        af32a = ap[0]; af32b = ap[1];
      }
    } else {
      if (arow_ok) astg = *(const bf16x8*)(A + (size_t)grow * FDIM + k0 + bq * 8);
    }
  };
  auto stage_write = [&](int b) {
    #pragma unroll
    for (int i = 0; i < 5; i++) {
      int ch = tid + i * 256;
      int col = ch >> 2, kc = ch & 3;
      *(bf16x8*)&Bs[b][col * GLSTR + kc * 8] = bstg[i];
    }
    bf16x8 v = {};
    if constexpr (std::is_same_v<TA, float>) {
      if (arow_ok) {
        v[0]=(__bf16)af32a.x; v[1]=(__bf16)af32a.y; v[2]=(__bf16)af32a.z; v[3]=(__bf16)af32a.w;
        v[4]=(__bf16)af32b.x; v[5]=(__bf16)af32b.y; v[6]=(__bf16)af32b.z; v[7]=(__bf16)af32b.w;
      }
    } else {
      if (arow_ok) v = astg;
    }
    *(bf16x8*)&As[b][brow * GLSTR + bq * 8] = v;
  };

  f32x4 acc0[10], acc1[10];
  #pragma unroll
  for (int i = 0; i < 10; i++) { acc0[i] = (f32x4){0,0,0,0}; acc1[i] = (f32x4){0,0,0,0}; }

  stage_load(0);
  stage_write(0);
  __syncthreads();

  int cur = 0;
  for (int k = 0; k < 10; k++) {
    if (k < 9) stage_load((k + 1) * 32);
    {
      bf16x8 a0 = *(const bf16x8*)&As[cur][(wr*32 + r)      * GLSTR + kg*8];
      bf16x8 a1 = *(const bf16x8*)&As[cur][(wr*32 + 16 + r) * GLSTR + kg*8];
      #pragma unroll
      for (int nf = 0; nf < 10; nf++) {
        bf16x8 b = *(const bf16x8*)&Bs[cur][(wc*160 + nf*16 + r) * GLSTR + kg*8];
        acc0[nf] = __builtin_amdgcn_mfma_f32_16x16x32_bf16(a0, b, acc0[nf], 0, 0, 0);
        acc1[nf] = __builtin_amdgcn_mfma_f32_16x16x32_bf16(a1, b, acc1[nf], 0, 0, 0);
      }
    }
    if (k < 9) {
      stage_write(cur ^ 1);
      __syncthreads();
      cur ^= 1;
    }
  }

  // ---- store C (global rows, local validity) ----
  #pragma unroll
  for (int nf = 0; nf < 10; nf++) {
    int gn = wc*160 + nf*16 + r;
    #pragma unroll
    for (int q = 0; q < 4; q++) {
      int gm0 = m0 + wr*32 + kg*4 + q;
      if (gm0 - loff < Nreal) C[(size_t)gm0 * FDIM + gn] = (__bf16)acc0[nf][q];
      int gm1 = gm0 + 16;
      if (gm1 - loff < Nreal) C[(size_t)gm1 * FDIM + gn] = (__bf16)acc1[nf][q];
    }
  }

  // ---- fused GAT scores ----
  if constexpr (SCORES) {
    #pragma unroll
    for (int th = 0; th < 5; th++) {
      int t = wc * 5 + th;
      float s0 = att_s[t*32 + r],      s1 = att_s[t*32 + 16 + r];
      float d0 = att_d[t*32 + r],      d1 = att_d[t*32 + 16 + r];
      #pragma unroll
      for (int q = 0; q < 4; q++) {
        float ps0 = acc0[2*th][q]*s0 + acc0[2*th+1][q]*s1;
        float ps1 = acc1[2*th][q]*s0 + acc1[2*th+1][q]*s1;
        float pd0 = acc0[2*th][q]*d0 + acc0[2*th+1][q]*d1;
        float pd1 = acc1[2*th][q]*d0 + acc1[2*th+1][q]*d1;
        #pragma unroll
        for (int off = 1; off < 16; off <<= 1) {
          ps0 += __shfl_xor(ps0, off, 16);
          ps1 += __shfl_xor(ps1, off, 16);
          pd0 += __shfl_xor(pd0, off, 16);
          pd1 += __shfl_xor(pd1, off, 16);
        }
        if (r == 0) {
          int row0 = m0 + wr*32 + kg*4 + q;
          if (row0 - loff < Nreal) { as_[row0*NHEADS + t] = ps0; ad_[row0*NHEADS + t] = pd0; }
          int row1 = row0 + 16;
          if (row1 - loff < Nreal) { as_[row1*NHEADS + t] = ps1; ad_[row1*NHEADS + t] = pd1; }
        }
      }
    }
  }
}

// ---------------- generic GEMM (FC layers): C = A*B, f32 in/out ------------
#define BM 128
#define BN 64
#define BK 32
#define LSTR 56

template<int FLAGS>  // bit0: relu, bit1: bias
__global__ __launch_bounds__(256) void gemm_bf16_kernel(
    const float* __restrict__ A, const float* __restrict__ B,
    float* __restrict__ C, const float* __restrict__ bias,
    int M, int N, int K, int ldc)
{
  __shared__ __bf16 As[BM * LSTR];
  __shared__ __bf16 Bs[BN * LSTR];

  const int tid = threadIdx.x;
  const int lane = tid & 63;
  const int w = tid >> 6;
  const int wm = w >> 1, wn = w & 1;
  const int r = lane & 15, kg = lane >> 4;
  const int m0 = blockIdx.x * BM, n0 = blockIdx.y * BN;

  f32x4 acc[4][2];
  #pragma unroll
  for (int i = 0; i < 4; i++)
    #pragma unroll
    for (int j = 0; j < 2; j++)
      acc[i][j] = (f32x4){0.f, 0.f, 0.f, 0.f};

  const int arow = tid >> 1, ahalf = tid & 1;
  const int bk = tid >> 3, bn = (tid & 7) * 8;

  for (int k0 = 0; k0 < K; k0 += BK) {
    __syncthreads();
    {
      int gm = m0 + arow;
      int kbase = k0 + ahalf * 16;
      float tmp[16];
      if (gm < M && kbase + 16 <= K) {
        const float4* ap = (const float4*)(A + (size_t)gm * K + kbase);
        #pragma unroll
        for (int q = 0; q < 4; q++) {
          float4 v = ap[q];
          tmp[q*4+0] = v.x; tmp[q*4+1] = v.y; tmp[q*4+2] = v.z; tmp[q*4+3] = v.w;
        }
      } else {
        #pragma unroll
        for (int q = 0; q < 16; q++) {
          int kk = kbase + q;
          tmp[q] = (gm < M && kk < K) ? A[(size_t)gm * K + kk] : 0.f;
        }
      }
      bf16x8 v0, v1;
      #pragma unroll
      for (int q = 0; q < 8; q++) { v0[q] = (__bf16)tmp[q]; v1[q] = (__bf16)tmp[q+8]; }
      bf16x8* dp = (bf16x8*)&As[arow * LSTR + ahalf * 16];
      dp[0] = v0; dp[1] = v1;
    }
    {
      int gk = k0 + bk;
      float tb[8];
      if (gk < K && n0 + bn + 8 <= N) {
        const float4* bp = (const float4*)(B + (size_t)gk * N + n0 + bn);
        float4 u0 = bp[0], u1 = bp[1];
        tb[0]=u0.x; tb[1]=u0.y; tb[2]=u0.z; tb[3]=u0.w;
        tb[4]=u1.x; tb[5]=u1.y; tb[6]=u1.z; tb[7]=u1.w;
      } else {
        #pragma unroll
        for (int q = 0; q < 8; q++) {
          int gn = n0 + bn + q;
          tb[q] = (gk < K && gn < N) ? B[(size_t)gk * N + gn] : 0.f;
        }
      }
      #pragma unroll
      for (int q = 0; q < 8; q++) Bs[(bn + q) * LSTR + bk] = (__bf16)tb[q];
    }
    __syncthreads();
    bf16x8 af[4], bfr[2];
    #pragma unroll
    for (int mf = 0; mf < 4; mf++)
      af[mf] = *(const bf16x8*)&As[(wm*64 + mf*16 + r) * LSTR + kg*8];
    #pragma unroll
    for (int nf = 0; nf < 2; nf++)
      bfr[nf] = *(const bf16x8*)&Bs[(wn*32 + nf*16 + r) * LSTR + kg*8];
    #pragma unroll
    for (int mf = 0; mf < 4; mf++)
      #pragma unroll
      for (int nf = 0; nf < 2; nf++)
        acc[mf][nf] = __builtin_amdgcn_mfma_f32_16x16x32_bf16(af[mf], bfr[nf], acc[mf][nf], 0, 0, 0);
  }

  #pragma unroll
  for (int mf = 0; mf < 4; mf++) {
    #pragma unroll
    for (int nf = 0; nf < 2; nf++) {
      #pragma unroll
      for (int q = 0; q < 4; q++) {
        int gm = m0 + wm*64 + mf*16 + kg*4 + q;
        int gn = n0 + wn*32 + nf*16 + r;
        if (gm < M && gn < N) {
          float v = acc[mf][nf][q];
          if (FLAGS & 2) v += bias[gn];
          if (FLAGS & 1) v = fmaxf(v, 0.f);
          C[(size_t)gm * ldc + gn] = v;
        }
      }
    }
  }
}

// ---------------- split-K GEMM: P[s][M][N] partials ----------------
__global__ __launch_bounds__(256) void gemm_splitk_kernel(
    const float* __restrict__ A, const float* __restrict__ B,
    float* __restrict__ P, int M, int N, int K, int KS)
{
  __shared__ __bf16 As[BM * LSTR];
  __shared__ __bf16 Bs[BN * LSTR];

  const int tid = threadIdx.x;
  const int lane = tid & 63;
  const int w = tid >> 6;
  const int wm = w >> 1, wn = w & 1;
  const int r = lane & 15, kg = lane >> 4;
  const int m0 = blockIdx.x * BM, n0 = blockIdx.y * BN;
  const int kstart = blockIdx.z * KS;
  const int kend = min(K, kstart + KS);

  f32x4 acc[4][2];
  #pragma unroll
  for (int i = 0; i < 4; i++)
    #pragma unroll
    for (int j = 0; j < 2; j++)
      acc[i][j] = (f32x4){0.f, 0.f, 0.f, 0.f};

  const int arow = tid >> 1, ahalf = tid & 1;
  const int bk = tid >> 3, bn = (tid & 7) * 8;

  for (int k0 = kstart; k0 < kend; k0 += BK) {
    __syncthreads();
    {
      int gm = m0 + arow;
      int kbase = k0 + ahalf * 16;
      float tmp[16];
      if (gm < M && kbase + 16 <= kend) {
        const float4* ap = (const float4*)(A + (size_t)gm * K + kbase);
        #pragma unroll
        for (int q = 0; q < 4; q++) {
          float4 v = ap[q];
          tmp[q*4+0] = v.x; tmp[q*4+1] = v.y; tmp[q*4+2] = v.z; tmp[q*4+3] = v.w;
        }
      } else {
        #pragma unroll
        for (int q = 0; q < 16; q++) {
          int kk = kbase + q;
          tmp[q] = (gm < M && kk < kend) ? A[(size_t)gm * K + kk] : 0.f;
        }
      }
      bf16x8 v0, v1;
      #pragma unroll
      for (int q = 0; q < 8; q++) { v0[q] = (__bf16)tmp[q]; v1[q] = (__bf16)tmp[q+8]; }
      bf16x8* dp = (bf16x8*)&As[arow * LSTR + ahalf * 16];
      dp[0] = v0; dp[1] = v1;
    }
    {
      int gk = k0 + bk;
      float tb[8];
      if (gk < kend && n0 + bn + 8 <= N) {
        const float4* bp = (const float4*)(B + (size_t)gk * N + n0 + bn);
        float4 u0 = bp[0], u1 = bp[1];
        tb[0]=u0.x; tb[1]=u0.y; tb[2]=u0.z; tb[3]=u0.w;
        tb[4]=u1.x; tb[5]=u1.y; tb[6]=u1.z; tb[7]=u1.w;
      } else {
        #pragma unroll
        for (int q = 0; q < 8; q++) {
          int gn = n0 + bn + q;
          tb[q] = (gk < kend && gn < N) ? B[(size_t)gk * N + gn] : 0.f;
        }
      }
      #pragma unroll
      for (int q = 0; q < 8; q++) Bs[(bn + q) * LSTR + bk] = (__bf16)tb[q];
    }
    __syncthreads();
    bf16x8 af[4], bfr[2];
    #pragma unroll
    for (int mf = 0; mf < 4; mf++)
      af[mf] = *(const bf16x8*)&As[(wm*64 + mf*16 + r) * LSTR + kg*8];
    #pragma unroll
    for (int nf = 0; nf < 2; nf++)
      bfr[nf] = *(const bf16x8*)&Bs[(wn*32 + nf*16 + r) * LSTR + kg*8];
    #pragma unroll
    for (int mf = 0; mf < 4; mf++)
      #pragma unroll
      for (int nf = 0; nf < 2; nf++)
        acc[mf][nf] = __builtin_amdgcn_mfma_f32_16x16x32_bf16(af[mf], bfr[nf], acc[mf][nf], 0, 0, 0);
  }

  float* Pp = P + (size_t)blockIdx.z * M * N;
  #pragma unroll
  for (int mf = 0; mf < 4; mf++) {
    #pragma unroll
    for (int nf = 0; nf < 2; nf++) {
      #pragma unroll
      for (int q = 0; q < 4; q++) {
        int gm = m0 + wm*64 + mf*16 + kg*4 + q;
        int gn = n0 + wn*32 + nf*16 + r;
        if (gm < M && gn < N)
          Pp[(size_t)gm * N + gn] = acc[mf][nf][q];
      }
    }
  }
}

// reduce partials; STACK: rows M/2.. go to cols N.. (fc_g2 branch packing)
template<int FLAGS, bool STACK>
__global__ void reduce_kernel(const float* __restrict__ P, float* __restrict__ C,
                              const float* __restrict__ bias, int M, int N, int S, int ldc)
{
  int i = blockIdx.x * 256 + threadIdx.x;
  if (i >= M * N) return;
  float v = 0.f;
  for (int s = 0; s < S; s++) v += P[(size_t)s * M * N + i];
  int row = i / N, col = i - row * N;
  if (FLAGS & 2) v += bias[col];
  if (FLAGS & 1) v = fmaxf(v, 0.f);
  if (STACK) { if (row >= (M >> 1)) { row -= (M >> 1); col += N; } }
  C[(size_t)row * ldc + col] = v;
}

// ---------------- CSR build (merged branches) ----------------
__global__ void count_kernel(const int* __restrict__ dst_a, const int* __restrict__ dst_b,
                             int* __restrict__ cnt, int E, int Npad) {
  int e = blockIdx.x * 256 + threadIdx.x;
  if (e < E) atomicAdd(&cnt[dst_a[e]], 1);
  else if (e < 2 * E) atomicAdd(&cnt[dst_b[e - E] + Npad], 1);
}

__global__ void bsum_kernel(const int* __restrict__ cnt, int* __restrict__ bsum, int n) {
  __shared__ int wp[4];
  int tid = threadIdx.x, lane = tid & 63, wid = tid >> 6;
  int i = blockIdx.x * 256 + tid;
  int v = (i < n) ? cnt[i] : 0;
  #pragma unroll
  for (int off = 32; off >= 1; off >>= 1) v += __shfl_xor(v, off, 64);
  if (lane == 0) wp[wid] = v;
  __syncthreads();
  if (tid == 0) bsum[blockIdx.x] = wp[0] + wp[1] + wp[2] + wp[3];
}

__global__ __launch_bounds__(1024) void bscan_kernel(int* __restrict__ bsum, int nb) {
  __shared__ int wp[16];
  int tid = threadIdx.x, lane = tid & 63, wid = tid >> 6;
  int v = (tid < nb) ? bsum[tid] : 0;
  int xv = v;
  #pragma unroll
  for (int off = 1; off < 64; off <<= 1) {
    int y = __shfl_up(xv, off, 64);
    if (lane >= off) xv += y;
  }
  if (lane == 63) wp[wid] = xv;
  __syncthreads();
  if (tid == 0) { int s = 0; for (int k = 0; k < 16; k++) { int t = wp[k]; wp[k] = s; s += t; } }
  __syncthreads();
  if (tid < nb) bsum[tid] = wp[wid] + xv - v;   // exclusive
}

__global__ void rpfill_kernel(const int* __restrict__ cnt, const int* __restrict__ bsum,
                              int* __restrict__ rp, float* __restrict__ dinv, int n, int E2) {
  __shared__ int wp[4];
  int tid = threadIdx.x, lane = tid & 63, wid = tid >> 6;
  int i = blockIdx.x * 256 + tid;
  int v = (i < n) ? cnt[i] : 0;
  int xv = v;
  #pragma unroll
  for (int off = 1; off < 64; off <<= 1) {
    int y = __shfl_up(xv, off, 64);
    if (lane >= off) xv += y;
  }
  if (lane == 63) wp[wid] = xv;
  __syncthreads();
  if (tid == 0) { int s = 0; for (int k = 0; k < 4; k++) { int t = wp[k]; wp[k] = s; s += t; } }
  __syncthreads();
  if (i < n) {
    rp[i] = bsum[blockIdx.x] + wp[wid] + xv - v;
    dinv[i] = rsqrtf((float)(v + 1));
  }
  if (blockIdx.x == 0 && tid == 0) rp[n] = E2;
}

__global__ void fill_kernel(const int* __restrict__ sa, const int* __restrict__ da,
                            const int* __restrict__ sb, const int* __restrict__ db,
                            const int* __restrict__ rp, int* __restrict__ fil,
                            int* __restrict__ csr, int E, int Npad) {
  int e = blockIdx.x * 256 + threadIdx.x;
  if (e >= 2 * E) return;
  int s, d;
  if (e < E) { s = sa[e]; d = da[e]; }
  else       { s = sb[e - E] + Npad; d = db[e - E] + Npad; }
  int pos = rp[d] + atomicAdd(&fil[d], 1);
  csr[pos] = s;
}

// -- GCN aggregate: scalar (SGPR) edge walk + 40-lane wide loads, 4-deep ----
__global__ void gcn_agg_kernel(const __bf16* __restrict__ h, const int* __restrict__ rp,
                               const int* __restrict__ csr, const float* __restrict__ dinv,
                               const float* __restrict__ bias, __bf16* __restrict__ out,
                               int n2, int Npad, int Nreal)
{
  const int lane = threadIdx.x & 63;
  int v0 = blockIdx.x * 4 + (threadIdx.x >> 6);
  if (v0 >= n2) return;
  const int v = __builtin_amdgcn_readfirstlane(v0);
  const int lv = (v >= Npad) ? v - Npad : v;
  if (lv >= Nreal) return;
  const bool act = lane < 40;
  const float dv = dinv[v];
  const int e0 = rp[v], e1 = rp[v + 1];
  float acc[8], bia[8];
  if (act) {
    bf16x8 hv = *(const bf16x8*)(h + (size_t)v * FDIM + 8 * lane);
    const float4* bp = (const float4*)(bias + 8 * lane);
    float4 b0 = bp[0], b1 = bp[1];
    bia[0]=b0.x; bia[1]=b0.y; bia[2]=b0.z; bia[3]=b0.w;
    bia[4]=b1.x; bia[5]=b1.y; bia[6]=b1.z; bia[7]=b1.w;
    #pragma unroll
    for (int j = 0; j < 8; j++) acc[j] = dv * (float)hv[j];
  }
  int e = e0;
  for (; e + 4 <= e1; e += 4) {
    int sj0 = csr[e], sj1 = csr[e+1], sj2 = csr[e+2], sj3 = csr[e+3];
    float c0 = dinv[sj0], c1 = dinv[sj1], c2 = dinv[sj2], c3 = dinv[sj3];
    if (act) {
      bf16x8 h0 = *(const bf16x8*)(h + (size_t)sj0 * FDIM + 8 * lane);
      bf16x8 h1 = *(const bf16x8*)(h + (size_t)sj1 * FDIM + 8 * lane);
      bf16x8 h2 = *(const bf16x8*)(h + (size_t)sj2 * FDIM + 8 * lane);
      bf16x8 h3 = *(const bf16x8*)(h + (size_t)sj3 * FDIM + 8 * lane);
      #pragma unroll
      for (int j = 0; j < 8; j++)
        acc[j] += c0 * (float)h0[j] + c1 * (float)h1[j]
                + c2 * (float)h2[j] + c3 * (float)h3[j];
    }
  }
  for (; e < e1; e++) {
    int sj = csr[e];
    float cj = dinv[sj];
    if (act) {
      bf16x8 hv = *(const bf16x8*)(h + (size_t)sj * FDIM + 8 * lane);
      #pragma unroll
      for (int j = 0; j < 8; j++) acc[j] += cj * (float)hv[j];
    }
  }
  if (act) {
    bf16x8 o;
    #pragma unroll
    for (int j = 0; j < 8; j++) o[j] = (__bf16)fmaxf(dv * acc[j] + bia[j], 0.f);
    *(bf16x8*)(out + (size_t)v * FDIM + 8 * lane) = o;
  }
}

__device__ __forceinline__ float lrelu(float x) { return x > 0.f ? x : 0.2f * x; }

// ---- softmax stats + materialized alpha (f32), merged node space ----------
__global__ void mdenom4_kernel(const int* __restrict__ rp, const int* __restrict__ csr,
                               const float* __restrict__ as_, const float* __restrict__ ad_,
                               float* __restrict__ aint, float* __restrict__ aself,
                               int n2, int Npad, int Nreal)
{
  int tid = blockIdx.x * 256 + threadIdx.x;
  if (tid >= n2 * NHEADS) return;
  int v = tid / NHEADS, t = tid - v * NHEADS;
  int lv = (v >= Npad) ? v - Npad : v;
  if (lv >= Nreal) return;
  int e0 = rp[v], e1 = rp[v + 1];
  float adv = ad_[tid];
  float esf = lrelu(as_[tid] + adv);
  float m = esf, den = 1.f;
  for (int e = e0; e < e1; e++) {
    int s = csr[e];
    float ev = lrelu(as_[s * NHEADS + t] + adv);
    float nm = fmaxf(m, ev);
    den = den * __expf(m - nm) + __expf(ev - nm);
    m = nm;
  }
  float inv = 1.f / den;
  for (int e = e0; e < e1; e++) {
    int s = csr[e];
    aint[(size_t)e * NHEADS + t] = __expf(lrelu(as_[s * NHEADS + t] + adv) - m) * inv;
  }
  aself[tid] = __expf(esf - m) * inv;
}

// -- GAT aggregate: scalar edge walk, linear aint read, 40-lane wide, 4-deep
__global__ void gat_agg_kernel(const __bf16* __restrict__ h, const int* __restrict__ rp,
                               const int* __restrict__ csr, const float* __restrict__ aint,
                               const float* __restrict__ aself, const float* __restrict__ bias,
                               __bf16* __restrict__ out, int n2, int Npad, int Nreal)
{
  const int lane = threadIdx.x & 63;
  int v0 = blockIdx.x * 4 + (threadIdx.x >> 6);
  if (v0 >= n2) return;
  const int v = __builtin_amdgcn_readfirstlane(v0);
  const int lv = (v >= Npad) ? v - Npad : v;
  if (lv >= Nreal) return;
  const bool act = lane < 40;
  const int hl = lane >> 2;
  const int e0 = rp[v], e1 = rp[v + 1];

  float acc[8], bia[8];
  if (act) {
    float aslf = aself[v * NHEADS + hl];
    bf16x8 hv = *(const bf16x8*)(h + (size_t)v * FDIM + 8 * lane);
    const float4* bp = (const float4*)(bias + 8 * lane);
    float4 b0 = bp[0], b1 = bp[1];
    bia[0]=b0.x; bia[1]=b0.y; bia[2]=b0.z; bia[3]=b0.w;
    bia[4]=b1.x; bia[5]=b1.y; bia[6]=b1.z; bia[7]=b1.w;
    #pragma unroll
    for (int j = 0; j < 8; j++) acc[j] = aslf * (float)hv[j];
  }

  int e = e0;
  for (; e + 4 <= e1; e += 4) {
    int sj0 = csr[e], sj1 = csr[e+1], sj2 = csr[e+2], sj3 = csr[e+3];
    if (act) {
      float a0 = aint[(size_t)(e+0) * NHEADS + hl];
      float a1 = aint[(size_t)(e+1) * NHEADS + hl];
      float a2 = aint[(size_t)(e+2) * NHEADS + hl];
      float a3 = aint[(size_t)(e+3) * NHEADS + hl];
      bf16x8 h0 = *(const bf16x8*)(h + (size_t)sj0 * FDIM + 8 * lane);
      bf16x8 h1 = *(const bf16x8*)(h + (size_t)sj1 * FDIM + 8 * lane);
      bf16x8 h2 = *(const bf16x8*)(h + (size_t)sj2 * FDIM + 8 * lane);
      bf16x8 h3 = *(const bf16x8*)(h + (size_t)sj3 * FDIM + 8 * lane);
      #pragma unroll
      for (int j = 0; j < 8; j++)
        acc[j] += a0 * (float)h0[j] + a1 * (float)h1[j]
                + a2 * (float)h2[j] + a3 * (float)h3[j];
    }
  }
  for (; e < e1; e++) {
    int sj = csr[e];
    if (act) {
      float al = aint[(size_t)e * NHEADS + hl];
      bf16x8 hv = *(const bf16x8*)(h + (size_t)sj * FDIM + 8 * lane);
      #pragma unroll
      for (int j = 0; j < 8; j++) acc[j] += al * (float)hv[j];
    }
  }
  if (act) {
    bf16x8 o;
    #pragma unroll
    for (int j = 0; j < 8; j++) o[j] = (__bf16)fmaxf(acc[j] + bia[j], 0.f);
    *(bf16x8*)(out + (size_t)v * FDIM + 8 * lane) = o;
  }
}

// ---------------- batch boundaries (merged) + pooling ----------------
__global__ void bstart_kernel(const int* __restrict__ ba, const int* __restrict__ bb,
                              int* __restrict__ bst, int n, int Npad) {
  int idx = blockIdx.x * 256 + threadIdx.x;
  if (idx >= 2 * (n + 1)) return;
  int br = idx >= (n + 1);
  int v = idx - br * (n + 1);
  const int* batch = br ? bb : ba;
  int off = br ? Npad : 0;
  int* bs = bst + br * (NGR + 1);
  int bv = (v < n) ? batch[v] : NGR;
  int bp = (v == 0) ? -1 : batch[v - 1];
  for (int gg = bp + 1; gg <= bv; gg++) bs[gg] = v + off;
}

// ---- pool: block per (branch,graph), 4 waves stride nodes, 40-lane --------
__global__ __launch_bounds__(256) void pool_kernel(
    const __bf16* __restrict__ xin, const int* __restrict__ bstart,
    float* __restrict__ g)
{
  __shared__ float pmx[4][FDIM];
  __shared__ float psm[4][FDIM];
  const int gid = blockIdx.x;              // 0 .. 2*NGR-1
  const int br = gid >= NGR;
  const int lg = gid - br * NGR;
  const int* bs = bstart + br * (NGR + 1);
  const int lane = threadIdx.x & 63;
  const int wid = threadIdx.x >> 6;
  const bool act = lane < 40;
  const int s = bs[lg], e = bs[lg + 1];
  float mx[8], sm[8];
  #pragma unroll
  for (int j = 0; j < 8; j++) { mx[j] = -__builtin_inff(); sm[j] = 0.f; }
  for (int v = s + wid; v < e; v += 4) {
    if (act) {
      bf16x8 hv = *(const bf16x8*)(xin + (size_t)v * FDIM + 8 * lane);
      #pragma unroll
      for (int j = 0; j < 8; j++) {
        float val = (float)hv[j];
        mx[j] = fmaxf(mx[j], val);
        sm[j] += val;
      }
    }
  }
  if (act) {
    #pragma unroll
    for (int j = 0; j < 8; j++) {
      pmx[wid][8 * lane + j] = mx[j];
      psm[wid][8 * lane + j] = sm[j];
    }
  }
  __syncthreads();
  if (wid == 0 && act) {
    float cntf = (float)(e - s);
    float rcnt = 1.f / fmaxf(cntf, 1.f);
    #pragma unroll
    for (int j = 0; j < 8; j++) {
      int c = 8 * lane + j;
      float m2 = fmaxf(fmaxf(pmx[0][c], pmx[1][c]), fmaxf(pmx[2][c], pmx[3][c]));
      float s2 = psm[0][c] + psm[1][c] + psm[2][c] + psm[3][c];
      g[gid * (2 * FDIM) + c] = m2;
      g[gid * (2 * FDIM) + FDIM + c] = s2 * rcnt;
    }
  }
}

// ---------------- launch ----------------
extern "C" void kernel_launch(void* const* d_in, const int* in_sizes, int n_in,
                              void* d_out, int out_size, void* d_ws, size_t ws_size,
                              hipStream_t stream)
{
  const int N = in_sizes[0] / FDIM;
  const int E = in_sizes[2] / 2;
  const int Npad = (N + 63) & ~63;
  const int n2 = 2 * Npad;
  const int NB2 = (n2 + 255) / 256;

  const float* x_a = (const float*)d_in[0];
  const float* x_b = (const float*)d_in[1];
  const int*   ei_a = (const int*)d_in[2];
  const int*   ei_b = (const int*)d_in[3];
  const int*   bat_a = (const int*)d_in[4];
  const int*   bat_b = (const int*)d_in[5];
  const float* W_gcn   = (const float*)d_in[6];
  const float* b_gcn   = (const float*)d_in[7];
  const float* W_gat   = (const float*)d_in[8];
  const float* att_src = (const float*)d_in[9];
  const float* att_dst = (const float*)d_in[10];
  const float* b_gat   = (const float*)d_in[11];
  const float* W_fc_g1 = (const float*)d_in[12];
  const float* b_fc_g1 = (const float*)d_in[13];
  const float* W_fc_g2 = (const float*)d_in[14];
  const float* b_fc_g2 = (const float*)d_in[15];
  const float* W_fc1   = (const float*)d_in[16];
  const float* b_fc1   = (const float*)d_in[17];
  const float* W_fc2   = (const float*)d_in[18];
  const float* b_fc2   = (const float*)d_in[19];
  const float* W_out   = (const float*)d_in[20];
  const float* b_out   = (const float*)d_in[21];
  float* outp = (float*)d_out;

  char* ws = (char*)d_ws;
  size_t off = 0;
  auto alloc = [&](size_t bytes) -> char* {
    char* p = ws + off;
    off += (bytes + 255) & ~(size_t)255;
    return p;
  };
  int*    cnt    = (int*)alloc((size_t)n2 * 4);
  int*    fil    = (int*)alloc((size_t)n2 * 4);
  size_t  zero_span = (size_t)((char*)fil - (char*)cnt) + (((size_t)n2 * 4 + 255) & ~(size_t)255);
  int*    rp     = (int*)alloc((size_t)(n2 + 1) * 4);
  int*    bsum   = (int*)alloc((size_t)NB2 * 4);
  int*    csr    = (int*)alloc((size_t)2 * E * 4);
  float*  dinv   = (float*)alloc((size_t)n2 * 4);
  int*    bstart = (int*)alloc((size_t)2 * (NGR + 1) * 4);
  __bf16* WgcnT  = (__bf16*)alloc((size_t)FDIM * FDIM * 2);
  __bf16* WgatT  = (__bf16*)alloc((size_t)FDIM * FDIM * 2);
  __bf16* hbuf   = (__bf16*)alloc((size_t)n2 * FDIM * 2);
  __bf16* xbuf   = (__bf16*)alloc((size_t)n2 * FDIM * 2);
  float*  as_    = (float*)alloc((size_t)n2 * NHEADS * 4);
  float*  ad_    = (float*)alloc((size_t)n2 * NHEADS * 4);
  float*  aself  = (float*)alloc((size_t)n2 * NHEADS * 4);
  size_t aint_bytes = (size_t)2 * E * NHEADS * 4;
  size_t part_bytes = (size_t)8 * 512 * 512 * 4;
  float*  aint   = (float*)alloc(aint_bytes > part_bytes ? aint_bytes : part_bytes);
  float*  part   = aint;   // aliased: aint dead after gat_agg, part used after pool
  float*  g      = (float*)alloc((size_t)2 * NGR * 2 * FDIM * 4);
  float*  t1     = (float*)alloc((size_t)2 * NGR * 1500 * 4);
  float*  xc     = (float*)alloc((size_t)NGR * 256 * 4);
  float*  t2     = (float*)alloc((size_t)NGR * 1024 * 4);
  float*  t3     = (float*)alloc((size_t)NGR * 512 * 4);
  if (off > ws_size) return;  // workspace too small: bail (visible as absmax fail)

  wconv2_kernel<<<2 * (FDIM * FDIM) / 256, 256, 0, stream>>>(W_gcn, W_gat, WgcnT, WgatT);

  hipMemsetAsync(cnt, 0, zero_span, stream);
  count_kernel<<<(2 * E + 255) / 256, 256, 0, stream>>>(ei_a + E, ei_b + E, cnt, E, Npad);
  bsum_kernel<<<NB2, 256, 0, stream>>>(cnt, bsum, n2);
  bscan_kernel<<<1, 1024, 0, stream>>>(bsum, NB2);
  rpfill_kernel<<<NB2, 256, 0, stream>>>(cnt, bsum, rp, dinv, n2, 2 * E);
  fill_kernel<<<(2 * E + 255) / 256, 256, 0, stream>>>(ei_a, ei_a + E, ei_b, ei_b + E,
                                                       rp, fil, csr, E, Npad);

  int g320 = n2 / 64;
  gemm320v3_kernel<float, false><<<g320, 256, 0, stream>>>(
      x_a, x_b, Npad, N, WgcnT, hbuf, nullptr, nullptr, nullptr, nullptr);
  gcn_agg_kernel<<<(n2 + 3) / 4, 256, 0, stream>>>(hbuf, rp, csr, dinv, b_gcn, xbuf, n2, Npad, N);
  gemm320v3_kernel<__bf16, true><<<g320, 256, 0, stream>>>(
      xbuf, nullptr, Npad, N, WgatT, hbuf, att_src, att_dst, as_, ad_);

  mdenom4_kernel<<<(n2 * NHEADS + 255) / 256, 256, 0, stream>>>(rp, csr, as_, ad_, aint, aself, n2, Npad, N);
  gat_agg_kernel<<<(n2 + 3) / 4, 256, 0, stream>>>(hbuf, rp, csr, aint, aself, b_gat, xbuf, n2, Npad, N);

  bstart_kernel<<<(2 * (N + 1) + 255) / 256, 256, 0, stream>>>(bat_a, bat_b, bstart, N, Npad);
  pool_kernel<<<2 * NGR, 256, 0, stream>>>(xbuf, bstart, g);

  // ---- batched FC head: M=512 covers both branches ----
  {
    dim3 gfc1((512 + BM - 1) / BM, (1500 + BN - 1) / BN);
    gemm_bf16_kernel<3><<<gfc1, 256, 0, stream>>>(g, W_fc_g1, t1, b_fc_g1, 512, 1500, 2 * FDIM, 1500);
    int S = 8, KS = ((1500 + S * BK - 1) / (S * BK)) * BK;
    dim3 gfc2((512 + BM - 1) / BM, (128 + BN - 1) / BN, S);
    gemm_splitk_kernel<<<gfc2, 256, 0, stream>>>(t1, W_fc_g2, part, 512, 128, 1500, KS);
    reduce_kernel<2, true><<<(512 * 128 + 255) / 256, 256, 0, stream>>>(part, xc, b_fc_g2, 512, 128, S, 256);
  }
  {
    dim3 gx1((NGR + BM - 1) / BM, (1024 + BN - 1) / BN);
    gemm_bf16_kernel<3><<<gx1, 256, 0, stream>>>(xc, W_fc1, t2, b_fc1, NGR, 1024, 256, 1024);
    int S = 4, KS = ((1024 + S * BK - 1) / (S * BK)) * BK;
    dim3 gx2((NGR + BM - 1) / BM, (512 + BN - 1) / BN, S);
    gemm_splitk_kernel<<<gx2, 256, 0, stream>>>(t2, W_fc2, part, NGR, 512, 1024, KS);
    reduce_kernel<3, false><<<(NGR * 512 + 255) / 256, 256, 0, stream>>>(part, t3, b_fc2, NGR, 512, S, 512);
    int S2 = 4, KS2 = ((512 + S2 * BK - 1) / (S2 * BK)) * BK;
    dim3 gx3((NGR + BM - 1) / BM, 1, S2);
    gemm_splitk_kernel<<<gx3, 256, 0, stream>>>(t3, W_out, part, NGR, 2, 512, KS2);
    reduce_kernel<2, false><<<(NGR * 2 + 255) / 256, 256, 0, stream>>>(part, outp, b_out, NGR, 2, S2, 2);
  }
}

// Round 15
// 591.914 us; speedup vs baseline: 1.2665x; 1.0341x over previous
//
#include <hip/hip_runtime.h>
#include <type_traits>

#define FDIM 320
#define NHEADS 10
#define NGR 256

typedef __bf16 bf16x8 __attribute__((ext_vector_type(8)));
typedef float f32x4 __attribute__((ext_vector_type(4)));

// ---- prep: wconv2 (blocks 0..799) | count | bstart  (all input-only) ------
__global__ void prep_kernel(const float* __restrict__ Wg, const float* __restrict__ Wa,
                            __bf16* __restrict__ Tg, __bf16* __restrict__ Ta,
                            const int* __restrict__ dst_a, const int* __restrict__ dst_b,
                            int* __restrict__ cnt, int E,
                            const int* __restrict__ ba, const int* __restrict__ bb,
                            int* __restrict__ bst, int n, int Npad,
                            int nbW, int nbC)
{
  int b = blockIdx.x;
  if (b < nbW) {
    int idx = b * 256 + threadIdx.x;
    bool first = idx < FDIM * FDIM;
    const float* W = first ? Wg : Wa;
    __bf16* T = first ? Tg : Ta;
    int i2 = first ? idx : idx - FDIM * FDIM;
    int k = i2 / FDIM, c = i2 - k * FDIM;
    T[c * FDIM + k] = (__bf16)W[i2];
  } else if (b < nbW + nbC) {
    int e = (b - nbW) * 256 + threadIdx.x;
    if (e < E) atomicAdd(&cnt[dst_a[e]], 1);
    else if (e < 2 * E) atomicAdd(&cnt[dst_b[e - E] + Npad], 1);
  } else {
    int idx = (b - nbW - nbC) * 256 + threadIdx.x;
    if (idx >= 2 * (n + 1)) return;
    int br = idx >= (n + 1);
    int v = idx - br * (n + 1);
    const int* batch = br ? bb : ba;
    int off2 = br ? Npad : 0;
    int* bs = bst + br * (NGR + 1);
    int bv = (v < n) ? batch[v] : NGR;
    int bp = (v == 0) ? -1 : batch[v - 1];
    for (int gg = bp + 1; gg <= bv; gg++) bs[gg] = v + off2;
  }
}

// ---------------- node GEMM v3 (merged branches): full-N, LDS dbuf ---------
#define GLSTR 40

template<typename TA, bool SCORES>
__global__ __launch_bounds__(256, 2) void gemm320v3_kernel(
    const TA* __restrict__ A, const TA* __restrict__ A2, int Npad, int Nreal,
    const __bf16* __restrict__ Wt, __bf16* __restrict__ C,
    const float* __restrict__ att_s, const float* __restrict__ att_d,
    float* __restrict__ as_, float* __restrict__ ad_)
{
  __shared__ __bf16 As[2][64 * GLSTR];
  __shared__ __bf16 Bs[2][320 * GLSTR];

  const int tid = threadIdx.x;
  const int lane = tid & 63;
  const int w = tid >> 6;
  const int wr = w >> 1, wc = w & 1;
  const int r = lane & 15, kg = lane >> 4;
  const int m0 = blockIdx.x * 64;
  const bool brB = m0 >= Npad;
  const int loff = brB ? Npad : 0;

  const int brow = tid >> 2, bq = tid & 3;
  const int grow = m0 + brow;
  const int lrow = grow - loff;
  const bool arow_ok = lrow < Nreal;

  bf16x8 bstg[5];
  bf16x8 astg;
  float4 af32a, af32b;

  auto stage_load = [&](int k0) {
    #pragma unroll
    for (int i = 0; i < 5; i++) {
      int ch = tid + i * 256;
      int col = ch >> 2, kc = ch & 3;
      bstg[i] = *(const bf16x8*)(Wt + (size_t)col * FDIM + k0 + kc * 8);
    }
    if constexpr (std::is_same_v<TA, float>) {
      if (arow_ok) {
        const float* Ab = brB ? A2 : A;
        const float4* ap = (const float4*)(Ab + (size_t)lrow * FDIM + k0 + bq * 8);
        af32a = ap[0]; af32b = ap[1];
      }
    } else {
      if (arow_ok) astg = *(const bf16x8*)(A + (size_t)grow * FDIM + k0 + bq * 8);
    }
  };
  auto stage_write = [&](int b) {
    #pragma unroll
    for (int i = 0; i < 5; i++) {
      int ch = tid + i * 256;
      int col = ch >> 2, kc = ch & 3;
      *(bf16x8*)&Bs[b][col * GLSTR + kc * 8] = bstg[i];
    }
    bf16x8 v = {};
    if constexpr (std::is_same_v<TA, float>) {
      if (arow_ok) {
        v[0]=(__bf16)af32a.x; v[1]=(__bf16)af32a.y; v[2]=(__bf16)af32a.z; v[3]=(__bf16)af32a.w;
        v[4]=(__bf16)af32b.x; v[5]=(__bf16)af32b.y; v[6]=(__bf16)af32b.z; v[7]=(__bf16)af32b.w;
      }
    } else {
      if (arow_ok) v = astg;
    }
    *(bf16x8*)&As[b][brow * GLSTR + bq * 8] = v;
  };

  f32x4 acc0[10], acc1[10];
  #pragma unroll
  for (int i = 0; i < 10; i++) { acc0[i] = (f32x4){0,0,0,0}; acc1[i] = (f32x4){0,0,0,0}; }

  stage_load(0);
  stage_write(0);
  __syncthreads();

  int cur = 0;
  for (int k = 0; k < 10; k++) {
    if (k < 9) stage_load((k + 1) * 32);
    {
      bf16x8 a0 = *(const bf16x8*)&As[cur][(wr*32 + r)      * GLSTR + kg*8];
      bf16x8 a1 = *(const bf16x8*)&As[cur][(wr*32 + 16 + r) * GLSTR + kg*8];
      #pragma unroll
      for (int nf = 0; nf < 10; nf++) {
        bf16x8 b = *(const bf16x8*)&Bs[cur][(wc*160 + nf*16 + r) * GLSTR + kg*8];
        acc0[nf] = __builtin_amdgcn_mfma_f32_16x16x32_bf16(a0, b, acc0[nf], 0, 0, 0);
        acc1[nf] = __builtin_amdgcn_mfma_f32_16x16x32_bf16(a1, b, acc1[nf], 0, 0, 0);
      }
    }
    if (k < 9) {
      stage_write(cur ^ 1);
      __syncthreads();
      cur ^= 1;
    }
  }

  #pragma unroll
  for (int nf = 0; nf < 10; nf++) {
    int gn = wc*160 + nf*16 + r;
    #pragma unroll
    for (int q = 0; q < 4; q++) {
      int gm0 = m0 + wr*32 + kg*4 + q;
      if (gm0 - loff < Nreal) C[(size_t)gm0 * FDIM + gn] = (__bf16)acc0[nf][q];
      int gm1 = gm0 + 16;
      if (gm1 - loff < Nreal) C[(size_t)gm1 * FDIM + gn] = (__bf16)acc1[nf][q];
    }
  }

  if constexpr (SCORES) {
    #pragma unroll
    for (int th = 0; th < 5; th++) {
      int t = wc * 5 + th;
      float s0 = att_s[t*32 + r],      s1 = att_s[t*32 + 16 + r];
      float d0 = att_d[t*32 + r],      d1 = att_d[t*32 + 16 + r];
      #pragma unroll
      for (int q = 0; q < 4; q++) {
        float ps0 = acc0[2*th][q]*s0 + acc0[2*th+1][q]*s1;
        float ps1 = acc1[2*th][q]*s0 + acc1[2*th+1][q]*s1;
        float pd0 = acc0[2*th][q]*d0 + acc0[2*th+1][q]*d1;
        float pd1 = acc1[2*th][q]*d0 + acc1[2*th+1][q]*d1;
        #pragma unroll
        for (int off = 1; off < 16; off <<= 1) {
          ps0 += __shfl_xor(ps0, off, 16);
          ps1 += __shfl_xor(ps1, off, 16);
          pd0 += __shfl_xor(pd0, off, 16);
          pd1 += __shfl_xor(pd1, off, 16);
        }
        if (r == 0) {
          int row0 = m0 + wr*32 + kg*4 + q;
          if (row0 - loff < Nreal) { as_[row0*NHEADS + t] = ps0; ad_[row0*NHEADS + t] = pd0; }
          int row1 = row0 + 16;
          if (row1 - loff < Nreal) { as_[row1*NHEADS + t] = ps1; ad_[row1*NHEADS + t] = pd1; }
        }
      }
    }
  }
}

// ---------------- generic GEMM (FC layers): C = A*B, f32 in/out ------------
#define BM 128
#define BN 64
#define BK 32
#define LSTR 56

template<int FLAGS>  // bit0: relu, bit1: bias
__global__ __launch_bounds__(256) void gemm_bf16_kernel(
    const float* __restrict__ A, const float* __restrict__ B,
    float* __restrict__ C, const float* __restrict__ bias,
    int M, int N, int K, int ldc)
{
  __shared__ __bf16 As[BM * LSTR];
  __shared__ __bf16 Bs[BN * LSTR];

  const int tid = threadIdx.x;
  const int lane = tid & 63;
  const int w = tid >> 6;
  const int wm = w >> 1, wn = w & 1;
  const int r = lane & 15, kg = lane >> 4;
  const int m0 = blockIdx.x * BM, n0 = blockIdx.y * BN;

  f32x4 acc[4][2];
  #pragma unroll
  for (int i = 0; i < 4; i++)
    #pragma unroll
    for (int j = 0; j < 2; j++)
      acc[i][j] = (f32x4){0.f, 0.f, 0.f, 0.f};

  const int arow = tid >> 1, ahalf = tid & 1;
  const int bk = tid >> 3, bn = (tid & 7) * 8;

  for (int k0 = 0; k0 < K; k0 += BK) {
    __syncthreads();
    {
      int gm = m0 + arow;
      int kbase = k0 + ahalf * 16;
      float tmp[16];
      if (gm < M && kbase + 16 <= K) {
        const float4* ap = (const float4*)(A + (size_t)gm * K + kbase);
        #pragma unroll
        for (int q = 0; q < 4; q++) {
          float4 v = ap[q];
          tmp[q*4+0] = v.x; tmp[q*4+1] = v.y; tmp[q*4+2] = v.z; tmp[q*4+3] = v.w;
        }
      } else {
        #pragma unroll
        for (int q = 0; q < 16; q++) {
          int kk = kbase + q;
          tmp[q] = (gm < M && kk < K) ? A[(size_t)gm * K + kk] : 0.f;
        }
      }
      bf16x8 v0, v1;
      #pragma unroll
      for (int q = 0; q < 8; q++) { v0[q] = (__bf16)tmp[q]; v1[q] = (__bf16)tmp[q+8]; }
      bf16x8* dp = (bf16x8*)&As[arow * LSTR + ahalf * 16];
      dp[0] = v0; dp[1] = v1;
    }
    {
      int gk = k0 + bk;
      float tb[8];
      if (gk < K && n0 + bn + 8 <= N) {
        const float4* bp = (const float4*)(B + (size_t)gk * N + n0 + bn);
        float4 u0 = bp[0], u1 = bp[1];
        tb[0]=u0.x; tb[1]=u0.y; tb[2]=u0.z; tb[3]=u0.w;
        tb[4]=u1.x; tb[5]=u1.y; tb[6]=u1.z; tb[7]=u1.w;
      } else {
        #pragma unroll
        for (int q = 0; q < 8; q++) {
          int gn = n0 + bn + q;
          tb[q] = (gk < K && gn < N) ? B[(size_t)gk * N + gn] : 0.f;
        }
      }
      #pragma unroll
      for (int q = 0; q < 8; q++) Bs[(bn + q) * LSTR + bk] = (__bf16)tb[q];
    }
    __syncthreads();
    bf16x8 af[4], bfr[2];
    #pragma unroll
    for (int mf = 0; mf < 4; mf++)
      af[mf] = *(const bf16x8*)&As[(wm*64 + mf*16 + r) * LSTR + kg*8];
    #pragma unroll
    for (int nf = 0; nf < 2; nf++)
      bfr[nf] = *(const bf16x8*)&Bs[(wn*32 + nf*16 + r) * LSTR + kg*8];
    #pragma unroll
    for (int mf = 0; mf < 4; mf++)
      #pragma unroll
      for (int nf = 0; nf < 2; nf++)
        acc[mf][nf] = __builtin_amdgcn_mfma_f32_16x16x32_bf16(af[mf], bfr[nf], acc[mf][nf], 0, 0, 0);
  }

  #pragma unroll
  for (int mf = 0; mf < 4; mf++) {
    #pragma unroll
    for (int nf = 0; nf < 2; nf++) {
      #pragma unroll
      for (int q = 0; q < 4; q++) {
        int gm = m0 + wm*64 + mf*16 + kg*4 + q;
        int gn = n0 + wn*32 + nf*16 + r;
        if (gm < M && gn < N) {
          float v = acc[mf][nf][q];
          if (FLAGS & 2) v += bias[gn];
          if (FLAGS & 1) v = fmaxf(v, 0.f);
          C[(size_t)gm * ldc + gn] = v;
        }
      }
    }
  }
}

// ---------------- split-K GEMM: P[s][M][N] partials ----------------
__global__ __launch_bounds__(256) void gemm_splitk_kernel(
    const float* __restrict__ A, const float* __restrict__ B,
    float* __restrict__ P, int M, int N, int K, int KS)
{
  __shared__ __bf16 As[BM * LSTR];
  __shared__ __bf16 Bs[BN * LSTR];

  const int tid = threadIdx.x;
  const int lane = tid & 63;
  const int w = tid >> 6;
  const int wm = w >> 1, wn = w & 1;
  const int r = lane & 15, kg = lane >> 4;
  const int m0 = blockIdx.x * BM, n0 = blockIdx.y * BN;
  const int kstart = blockIdx.z * KS;
  const int kend = min(K, kstart + KS);

  f32x4 acc[4][2];
  #pragma unroll
  for (int i = 0; i < 4; i++)
    #pragma unroll
    for (int j = 0; j < 2; j++)
      acc[i][j] = (f32x4){0.f, 0.f, 0.f, 0.f};

  const int arow = tid >> 1, ahalf = tid & 1;
  const int bk = tid >> 3, bn = (tid & 7) * 8;

  for (int k0 = kstart; k0 < kend; k0 += BK) {
    __syncthreads();
    {
      int gm = m0 + arow;
      int kbase = k0 + ahalf * 16;
      float tmp[16];
      if (gm < M && kbase + 16 <= kend) {
        const float4* ap = (const float4*)(A + (size_t)gm * K + kbase);
        #pragma unroll
        for (int q = 0; q < 4; q++) {
          float4 v = ap[q];
          tmp[q*4+0] = v.x; tmp[q*4+1] = v.y; tmp[q*4+2] = v.z; tmp[q*4+3] = v.w;
        }
      } else {
        #pragma unroll
        for (int q = 0; q < 16; q++) {
          int kk = kbase + q;
          tmp[q] = (gm < M && kk < kend) ? A[(size_t)gm * K + kk] : 0.f;
        }
      }
      bf16x8 v0, v1;
      #pragma unroll
      for (int q = 0; q < 8; q++) { v0[q] = (__bf16)tmp[q]; v1[q] = (__bf16)tmp[q+8]; }
      bf16x8* dp = (bf16x8*)&As[arow * LSTR + ahalf * 16];
      dp[0] = v0; dp[1] = v1;
    }
    {
      int gk = k0 + bk;
      float tb[8];
      if (gk < kend && n0 + bn + 8 <= N) {
        const float4* bp = (const float4*)(B + (size_t)gk * N + n0 + bn);
        float4 u0 = bp[0], u1 = bp[1];
        tb[0]=u0.x; tb[1]=u0.y; tb[2]=u0.z; tb[3]=u0.w;
        tb[4]=u1.x; tb[5]=u1.y; tb[6]=u1.z; tb[7]=u1.w;
      } else {
        #pragma unroll
        for (int q = 0; q < 8; q++) {
          int gn = n0 + bn + q;
          tb[q] = (gk < kend && gn < N) ? B[(size_t)gk * N + gn] : 0.f;
        }
      }
      #pragma unroll
      for (int q = 0; q < 8; q++) Bs[(bn + q) * LSTR + bk] = (__bf16)tb[q];
    }
    __syncthreads();
    bf16x8 af[4], bfr[2];
    #pragma unroll
    for (int mf = 0; mf < 4; mf++)
      af[mf] = *(const bf16x8*)&As[(wm*64 + mf*16 + r) * LSTR + kg*8];
    #pragma unroll
    for (int nf = 0; nf < 2; nf++)
      bfr[nf] = *(const bf16x8*)&Bs[(wn*32 + nf*16 + r) * LSTR + kg*8];
    #pragma unroll
    for (int mf = 0; mf < 4; mf++)
      #pragma unroll
      for (int nf = 0; nf < 2; nf++)
        acc[mf][nf] = __builtin_amdgcn_mfma_f32_16x16x32_bf16(af[mf], bfr[nf], acc[mf][nf], 0, 0, 0);
  }

  float* Pp = P + (size_t)blockIdx.z * M * N;
  #pragma unroll
  for (int mf = 0; mf < 4; mf++) {
    #pragma unroll
    for (int nf = 0; nf < 2; nf++) {
      #pragma unroll
      for (int q = 0; q < 4; q++) {
        int gm = m0 + wm*64 + mf*16 + kg*4 + q;
        int gn = n0 + wn*32 + nf*16 + r;
        if (gm < M && gn < N)
          Pp[(size_t)gm * N + gn] = acc[mf][nf][q];
      }
    }
  }
}

// reduce partials; STACK: rows M/2.. go to cols N.. (fc_g2 branch packing)
template<int FLAGS, bool STACK>
__global__ void reduce_kernel(const float* __restrict__ P, float* __restrict__ C,
                              const float* __restrict__ bias, int M, int N, int S, int ldc)
{
  int i = blockIdx.x * 256 + threadIdx.x;
  if (i >= M * N) return;
  float v = 0.f;
  for (int s = 0; s < S; s++) v += P[(size_t)s * M * N + i];
  int row = i / N, col = i - row * N;
  if (FLAGS & 2) v += bias[col];
  if (FLAGS & 1) v = fmaxf(v, 0.f);
  if (STACK) { if (row >= (M >> 1)) { row -= (M >> 1); col += N; } }
  C[(size_t)row * ldc + col] = v;
}

// ---------------- CSR build (merged) ----------------
__global__ void bsum_kernel(const int* __restrict__ cnt, int* __restrict__ bsum, int n) {
  __shared__ int wp[4];
  int tid = threadIdx.x, lane = tid & 63, wid = tid >> 6;
  int i = blockIdx.x * 256 + tid;
  int v = (i < n) ? cnt[i] : 0;
  #pragma unroll
  for (int off = 32; off >= 1; off >>= 1) v += __shfl_xor(v, off, 64);
  if (lane == 0) wp[wid] = v;
  __syncthreads();
  if (tid == 0) bsum[blockIdx.x] = wp[0] + wp[1] + wp[2] + wp[3];
}

__global__ __launch_bounds__(1024) void bscan_kernel(int* __restrict__ bsum, int nb) {
  __shared__ int wp[16];
  int tid = threadIdx.x, lane = tid & 63, wid = tid >> 6;
  int v = (tid < nb) ? bsum[tid] : 0;
  int xv = v;
  #pragma unroll
  for (int off = 1; off < 64; off <<= 1) {
    int y = __shfl_up(xv, off, 64);
    if (lane >= off) xv += y;
  }
  if (lane == 63) wp[wid] = xv;
  __syncthreads();
  if (tid == 0) { int s = 0; for (int k = 0; k < 16; k++) { int t = wp[k]; wp[k] = s; s += t; } }
  __syncthreads();
  if (tid < nb) bsum[tid] = wp[wid] + xv - v;   // exclusive
}

__global__ void rpfill_kernel(const int* __restrict__ cnt, const int* __restrict__ bsum,
                              int* __restrict__ rp, float* __restrict__ dinv, int n, int E2) {
  __shared__ int wp[4];
  int tid = threadIdx.x, lane = tid & 63, wid = tid >> 6;
  int i = blockIdx.x * 256 + tid;
  int v = (i < n) ? cnt[i] : 0;
  int xv = v;
  #pragma unroll
  for (int off = 1; off < 64; off <<= 1) {
    int y = __shfl_up(xv, off, 64);
    if (lane >= off) xv += y;
  }
  if (lane == 63) wp[wid] = xv;
  __syncthreads();
  if (tid == 0) { int s = 0; for (int k = 0; k < 4; k++) { int t = wp[k]; wp[k] = s; s += t; } }
  __syncthreads();
  if (i < n) {
    rp[i] = bsum[blockIdx.x] + wp[wid] + xv - v;
    dinv[i] = rsqrtf((float)(v + 1));
  }
  if (blockIdx.x == 0 && tid == 0) rp[n] = E2;
}

__global__ void fill_kernel(const int* __restrict__ sa, const int* __restrict__ da,
                            const int* __restrict__ sb, const int* __restrict__ db,
                            const int* __restrict__ rp, int* __restrict__ fil,
                            int* __restrict__ csr, int E, int Npad) {
  int e = blockIdx.x * 256 + threadIdx.x;
  if (e >= 2 * E) return;
  int s, d;
  if (e < E) { s = sa[e]; d = da[e]; }
  else       { s = sb[e - E] + Npad; d = db[e - E] + Npad; }
  int pos = rp[d] + atomicAdd(&fil[d], 1);
  csr[pos] = s;
}

// -- GCN aggregate: scalar (SGPR) edge walk + 40-lane wide loads, 4-deep ----
__global__ void gcn_agg_kernel(const __bf16* __restrict__ h, const int* __restrict__ rp,
                               const int* __restrict__ csr, const float* __restrict__ dinv,
                               const float* __restrict__ bias, __bf16* __restrict__ out,
                               int n2, int Npad, int Nreal)
{
  const int lane = threadIdx.x & 63;
  int v0 = blockIdx.x * 4 + (threadIdx.x >> 6);
  if (v0 >= n2) return;
  const int v = __builtin_amdgcn_readfirstlane(v0);
  const int lv = (v >= Npad) ? v - Npad : v;
  if (lv >= Nreal) return;
  const bool act = lane < 40;
  const float dv = dinv[v];
  const int e0 = rp[v], e1 = rp[v + 1];
  float acc[8], bia[8];
  if (act) {
    bf16x8 hv = *(const bf16x8*)(h + (size_t)v * FDIM + 8 * lane);
    const float4* bp = (const float4*)(bias + 8 * lane);
    float4 b0 = bp[0], b1 = bp[1];
    bia[0]=b0.x; bia[1]=b0.y; bia[2]=b0.z; bia[3]=b0.w;
    bia[4]=b1.x; bia[5]=b1.y; bia[6]=b1.z; bia[7]=b1.w;
    #pragma unroll
    for (int j = 0; j < 8; j++) acc[j] = dv * (float)hv[j];
  }
  int e = e0;
  for (; e + 4 <= e1; e += 4) {
    int sj0 = csr[e], sj1 = csr[e+1], sj2 = csr[e+2], sj3 = csr[e+3];
    float c0 = dinv[sj0], c1 = dinv[sj1], c2 = dinv[sj2], c3 = dinv[sj3];
    if (act) {
      bf16x8 h0 = *(const bf16x8*)(h + (size_t)sj0 * FDIM + 8 * lane);
      bf16x8 h1 = *(const bf16x8*)(h + (size_t)sj1 * FDIM + 8 * lane);
      bf16x8 h2 = *(const bf16x8*)(h + (size_t)sj2 * FDIM + 8 * lane);
      bf16x8 h3 = *(const bf16x8*)(h + (size_t)sj3 * FDIM + 8 * lane);
      #pragma unroll
      for (int j = 0; j < 8; j++)
        acc[j] += c0 * (float)h0[j] + c1 * (float)h1[j]
                + c2 * (float)h2[j] + c3 * (float)h3[j];
    }
  }
  for (; e < e1; e++) {
    int sj = csr[e];
    float cj = dinv[sj];
    if (act) {
      bf16x8 hv = *(const bf16x8*)(h + (size_t)sj * FDIM + 8 * lane);
      #pragma unroll
      for (int j = 0; j < 8; j++) acc[j] += cj * (float)hv[j];
    }
  }
  if (act) {
    bf16x8 o;
    #pragma unroll
    for (int j = 0; j < 8; j++) o[j] = (__bf16)fmaxf(dv * acc[j] + bia[j], 0.f);
    *(bf16x8*)(out + (size_t)v * FDIM + 8 * lane) = o;
  }
}

__device__ __forceinline__ float lrelu(float x) { return x > 0.f ? x : 0.2f * x; }

// ---- softmax stats, NO max-shift (scores O(1), exp safe): one edge pass ---
// writes unnormalized p to aint, pself to aself, 1/den to invden.
__global__ void mdenom5_kernel(const int* __restrict__ rp, const int* __restrict__ csr,
                               const float* __restrict__ as_, const float* __restrict__ ad_,
                               float* __restrict__ aint, float* __restrict__ aself,
                               float* __restrict__ invden, int n2, int Npad, int Nreal)
{
  int tid = blockIdx.x * 256 + threadIdx.x;
  if (tid >= n2 * NHEADS) return;
  int v = tid / NHEADS, t = tid - v * NHEADS;
  int lv = (v >= Npad) ? v - Npad : v;
  if (lv >= Nreal) return;
  int e0 = rp[v], e1 = rp[v + 1];
  float adv = ad_[tid];
  float pself = __expf(lrelu(as_[tid] + adv));
  float den = pself;
  for (int e = e0; e < e1; e++) {
    int s = csr[e];
    float p = __expf(lrelu(as_[s * NHEADS + t] + adv));
    aint[(size_t)e * NHEADS + t] = p;
    den += p;
  }
  aself[tid] = pself;
  invden[tid] = 1.f / den;
}

// -- GAT aggregate: unnormalized p accumulation, scale by inv at end --------
__global__ void gat_agg_kernel(const __bf16* __restrict__ h, const int* __restrict__ rp,
                               const int* __restrict__ csr, const float* __restrict__ aint,
                               const float* __restrict__ aself, const float* __restrict__ invden,
                               const float* __restrict__ bias, __bf16* __restrict__ out,
                               int n2, int Npad, int Nreal)
{
  const int lane = threadIdx.x & 63;
  int v0 = blockIdx.x * 4 + (threadIdx.x >> 6);
  if (v0 >= n2) return;
  const int v = __builtin_amdgcn_readfirstlane(v0);
  const int lv = (v >= Npad) ? v - Npad : v;
  if (lv >= Nreal) return;
  const bool act = lane < 40;
  const int hl = lane >> 2;
  const int e0 = rp[v], e1 = rp[v + 1];

  float acc[8], bia[8], inv_t = 0.f;
  if (act) {
    float aslf = aself[v * NHEADS + hl];
    inv_t = invden[v * NHEADS + hl];
    bf16x8 hv = *(const bf16x8*)(h + (size_t)v * FDIM + 8 * lane);
    const float4* bp = (const float4*)(bias + 8 * lane);
    float4 b0 = bp[0], b1 = bp[1];
    bia[0]=b0.x; bia[1]=b0.y; bia[2]=b0.z; bia[3]=b0.w;
    bia[4]=b1.x; bia[5]=b1.y; bia[6]=b1.z; bia[7]=b1.w;
    #pragma unroll
    for (int j = 0; j < 8; j++) acc[j] = aslf * (float)hv[j];
  }

  int e = e0;
  for (; e + 4 <= e1; e += 4) {
    int sj0 = csr[e], sj1 = csr[e+1], sj2 = csr[e+2], sj3 = csr[e+3];
    if (act) {
      float a0 = aint[(size_t)(e+0) * NHEADS + hl];
      float a1 = aint[(size_t)(e+1) * NHEADS + hl];
      float a2 = aint[(size_t)(e+2) * NHEADS + hl];
      float a3 = aint[(size_t)(e+3) * NHEADS + hl];
      bf16x8 h0 = *(const bf16x8*)(h + (size_t)sj0 * FDIM + 8 * lane);
      bf16x8 h1 = *(const bf16x8*)(h + (size_t)sj1 * FDIM + 8 * lane);
      bf16x8 h2 = *(const bf16x8*)(h + (size_t)sj2 * FDIM + 8 * lane);
      bf16x8 h3 = *(const bf16x8*)(h + (size_t)sj3 * FDIM + 8 * lane);
      #pragma unroll
      for (int j = 0; j < 8; j++)
        acc[j] += a0 * (float)h0[j] + a1 * (float)h1[j]
                + a2 * (float)h2[j] + a3 * (float)h3[j];
    }
  }
  for (; e < e1; e++) {
    int sj = csr[e];
    if (act) {
      float al = aint[(size_t)e * NHEADS + hl];
      bf16x8 hv = *(const bf16x8*)(h + (size_t)sj * FDIM + 8 * lane);
      #pragma unroll
      for (int j = 0; j < 8; j++) acc[j] += al * (float)hv[j];
    }
  }
  if (act) {
    bf16x8 o;
    #pragma unroll
    for (int j = 0; j < 8; j++) o[j] = (__bf16)fmaxf(acc[j] * inv_t + bia[j], 0.f);
    *(bf16x8*)(out + (size_t)v * FDIM + 8 * lane) = o;
  }
}

// ---- pool: block per (branch,graph), 4 waves stride nodes, 40-lane --------
__global__ __launch_bounds__(256) void pool_kernel(
    const __bf16* __restrict__ xin, const int* __restrict__ bstart,
    float* __restrict__ g)
{
  __shared__ float pmx[4][FDIM];
  __shared__ float psm[4][FDIM];
  const int gid = blockIdx.x;              // 0 .. 2*NGR-1
  const int br = gid >= NGR;
  const int lg = gid - br * NGR;
  const int* bs = bstart + br * (NGR + 1);
  const int lane = threadIdx.x & 63;
  const int wid = threadIdx.x >> 6;
  const bool act = lane < 40;
  const int s = bs[lg], e = bs[lg + 1];
  float mx[8], sm[8];
  #pragma unroll
  for (int j = 0; j < 8; j++) { mx[j] = -__builtin_inff(); sm[j] = 0.f; }
  for (int v = s + wid; v < e; v += 4) {
    if (act) {
      bf16x8 hv = *(const bf16x8*)(xin + (size_t)v * FDIM + 8 * lane);
      #pragma unroll
      for (int j = 0; j < 8; j++) {
        float val = (float)hv[j];
        mx[j] = fmaxf(mx[j], val);
        sm[j] += val;
      }
    }
  }
  if (act) {
    #pragma unroll
    for (int j = 0; j < 8; j++) {
      pmx[wid][8 * lane + j] = mx[j];
      psm[wid][8 * lane + j] = sm[j];
    }
  }
  __syncthreads();
  if (wid == 0 && act) {
    float cntf = (float)(e - s);
    float rcnt = 1.f / fmaxf(cntf, 1.f);
    #pragma unroll
    for (int j = 0; j < 8; j++) {
      int c = 8 * lane + j;
      float m2 = fmaxf(fmaxf(pmx[0][c], pmx[1][c]), fmaxf(pmx[2][c], pmx[3][c]));
      float s2 = psm[0][c] + psm[1][c] + psm[2][c] + psm[3][c];
      g[gid * (2 * FDIM) + c] = m2;
      g[gid * (2 * FDIM) + FDIM + c] = s2 * rcnt;
    }
  }
}

// ---------------- launch ----------------
extern "C" void kernel_launch(void* const* d_in, const int* in_sizes, int n_in,
                              void* d_out, int out_size, void* d_ws, size_t ws_size,
                              hipStream_t stream)
{
  const int N = in_sizes[0] / FDIM;
  const int E = in_sizes[2] / 2;
  const int Npad = (N + 63) & ~63;
  const int n2 = 2 * Npad;
  const int NB2 = (n2 + 255) / 256;

  const float* x_a = (const float*)d_in[0];
  const float* x_b = (const float*)d_in[1];
  const int*   ei_a = (const int*)d_in[2];
  const int*   ei_b = (const int*)d_in[3];
  const int*   bat_a = (const int*)d_in[4];
  const int*   bat_b = (const int*)d_in[5];
  const float* W_gcn   = (const float*)d_in[6];
  const float* b_gcn   = (const float*)d_in[7];
  const float* W_gat   = (const float*)d_in[8];
  const float* att_src = (const float*)d_in[9];
  const float* att_dst = (const float*)d_in[10];
  const float* b_gat   = (const float*)d_in[11];
  const float* W_fc_g1 = (const float*)d_in[12];
  const float* b_fc_g1 = (const float*)d_in[13];
  const float* W_fc_g2 = (const float*)d_in[14];
  const float* b_fc_g2 = (const float*)d_in[15];
  const float* W_fc1   = (const float*)d_in[16];
  const float* b_fc1   = (const float*)d_in[17];
  const float* W_fc2   = (const float*)d_in[18];
  const float* b_fc2   = (const float*)d_in[19];
  const float* W_out   = (const float*)d_in[20];
  const float* b_out   = (const float*)d_in[21];
  float* outp = (float*)d_out;

  char* ws = (char*)d_ws;
  size_t off = 0;
  auto alloc = [&](size_t bytes) -> char* {
    char* p = ws + off;
    off += (bytes + 255) & ~(size_t)255;
    return p;
  };
  int*    cnt    = (int*)alloc((size_t)n2 * 4);
  int*    fil    = (int*)alloc((size_t)n2 * 4);
  size_t  zero_span = (size_t)((char*)fil - (char*)cnt) + (((size_t)n2 * 4 + 255) & ~(size_t)255);
  int*    rp     = (int*)alloc((size_t)(n2 + 1) * 4);
  int*    bsum   = (int*)alloc((size_t)NB2 * 4);
  int*    csr    = (int*)alloc((size_t)2 * E * 4);
  float*  dinv   = (float*)alloc((size_t)n2 * 4);
  int*    bstart = (int*)alloc((size_t)2 * (NGR + 1) * 4);
  __bf16* WgcnT  = (__bf16*)alloc((size_t)FDIM * FDIM * 2);
  __bf16* WgatT  = (__bf16*)alloc((size_t)FDIM * FDIM * 2);
  __bf16* hbuf   = (__bf16*)alloc((size_t)n2 * FDIM * 2);
  __bf16* xbuf   = (__bf16*)alloc((size_t)n2 * FDIM * 2);
  float*  as_    = (float*)alloc((size_t)n2 * NHEADS * 4);
  float*  ad_    = (float*)alloc((size_t)n2 * NHEADS * 4);
  float*  aself  = (float*)alloc((size_t)n2 * NHEADS * 4);
  float*  invden = (float*)alloc((size_t)n2 * NHEADS * 4);
  size_t aint_bytes = (size_t)2 * E * NHEADS * 4;
  size_t part_bytes = (size_t)8 * 512 * 512 * 4;
  float*  aint   = (float*)alloc(aint_bytes > part_bytes ? aint_bytes : part_bytes);
  float*  part   = aint;   // aliased: aint dead after gat_agg
  float*  g      = (float*)alloc((size_t)2 * NGR * 2 * FDIM * 4);
  float*  t1     = (float*)alloc((size_t)2 * NGR * 1500 * 4);
  float*  xc     = (float*)alloc((size_t)NGR * 256 * 4);
  float*  t2     = (float*)alloc((size_t)NGR * 1024 * 4);
  float*  t3     = (float*)alloc((size_t)NGR * 512 * 4);
  if (off > ws_size) return;  // workspace too small: bail (visible as absmax fail)

  hipMemsetAsync(cnt, 0, zero_span, stream);
  {
    int nbW = 2 * (FDIM * FDIM) / 256;
    int nbC = (2 * E + 255) / 256;
    int nbB = (2 * (N + 1) + 255) / 256;
    prep_kernel<<<nbW + nbC + nbB, 256, 0, stream>>>(
        W_gcn, W_gat, WgcnT, WgatT, ei_a + E, ei_b + E, cnt, E,
        bat_a, bat_b, bstart, N, Npad, nbW, nbC);
  }
  bsum_kernel<<<NB2, 256, 0, stream>>>(cnt, bsum, n2);
  bscan_kernel<<<1, 1024, 0, stream>>>(bsum, NB2);
  rpfill_kernel<<<NB2, 256, 0, stream>>>(cnt, bsum, rp, dinv, n2, 2 * E);
  fill_kernel<<<(2 * E + 255) / 256, 256, 0, stream>>>(ei_a, ei_a + E, ei_b, ei_b + E,
                                                       rp, fil, csr, E, Npad);

  int g320 = n2 / 64;
  gemm320v3_kernel<float, false><<<g320, 256, 0, stream>>>(
      x_a, x_b, Npad, N, WgcnT, hbuf, nullptr, nullptr, nullptr, nullptr);
  gcn_agg_kernel<<<(n2 + 3) / 4, 256, 0, stream>>>(hbuf, rp, csr, dinv, b_gcn, xbuf, n2, Npad, N);
  gemm320v3_kernel<__bf16, true><<<g320, 256, 0, stream>>>(
      xbuf, nullptr, Npad, N, WgatT, hbuf, att_src, att_dst, as_, ad_);

  mdenom5_kernel<<<(n2 * NHEADS + 255) / 256, 256, 0, stream>>>(
      rp, csr, as_, ad_, aint, aself, invden, n2, Npad, N);
  gat_agg_kernel<<<(n2 + 3) / 4, 256, 0, stream>>>(
      hbuf, rp, csr, aint, aself, invden, b_gat, xbuf, n2, Npad, N);

  pool_kernel<<<2 * NGR, 256, 0, stream>>>(xbuf, bstart, g);

  // ---- batched FC head: M=512 covers both branches ----
  {
    dim3 gfc1((512 + BM - 1) / BM, (1500 + BN - 1) / BN);
    gemm_bf16_kernel<3><<<gfc1, 256, 0, stream>>>(g, W_fc_g1, t1, b_fc_g1, 512, 1500, 2 * FDIM, 1500);
    int S = 8, KS = ((1500 + S * BK - 1) / (S * BK)) * BK;
    dim3 gfc2((512 + BM - 1) / BM, (128 + BN - 1) / BN, S);
    gemm_splitk_kernel<<<gfc2, 256, 0, stream>>>(t1, W_fc_g2, part, 512, 128, 1500, KS);
    reduce_kernel<2, true><<<(512 * 128 + 255) / 256, 256, 0, stream>>>(part, xc, b_fc_g2, 512, 128, S, 256);
  }
  {
    dim3 gx1((NGR + BM - 1) / BM, (1024 + BN - 1) / BN);
    gemm_bf16_kernel<3><<<gx1, 256, 0, stream>>>(xc, W_fc1, t2, b_fc1, NGR, 1024, 256, 1024);
    int S = 4, KS = ((1024 + S * BK - 1) / (S * BK)) * BK;
    dim3 gx2((NGR + BM - 1) / BM, (512 + BN - 1) / BN, S);
    gemm_splitk_kernel<<<gx2, 256, 0, stream>>>(t2, W_fc2, part, NGR, 512, 1024, KS);
    reduce_kernel<3, false><<<(NGR * 512 + 255) / 256, 256, 0, stream>>>(part, t3, b_fc2, NGR, 512, S, 512);
    int S2 = 4, KS2 = ((512 + S2 * BK - 1) / (S2 * BK)) * BK;
    dim3 gx3((NGR + BM - 1) / BM, 1, S2);
    gemm_splitk_kernel<<<gx3, 256, 0, stream>>>(t3, W_out, part, NGR, 2, 512, KS2);
    reduce_kernel<2, false><<<(NGR * 2 + 255) / 256, 256, 0, stream>>>(part, outp, b_out, NGR, 2, S2, 2);
  }
}

// Round 16
// 572.058 us; speedup vs baseline: 1.3105x; 1.0347x over previous
//
#include <hip/hip_runtime.h>
#include <type_traits>

#define FDIM 320
#define NHEADS 10
#define NGR 256

typedef __bf16 bf16x8 __attribute__((ext_vector_type(8)));
typedef float f32x4 __attribute__((ext_vector_type(4)));

// ---- prep: wconv2 (blocks 0..nbW-1) | count | bstart  (all input-only) ----
__global__ void prep_kernel(const float* __restrict__ Wg, const float* __restrict__ Wa,
                            __bf16* __restrict__ Tg, __bf16* __restrict__ Ta,
                            const int* __restrict__ dst_a, const int* __restrict__ dst_b,
                            int* __restrict__ cnt, int E,
                            const int* __restrict__ ba, const int* __restrict__ bb,
                            int* __restrict__ bst, int n, int Npad,
                            int nbW, int nbC)
{
  int b = blockIdx.x;
  if (b < nbW) {
    int idx = b * 256 + threadIdx.x;
    bool first = idx < FDIM * FDIM;
    const float* W = first ? Wg : Wa;
    __bf16* T = first ? Tg : Ta;
    int i2 = first ? idx : idx - FDIM * FDIM;
    int k = i2 / FDIM, c = i2 - k * FDIM;
    T[c * FDIM + k] = (__bf16)W[i2];
  } else if (b < nbW + nbC) {
    int e = (b - nbW) * 256 + threadIdx.x;
    if (e < E) atomicAdd(&cnt[dst_a[e]], 1);
    else if (e < 2 * E) atomicAdd(&cnt[dst_b[e - E] + Npad], 1);
  } else {
    int idx = (b - nbW - nbC) * 256 + threadIdx.x;
    if (idx >= 2 * (n + 1)) return;
    int br = idx >= (n + 1);
    int v = idx - br * (n + 1);
    const int* batch = br ? bb : ba;
    int off2 = br ? Npad : 0;
    int* bs = bst + br * (NGR + 1);
    int bv = (v < n) ? batch[v] : NGR;
    int bp = (v == 0) ? -1 : batch[v - 1];
    for (int gg = bp + 1; gg <= bv; gg++) bs[gg] = v + off2;
  }
}

// ---------------- node GEMM v3 (merged branches): full-N, LDS dbuf ---------
#define GLSTR 40

template<typename TA, bool SCORES>
__global__ __launch_bounds__(256, 2) void gemm320v3_kernel(
    const TA* __restrict__ A, const TA* __restrict__ A2, int Npad, int Nreal,
    const __bf16* __restrict__ Wt, __bf16* __restrict__ C,
    const float* __restrict__ att_s, const float* __restrict__ att_d,
    float* __restrict__ as_, float* __restrict__ ad_)
{
  __shared__ __bf16 As[2][64 * GLSTR];
  __shared__ __bf16 Bs[2][320 * GLSTR];

  const int tid = threadIdx.x;
  const int lane = tid & 63;
  const int w = tid >> 6;
  const int wr = w >> 1, wc = w & 1;
  const int r = lane & 15, kg = lane >> 4;
  const int m0 = blockIdx.x * 64;
  const bool brB = m0 >= Npad;
  const int loff = brB ? Npad : 0;

  const int brow = tid >> 2, bq = tid & 3;
  const int grow = m0 + brow;
  const int lrow = grow - loff;
  const bool arow_ok = lrow < Nreal;

  bf16x8 bstg[5];
  bf16x8 astg;
  float4 af32a, af32b;

  auto stage_load = [&](int k0) {
    #pragma unroll
    for (int i = 0; i < 5; i++) {
      int ch = tid + i * 256;
      int col = ch >> 2, kc = ch & 3;
      bstg[i] = *(const bf16x8*)(Wt + (size_t)col * FDIM + k0 + kc * 8);
    }
    if constexpr (std::is_same_v<TA, float>) {
      if (arow_ok) {
        const float* Ab = brB ? A2 : A;
        const float4* ap = (const float4*)(Ab + (size_t)lrow * FDIM + k0 + bq * 8);
        af32a = ap[0]; af32b = ap[1];
      }
    } else {
      if (arow_ok) astg = *(const bf16x8*)(A + (size_t)grow * FDIM + k0 + bq * 8);
    }
  };
  auto stage_write = [&](int b) {
    #pragma unroll
    for (int i = 0; i < 5; i++) {
      int ch = tid + i * 256;
      int col = ch >> 2, kc = ch & 3;
      *(bf16x8*)&Bs[b][col * GLSTR + kc * 8] = bstg[i];
    }
    bf16x8 v = {};
    if constexpr (std::is_same_v<TA, float>) {
      if (arow_ok) {
        v[0]=(__bf16)af32a.x; v[1]=(__bf16)af32a.y; v[2]=(__bf16)af32a.z; v[3]=(__bf16)af32a.w;
        v[4]=(__bf16)af32b.x; v[5]=(__bf16)af32b.y; v[6]=(__bf16)af32b.z; v[7]=(__bf16)af32b.w;
      }
    } else {
      if (arow_ok) v = astg;
    }
    *(bf16x8*)&As[b][brow * GLSTR + bq * 8] = v;
  };

  f32x4 acc0[10], acc1[10];
  #pragma unroll
  for (int i = 0; i < 10; i++) { acc0[i] = (f32x4){0,0,0,0}; acc1[i] = (f32x4){0,0,0,0}; }

  stage_load(0);
  stage_write(0);
  __syncthreads();

  int cur = 0;
  for (int k = 0; k < 10; k++) {
    if (k < 9) stage_load((k + 1) * 32);
    {
      bf16x8 a0 = *(const bf16x8*)&As[cur][(wr*32 + r)      * GLSTR + kg*8];
      bf16x8 a1 = *(const bf16x8*)&As[cur][(wr*32 + 16 + r) * GLSTR + kg*8];
      #pragma unroll
      for (int nf = 0; nf < 10; nf++) {
        bf16x8 b = *(const bf16x8*)&Bs[cur][(wc*160 + nf*16 + r) * GLSTR + kg*8];
        acc0[nf] = __builtin_amdgcn_mfma_f32_16x16x32_bf16(a0, b, acc0[nf], 0, 0, 0);
        acc1[nf] = __builtin_amdgcn_mfma_f32_16x16x32_bf16(a1, b, acc1[nf], 0, 0, 0);
      }
    }
    if (k < 9) {
      stage_write(cur ^ 1);
      __syncthreads();
      cur ^= 1;
    }
  }

  #pragma unroll
  for (int nf = 0; nf < 10; nf++) {
    int gn = wc*160 + nf*16 + r;
    #pragma unroll
    for (int q = 0; q < 4; q++) {
      int gm0 = m0 + wr*32 + kg*4 + q;
      if (gm0 - loff < Nreal) C[(size_t)gm0 * FDIM + gn] = (__bf16)acc0[nf][q];
      int gm1 = gm0 + 16;
      if (gm1 - loff < Nreal) C[(size_t)gm1 * FDIM + gn] = (__bf16)acc1[nf][q];
    }
  }

  if constexpr (SCORES) {
    #pragma unroll
    for (int th = 0; th < 5; th++) {
      int t = wc * 5 + th;
      float s0 = att_s[t*32 + r],      s1 = att_s[t*32 + 16 + r];
      float d0 = att_d[t*32 + r],      d1 = att_d[t*32 + 16 + r];
      #pragma unroll
      for (int q = 0; q < 4; q++) {
        float ps0 = acc0[2*th][q]*s0 + acc0[2*th+1][q]*s1;
        float ps1 = acc1[2*th][q]*s0 + acc1[2*th+1][q]*s1;
        float pd0 = acc0[2*th][q]*d0 + acc0[2*th+1][q]*d1;
        float pd1 = acc1[2*th][q]*d0 + acc1[2*th+1][q]*d1;
        #pragma unroll
        for (int off = 1; off < 16; off <<= 1) {
          ps0 += __shfl_xor(ps0, off, 16);
          ps1 += __shfl_xor(ps1, off, 16);
          pd0 += __shfl_xor(pd0, off, 16);
          pd1 += __shfl_xor(pd1, off, 16);
        }
        if (r == 0) {
          int row0 = m0 + wr*32 + kg*4 + q;
          if (row0 - loff < Nreal) { as_[row0*NHEADS + t] = ps0; ad_[row0*NHEADS + t] = pd0; }
          int row1 = row0 + 16;
          if (row1 - loff < Nreal) { as_[row1*NHEADS + t] = ps1; ad_[row1*NHEADS + t] = pd1; }
        }
      }
    }
  }
}

// ---------------- generic GEMM (FC layers): C = A*B, f32 in/out ------------
#define BM 128
#define BN 64
#define BK 32
#define LSTR 56

template<int FLAGS>  // bit0: relu, bit1: bias
__global__ __launch_bounds__(256) void gemm_bf16_kernel(
    const float* __restrict__ A, const float* __restrict__ B,
    float* __restrict__ C, const float* __restrict__ bias,
    int M, int N, int K, int ldc)
{
  __shared__ __bf16 As[BM * LSTR];
  __shared__ __bf16 Bs[BN * LSTR];

  const int tid = threadIdx.x;
  const int lane = tid & 63;
  const int w = tid >> 6;
  const int wm = w >> 1, wn = w & 1;
  const int r = lane & 15, kg = lane >> 4;
  const int m0 = blockIdx.x * BM, n0 = blockIdx.y * BN;

  f32x4 acc[4][2];
  #pragma unroll
  for (int i = 0; i < 4; i++)
    #pragma unroll
    for (int j = 0; j < 2; j++)
      acc[i][j] = (f32x4){0.f, 0.f, 0.f, 0.f};

  const int arow = tid >> 1, ahalf = tid & 1;
  const int bk = tid >> 3, bn = (tid & 7) * 8;

  for (int k0 = 0; k0 < K; k0 += BK) {
    __syncthreads();
    {
      int gm = m0 + arow;
      int kbase = k0 + ahalf * 16;
      float tmp[16];
      if (gm < M && kbase + 16 <= K) {
        const float4* ap = (const float4*)(A + (size_t)gm * K + kbase);
        #pragma unroll
        for (int q = 0; q < 4; q++) {
          float4 v = ap[q];
          tmp[q*4+0] = v.x; tmp[q*4+1] = v.y; tmp[q*4+2] = v.z; tmp[q*4+3] = v.w;
        }
      } else {
        #pragma unroll
        for (int q = 0; q < 16; q++) {
          int kk = kbase + q;
          tmp[q] = (gm < M && kk < K) ? A[(size_t)gm * K + kk] : 0.f;
        }
      }
      bf16x8 v0, v1;
      #pragma unroll
      for (int q = 0; q < 8; q++) { v0[q] = (__bf16)tmp[q]; v1[q] = (__bf16)tmp[q+8]; }
      bf16x8* dp = (bf16x8*)&As[arow * LSTR + ahalf * 16];
      dp[0] = v0; dp[1] = v1;
    }
    {
      int gk = k0 + bk;
      float tb[8];
      if (gk < K && n0 + bn + 8 <= N) {
        const float4* bp = (const float4*)(B + (size_t)gk * N + n0 + bn);
        float4 u0 = bp[0], u1 = bp[1];
        tb[0]=u0.x; tb[1]=u0.y; tb[2]=u0.z; tb[3]=u0.w;
        tb[4]=u1.x; tb[5]=u1.y; tb[6]=u1.z; tb[7]=u1.w;
      } else {
        #pragma unroll
        for (int q = 0; q < 8; q++) {
          int gn = n0 + bn + q;
          tb[q] = (gk < K && gn < N) ? B[(size_t)gk * N + gn] : 0.f;
        }
      }
      #pragma unroll
      for (int q = 0; q < 8; q++) Bs[(bn + q) * LSTR + bk] = (__bf16)tb[q];
    }
    __syncthreads();
    bf16x8 af[4], bfr[2];
    #pragma unroll
    for (int mf = 0; mf < 4; mf++)
      af[mf] = *(const bf16x8*)&As[(wm*64 + mf*16 + r) * LSTR + kg*8];
    #pragma unroll
    for (int nf = 0; nf < 2; nf++)
      bfr[nf] = *(const bf16x8*)&Bs[(wn*32 + nf*16 + r) * LSTR + kg*8];
    #pragma unroll
    for (int mf = 0; mf < 4; mf++)
      #pragma unroll
      for (int nf = 0; nf < 2; nf++)
        acc[mf][nf] = __builtin_amdgcn_mfma_f32_16x16x32_bf16(af[mf], bfr[nf], acc[mf][nf], 0, 0, 0);
  }

  #pragma unroll
  for (int mf = 0; mf < 4; mf++) {
    #pragma unroll
    for (int nf = 0; nf < 2; nf++) {
      #pragma unroll
      for (int q = 0; q < 4; q++) {
        int gm = m0 + wm*64 + mf*16 + kg*4 + q;
        int gn = n0 + wn*32 + nf*16 + r;
        if (gm < M && gn < N) {
          float v = acc[mf][nf][q];
          if (FLAGS & 2) v += bias[gn];
          if (FLAGS & 1) v = fmaxf(v, 0.f);
          C[(size_t)gm * ldc + gn] = v;
        }
      }
    }
  }
}

// ---------------- split-K GEMM: P[s][M][N] partials ----------------
__global__ __launch_bounds__(256) void gemm_splitk_kernel(
    const float* __restrict__ A, const float* __restrict__ B,
    float* __restrict__ P, int M, int N, int K, int KS)
{
  __shared__ __bf16 As[BM * LSTR];
  __shared__ __bf16 Bs[BN * LSTR];

  const int tid = threadIdx.x;
  const int lane = tid & 63;
  const int w = tid >> 6;
  const int wm = w >> 1, wn = w & 1;
  const int r = lane & 15, kg = lane >> 4;
  const int m0 = blockIdx.x * BM, n0 = blockIdx.y * BN;
  const int kstart = blockIdx.z * KS;
  const int kend = min(K, kstart + KS);

  f32x4 acc[4][2];
  #pragma unroll
  for (int i = 0; i < 4; i++)
    #pragma unroll
    for (int j = 0; j < 2; j++)
      acc[i][j] = (f32x4){0.f, 0.f, 0.f, 0.f};

  const int arow = tid >> 1, ahalf = tid & 1;
  const int bk = tid >> 3, bn = (tid & 7) * 8;

  for (int k0 = kstart; k0 < kend; k0 += BK) {
    __syncthreads();
    {
      int gm = m0 + arow;
      int kbase = k0 + ahalf * 16;
      float tmp[16];
      if (gm < M && kbase + 16 <= kend) {
        const float4* ap = (const float4*)(A + (size_t)gm * K + kbase);
        #pragma unroll
        for (int q = 0; q < 4; q++) {
          float4 v = ap[q];
          tmp[q*4+0] = v.x; tmp[q*4+1] = v.y; tmp[q*4+2] = v.z; tmp[q*4+3] = v.w;
        }
      } else {
        #pragma unroll
        for (int q = 0; q < 16; q++) {
          int kk = kbase + q;
          tmp[q] = (gm < M && kk < kend) ? A[(size_t)gm * K + kk] : 0.f;
        }
      }
      bf16x8 v0, v1;
      #pragma unroll
      for (int q = 0; q < 8; q++) { v0[q] = (__bf16)tmp[q]; v1[q] = (__bf16)tmp[q+8]; }
      bf16x8* dp = (bf16x8*)&As[arow * LSTR + ahalf * 16];
      dp[0] = v0; dp[1] = v1;
    }
    {
      int gk = k0 + bk;
      float tb[8];
      if (gk < kend && n0 + bn + 8 <= N) {
        const float4* bp = (const float4*)(B + (size_t)gk * N + n0 + bn);
        float4 u0 = bp[0], u1 = bp[1];
        tb[0]=u0.x; tb[1]=u0.y; tb[2]=u0.z; tb[3]=u0.w;
        tb[4]=u1.x; tb[5]=u1.y; tb[6]=u1.z; tb[7]=u1.w;
      } else {
        #pragma unroll
        for (int q = 0; q < 8; q++) {
          int gn = n0 + bn + q;
          tb[q] = (gk < kend && gn < N) ? B[(size_t)gk * N + gn] : 0.f;
        }
      }
      #pragma unroll
      for (int q = 0; q < 8; q++) Bs[(bn + q) * LSTR + bk] = (__bf16)tb[q];
    }
    __syncthreads();
    bf16x8 af[4], bfr[2];
    #pragma unroll
    for (int mf = 0; mf < 4; mf++)
      af[mf] = *(const bf16x8*)&As[(wm*64 + mf*16 + r) * LSTR + kg*8];
    #pragma unroll
    for (int nf = 0; nf < 2; nf++)
      bfr[nf] = *(const bf16x8*)&Bs[(wn*32 + nf*16 + r) * LSTR + kg*8];
    #pragma unroll
    for (int mf = 0; mf < 4; mf++)
      #pragma unroll
      for (int nf = 0; nf < 2; nf++)
        acc[mf][nf] = __builtin_amdgcn_mfma_f32_16x16x32_bf16(af[mf], bfr[nf], acc[mf][nf], 0, 0, 0);
  }

  float* Pp = P + (size_t)blockIdx.z * M * N;
  #pragma unroll
  for (int mf = 0; mf < 4; mf++) {
    #pragma unroll
    for (int nf = 0; nf < 2; nf++) {
      #pragma unroll
      for (int q = 0; q < 4; q++) {
        int gm = m0 + wm*64 + mf*16 + kg*4 + q;
        int gn = n0 + wn*32 + nf*16 + r;
        if (gm < M && gn < N)
          Pp[(size_t)gm * N + gn] = acc[mf][nf][q];
      }
    }
  }
}

// reduce partials; STACK: rows M/2.. go to cols N.. (fc_g2 branch packing)
template<int FLAGS, bool STACK>
__global__ void reduce_kernel(const float* __restrict__ P, float* __restrict__ C,
                              const float* __restrict__ bias, int M, int N, int S, int ldc)
{
  int i = blockIdx.x * 256 + threadIdx.x;
  if (i >= M * N) return;
  float v = 0.f;
  for (int s = 0; s < S; s++) v += P[(size_t)s * M * N + i];
  int row = i / N, col = i - row * N;
  if (FLAGS & 2) v += bias[col];
  if (FLAGS & 1) v = fmaxf(v, 0.f);
  if (STACK) { if (row >= (M >> 1)) { row -= (M >> 1); col += N; } }
  C[(size_t)row * ldc + col] = v;
}

// ---------------- CSR build (merged) ----------------
__global__ void bsum_kernel(const int* __restrict__ cnt, int* __restrict__ bsum, int n) {
  __shared__ int wp[4];
  int tid = threadIdx.x, lane = tid & 63, wid = tid >> 6;
  int i = blockIdx.x * 256 + tid;
  int v = (i < n) ? cnt[i] : 0;
  #pragma unroll
  for (int off = 32; off >= 1; off >>= 1) v += __shfl_xor(v, off, 64);
  if (lane == 0) wp[wid] = v;
  __syncthreads();
  if (tid == 0) bsum[blockIdx.x] = wp[0] + wp[1] + wp[2] + wp[3];
}

__global__ __launch_bounds__(1024) void bscan_kernel(int* __restrict__ bsum, int nb) {
  __shared__ int wp[16];
  int tid = threadIdx.x, lane = tid & 63, wid = tid >> 6;
  int v = (tid < nb) ? bsum[tid] : 0;
  int xv = v;
  #pragma unroll
  for (int off = 1; off < 64; off <<= 1) {
    int y = __shfl_up(xv, off, 64);
    if (lane >= off) xv += y;
  }
  if (lane == 63) wp[wid] = xv;
  __syncthreads();
  if (tid == 0) { int s = 0; for (int k = 0; k < 16; k++) { int t = wp[k]; wp[k] = s; s += t; } }
  __syncthreads();
  if (tid < nb) bsum[tid] = wp[wid] + xv - v;   // exclusive
}

__global__ void rpfill_kernel(const int* __restrict__ cnt, const int* __restrict__ bsum,
                              int* __restrict__ rp, float* __restrict__ dinv, int n, int E2) {
  __shared__ int wp[4];
  int tid = threadIdx.x, lane = tid & 63, wid = tid >> 6;
  int i = blockIdx.x * 256 + tid;
  int v = (i < n) ? cnt[i] : 0;
  int xv = v;
  #pragma unroll
  for (int off = 1; off < 64; off <<= 1) {
    int y = __shfl_up(xv, off, 64);
    if (lane >= off) xv += y;
  }
  if (lane == 63) wp[wid] = xv;
  __syncthreads();
  if (tid == 0) { int s = 0; for (int k = 0; k < 4; k++) { int t = wp[k]; wp[k] = s; s += t; } }
  __syncthreads();
  if (i < n) {
    rp[i] = bsum[blockIdx.x] + wp[wid] + xv - v;
    dinv[i] = rsqrtf((float)(v + 1));
  }
  if (blockIdx.x == 0 && tid == 0) rp[n] = E2;
}

__global__ void fill_kernel(const int* __restrict__ sa, const int* __restrict__ da,
                            const int* __restrict__ sb, const int* __restrict__ db,
                            const int* __restrict__ rp, int* __restrict__ fil,
                            int* __restrict__ csr, int E, int Npad) {
  int e = blockIdx.x * 256 + threadIdx.x;
  if (e >= 2 * E) return;
  int s, d;
  if (e < E) { s = sa[e]; d = da[e]; }
  else       { s = sb[e - E] + Npad; d = db[e - E] + Npad; }
  int pos = rp[d] + atomicAdd(&fil[d], 1);
  csr[pos] = s;
}

// -- GCN aggregate: scalar (SGPR) edge walk + 40-lane wide loads, 4-deep ----
__global__ void gcn_agg_kernel(const __bf16* __restrict__ h, const int* __restrict__ rp,
                               const int* __restrict__ csr, const float* __restrict__ dinv,
                               const float* __restrict__ bias, __bf16* __restrict__ out,
                               int n2, int Npad, int Nreal)
{
  const int lane = threadIdx.x & 63;
  int v0 = blockIdx.x * 4 + (threadIdx.x >> 6);
  if (v0 >= n2) return;
  const int v = __builtin_amdgcn_readfirstlane(v0);
  const int lv = (v >= Npad) ? v - Npad : v;
  if (lv >= Nreal) return;
  const bool act = lane < 40;
  const float dv = dinv[v];
  const int e0 = rp[v], e1 = rp[v + 1];
  float acc[8], bia[8];
  if (act) {
    bf16x8 hv = *(const bf16x8*)(h + (size_t)v * FDIM + 8 * lane);
    const float4* bp = (const float4*)(bias + 8 * lane);
    float4 b0 = bp[0], b1 = bp[1];
    bia[0]=b0.x; bia[1]=b0.y; bia[2]=b0.z; bia[3]=b0.w;
    bia[4]=b1.x; bia[5]=b1.y; bia[6]=b1.z; bia[7]=b1.w;
    #pragma unroll
    for (int j = 0; j < 8; j++) acc[j] = dv * (float)hv[j];
  }
  int e = e0;
  for (; e + 4 <= e1; e += 4) {
    int sj0 = csr[e], sj1 = csr[e+1], sj2 = csr[e+2], sj3 = csr[e+3];
    float c0 = dinv[sj0], c1 = dinv[sj1], c2 = dinv[sj2], c3 = dinv[sj3];
    if (act) {
      bf16x8 h0 = *(const bf16x8*)(h + (size_t)sj0 * FDIM + 8 * lane);
      bf16x8 h1 = *(const bf16x8*)(h + (size_t)sj1 * FDIM + 8 * lane);
      bf16x8 h2 = *(const bf16x8*)(h + (size_t)sj2 * FDIM + 8 * lane);
      bf16x8 h3 = *(const bf16x8*)(h + (size_t)sj3 * FDIM + 8 * lane);
      #pragma unroll
      for (int j = 0; j < 8; j++)
        acc[j] += c0 * (float)h0[j] + c1 * (float)h1[j]
                + c2 * (float)h2[j] + c3 * (float)h3[j];
    }
  }
  for (; e < e1; e++) {
    int sj = csr[e];
    float cj = dinv[sj];
    if (act) {
      bf16x8 hv = *(const bf16x8*)(h + (size_t)sj * FDIM + 8 * lane);
      #pragma unroll
      for (int j = 0; j < 8; j++) acc[j] += cj * (float)hv[j];
    }
  }
  if (act) {
    bf16x8 o;
    #pragma unroll
    for (int j = 0; j < 8; j++) o[j] = (__bf16)fmaxf(dv * acc[j] + bia[j], 0.f);
    *(bf16x8*)(out + (size_t)v * FDIM + 8 * lane) = o;
  }
}

__device__ __forceinline__ float lrelu(float x) { return x > 0.f ? x : 0.2f * x; }

// ---- softmax stats, NO max-shift: one edge pass, bf16 alpha ---------------
__global__ void mdenom5_kernel(const int* __restrict__ rp, const int* __restrict__ csr,
                               const float* __restrict__ as_, const float* __restrict__ ad_,
                               __bf16* __restrict__ aint, float* __restrict__ aself,
                               float* __restrict__ invden, int n2, int Npad, int Nreal)
{
  int tid = blockIdx.x * 256 + threadIdx.x;
  if (tid >= n2 * NHEADS) return;
  int v = tid / NHEADS, t = tid - v * NHEADS;
  int lv = (v >= Npad) ? v - Npad : v;
  if (lv >= Nreal) return;
  int e0 = rp[v], e1 = rp[v + 1];
  float adv = ad_[tid];
  float pself = __expf(lrelu(as_[tid] + adv));
  float den = pself;
  for (int e = e0; e < e1; e++) {
    int s = csr[e];
    float p = __expf(lrelu(as_[s * NHEADS + t] + adv));
    __bf16 pb = (__bf16)p;
    aint[(size_t)e * NHEADS + t] = pb;
    den += (float)pb;        // den matches stored precision (exact normalization)
  }
  aself[tid] = pself;
  invden[tid] = 1.f / den;
}

// -- GAT aggregate: unnormalized bf16 p, scale by inv at end ----------------
__global__ void gat_agg_kernel(const __bf16* __restrict__ h, const int* __restrict__ rp,
                               const int* __restrict__ csr, const __bf16* __restrict__ aint,
                               const float* __restrict__ aself, const float* __restrict__ invden,
                               const float* __restrict__ bias, __bf16* __restrict__ out,
                               int n2, int Npad, int Nreal)
{
  const int lane = threadIdx.x & 63;
  int v0 = blockIdx.x * 4 + (threadIdx.x >> 6);
  if (v0 >= n2) return;
  const int v = __builtin_amdgcn_readfirstlane(v0);
  const int lv = (v >= Npad) ? v - Npad : v;
  if (lv >= Nreal) return;
  const bool act = lane < 40;
  const int hl = lane >> 2;
  const int e0 = rp[v], e1 = rp[v + 1];

  float acc[8], bia[8], inv_t = 0.f;
  if (act) {
    float aslf = aself[v * NHEADS + hl];
    inv_t = invden[v * NHEADS + hl];
    bf16x8 hv = *(const bf16x8*)(h + (size_t)v * FDIM + 8 * lane);
    const float4* bp = (const float4*)(bias + 8 * lane);
    float4 b0 = bp[0], b1 = bp[1];
    bia[0]=b0.x; bia[1]=b0.y; bia[2]=b0.z; bia[3]=b0.w;
    bia[4]=b1.x; bia[5]=b1.y; bia[6]=b1.z; bia[7]=b1.w;
    #pragma unroll
    for (int j = 0; j < 8; j++) acc[j] = aslf * (float)hv[j];
  }

  int e = e0;
  for (; e + 4 <= e1; e += 4) {
    int sj0 = csr[e], sj1 = csr[e+1], sj2 = csr[e+2], sj3 = csr[e+3];
    if (act) {
      float a0 = (float)aint[(size_t)(e+0) * NHEADS + hl];
      float a1 = (float)aint[(size_t)(e+1) * NHEADS + hl];
      float a2 = (float)aint[(size_t)(e+2) * NHEADS + hl];
      float a3 = (float)aint[(size_t)(e+3) * NHEADS + hl];
      bf16x8 h0 = *(const bf16x8*)(h + (size_t)sj0 * FDIM + 8 * lane);
      bf16x8 h1 = *(const bf16x8*)(h + (size_t)sj1 * FDIM + 8 * lane);
      bf16x8 h2 = *(const bf16x8*)(h + (size_t)sj2 * FDIM + 8 * lane);
      bf16x8 h3 = *(const bf16x8*)(h + (size_t)sj3 * FDIM + 8 * lane);
      #pragma unroll
      for (int j = 0; j < 8; j++)
        acc[j] += a0 * (float)h0[j] + a1 * (float)h1[j]
                + a2 * (float)h2[j] + a3 * (float)h3[j];
    }
  }
  for (; e < e1; e++) {
    int sj = csr[e];
    if (act) {
      float al = (float)aint[(size_t)e * NHEADS + hl];
      bf16x8 hv = *(const bf16x8*)(h + (size_t)sj * FDIM + 8 * lane);
      #pragma unroll
      for (int j = 0; j < 8; j++) acc[j] += al * (float)hv[j];
    }
  }
  if (act) {
    bf16x8 o;
    #pragma unroll
    for (int j = 0; j < 8; j++) o[j] = (__bf16)fmaxf(acc[j] * inv_t + bia[j], 0.f);
    *(bf16x8*)(out + (size_t)v * FDIM + 8 * lane) = o;
  }
}

// ---- pool: block per (branch,graph), 4 waves stride nodes, 40-lane --------
__global__ __launch_bounds__(256) void pool_kernel(
    const __bf16* __restrict__ xin, const int* __restrict__ bstart,
    float* __restrict__ g)
{
  __shared__ float pmx[4][FDIM];
  __shared__ float psm[4][FDIM];
  const int gid = blockIdx.x;              // 0 .. 2*NGR-1
  const int br = gid >= NGR;
  const int lg = gid - br * NGR;
  const int* bs = bstart + br * (NGR + 1);
  const int lane = threadIdx.x & 63;
  const int wid = threadIdx.x >> 6;
  const bool act = lane < 40;
  const int s = bs[lg], e = bs[lg + 1];
  float mx[8], sm[8];
  #pragma unroll
  for (int j = 0; j < 8; j++) { mx[j] = -__builtin_inff(); sm[j] = 0.f; }
  for (int v = s + wid; v < e; v += 4) {
    if (act) {
      bf16x8 hv = *(const bf16x8*)(xin + (size_t)v * FDIM + 8 * lane);
      #pragma unroll
      for (int j = 0; j < 8; j++) {
        float val = (float)hv[j];
        mx[j] = fmaxf(mx[j], val);
        sm[j] += val;
      }
    }
  }
  if (act) {
    #pragma unroll
    for (int j = 0; j < 8; j++) {
      pmx[wid][8 * lane + j] = mx[j];
      psm[wid][8 * lane + j] = sm[j];
    }
  }
  __syncthreads();
  if (wid == 0 && act) {
    float cntf = (float)(e - s);
    float rcnt = 1.f / fmaxf(cntf, 1.f);
    #pragma unroll
    for (int j = 0; j < 8; j++) {
      int c = 8 * lane + j;
      float m2 = fmaxf(fmaxf(pmx[0][c], pmx[1][c]), fmaxf(pmx[2][c], pmx[3][c]));
      float s2 = psm[0][c] + psm[1][c] + psm[2][c] + psm[3][c];
      g[gid * (2 * FDIM) + c] = m2;
      g[gid * (2 * FDIM) + FDIM + c] = s2 * rcnt;
    }
  }
}

// ---------------- launch ----------------
extern "C" void kernel_launch(void* const* d_in, const int* in_sizes, int n_in,
                              void* d_out, int out_size, void* d_ws, size_t ws_size,
                              hipStream_t stream)
{
  const int N = in_sizes[0] / FDIM;
  const int E = in_sizes[2] / 2;
  const int Npad = (N + 63) & ~63;
  const int n2 = 2 * Npad;
  const int NB2 = (n2 + 255) / 256;

  const float* x_a = (const float*)d_in[0];
  const float* x_b = (const float*)d_in[1];
  const int*   ei_a = (const int*)d_in[2];
  const int*   ei_b = (const int*)d_in[3];
  const int*   bat_a = (const int*)d_in[4];
  const int*   bat_b = (const int*)d_in[5];
  const float* W_gcn   = (const float*)d_in[6];
  const float* b_gcn   = (const float*)d_in[7];
  const float* W_gat   = (const float*)d_in[8];
  const float* att_src = (const float*)d_in[9];
  const float* att_dst = (const float*)d_in[10];
  const float* b_gat   = (const float*)d_in[11];
  const float* W_fc_g1 = (const float*)d_in[12];
  const float* b_fc_g1 = (const float*)d_in[13];
  const float* W_fc_g2 = (const float*)d_in[14];
  const float* b_fc_g2 = (const float*)d_in[15];
  const float* W_fc1   = (const float*)d_in[16];
  const float* b_fc1   = (const float*)d_in[17];
  const float* W_fc2   = (const float*)d_in[18];
  const float* b_fc2   = (const float*)d_in[19];
  const float* W_out   = (const float*)d_in[20];
  const float* b_out   = (const float*)d_in[21];
  float* outp = (float*)d_out;

  char* ws = (char*)d_ws;
  size_t off = 0;
  auto alloc = [&](size_t bytes) -> char* {
    char* p = ws + off;
    off += (bytes + 255) & ~(size_t)255;
    return p;
  };
  int*    cnt    = (int*)alloc((size_t)n2 * 4);
  int*    fil    = (int*)alloc((size_t)n2 * 4);
  size_t  zero_span = (size_t)((char*)fil - (char*)cnt) + (((size_t)n2 * 4 + 255) & ~(size_t)255);
  int*    rp     = (int*)alloc((size_t)(n2 + 1) * 4);
  int*    bsum   = (int*)alloc((size_t)NB2 * 4);
  int*    csr    = (int*)alloc((size_t)2 * E * 4);
  float*  dinv   = (float*)alloc((size_t)n2 * 4);
  int*    bstart = (int*)alloc((size_t)2 * (NGR + 1) * 4);
  __bf16* WgcnT  = (__bf16*)alloc((size_t)FDIM * FDIM * 2);
  __bf16* WgatT  = (__bf16*)alloc((size_t)FDIM * FDIM * 2);
  __bf16* hbuf   = (__bf16*)alloc((size_t)n2 * FDIM * 2);
  __bf16* xbuf   = (__bf16*)alloc((size_t)n2 * FDIM * 2);
  float*  as_    = (float*)alloc((size_t)n2 * NHEADS * 4);
  float*  ad_    = (float*)alloc((size_t)n2 * NHEADS * 4);
  float*  aself  = (float*)alloc((size_t)n2 * NHEADS * 4);
  float*  invden = (float*)alloc((size_t)n2 * NHEADS * 4);
  __bf16* aint   = (__bf16*)alloc((size_t)2 * E * NHEADS * 2);   // bf16 alpha (40 MB)
  float*  part   = (float*)alloc((size_t)4 * 512 * 1500 * 4);    // split-K partials (12.3 MB)
  float*  g      = (float*)alloc((size_t)2 * NGR * 2 * FDIM * 4);
  float*  t1     = (float*)alloc((size_t)2 * NGR * 1500 * 4);
  float*  xc     = (float*)alloc((size_t)NGR * 256 * 4);
  float*  t2     = (float*)alloc((size_t)NGR * 1024 * 4);
  float*  t3     = (float*)alloc((size_t)NGR * 512 * 4);
  if (off > ws_size) return;  // workspace too small: bail (visible as absmax fail)

  hipMemsetAsync(cnt, 0, zero_span, stream);
  {
    int nbW = 2 * (FDIM * FDIM) / 256;
    int nbC = (2 * E + 255) / 256;
    int nbB = (2 * (N + 1) + 255) / 256;
    prep_kernel<<<nbW + nbC + nbB, 256, 0, stream>>>(
        W_gcn, W_gat, WgcnT, WgatT, ei_a + E, ei_b + E, cnt, E,
        bat_a, bat_b, bstart, N, Npad, nbW, nbC);
  }
  bsum_kernel<<<NB2, 256, 0, stream>>>(cnt, bsum, n2);
  bscan_kernel<<<1, 1024, 0, stream>>>(bsum, NB2);
  rpfill_kernel<<<NB2, 256, 0, stream>>>(cnt, bsum, rp, dinv, n2, 2 * E);
  fill_kernel<<<(2 * E + 255) / 256, 256, 0, stream>>>(ei_a, ei_a + E, ei_b, ei_b + E,
                                                       rp, fil, csr, E, Npad);

  int g320 = n2 / 64;
  gemm320v3_kernel<float, false><<<g320, 256, 0, stream>>>(
      x_a, x_b, Npad, N, WgcnT, hbuf, nullptr, nullptr, nullptr, nullptr);
  gcn_agg_kernel<<<(n2 + 3) / 4, 256, 0, stream>>>(hbuf, rp, csr, dinv, b_gcn, xbuf, n2, Npad, N);
  gemm320v3_kernel<__bf16, true><<<g320, 256, 0, stream>>>(
      xbuf, nullptr, Npad, N, WgatT, hbuf, att_src, att_dst, as_, ad_);

  mdenom5_kernel<<<(n2 * NHEADS + 255) / 256, 256, 0, stream>>>(
      rp, csr, as_, ad_, aint, aself, invden, n2, Npad, N);
  gat_agg_kernel<<<(n2 + 3) / 4, 256, 0, stream>>>(
      hbuf, rp, csr, aint, aself, invden, b_gat, xbuf, n2, Npad, N);

  pool_kernel<<<2 * NGR, 256, 0, stream>>>(xbuf, bstart, g);

  // ---- batched FC head: M=512 covers both branches ----
  {
    // fc_g1: [512,640] x [640,1500], split-K S=4
    int S = 4, KS = ((2 * FDIM + S * BK - 1) / (S * BK)) * BK;
    dim3 gfc1((512 + BM - 1) / BM, (1500 + BN - 1) / BN, S);
    gemm_splitk_kernel<<<gfc1, 256, 0, stream>>>(g, W_fc_g1, part, 512, 1500, 2 * FDIM, KS);
    reduce_kernel<3, false><<<(512 * 1500 + 255) / 256, 256, 0, stream>>>(part, t1, b_fc_g1, 512, 1500, S, 1500);
    // fc_g2: [512,1500] x [1500,128] -> xc packed [256,256] via STACK, S=8
    int S2 = 8, KS2 = ((1500 + S2 * BK - 1) / (S2 * BK)) * BK;
    dim3 gfc2((512 + BM - 1) / BM, (128 + BN - 1) / BN, S2);
    gemm_splitk_kernel<<<gfc2, 256, 0, stream>>>(t1, W_fc_g2, part, 512, 128, 1500, KS2);
    reduce_kernel<2, true><<<(512 * 128 + 255) / 256, 256, 0, stream>>>(part, xc, b_fc_g2, 512, 128, S2, 256);
  }
  {
    dim3 gx1((NGR + BM - 1) / BM, (1024 + BN - 1) / BN);
    gemm_bf16_kernel<3><<<gx1, 256, 0, stream>>>(xc, W_fc1, t2, b_fc1, NGR, 1024, 256, 1024);
    int S = 4, KS = ((1024 + S * BK - 1) / (S * BK)) * BK;
    dim3 gx2((NGR + BM - 1) / BM, (512 + BN - 1) / BN, S);
    gemm_splitk_kernel<<<gx2, 256, 0, stream>>>(t2, W_fc2, part, NGR, 512, 1024, KS);
    reduce_kernel<3, false><<<(NGR * 512 + 255) / 256, 256, 0, stream>>>(part, t3, b_fc2, NGR, 512, S, 512);
    int S2 = 4, KS2 = ((512 + S2 * BK - 1) / (S2 * BK)) * BK;
    dim3 gx3((NGR + BM - 1) / BM, 1, S2);
    gemm_splitk_kernel<<<gx3, 256, 0, stream>>>(t3, W_out, part, NGR, 2, 512, KS2);
    reduce_kernel<2, false><<<(NGR * 2 + 255) / 256, 256, 0, stream>>>(part, outp, b_out, NGR, 2, S2, 2);
  }
}